// Round 1
// baseline (1606.173 us; speedup 1.0000x reference)
//
#include <hip/hip_runtime.h>
#include <math.h>

#define BB 16
#define NN 2048
#define BN_EPS_ 1e-5f

// ---------------- density: inv[b,n] = 1/mean(32 smallest cos-dist), + global max ----------------
__global__ __launch_bounds__(256) void density_kernel(const float* __restrict__ x,
        float* __restrict__ inv, unsigned int* __restrict__ maxbits){
  __shared__ float u[NN][3];
  const int b = blockIdx.y;
  const float* xb = x + (size_t)b*3*NN;
  const int t = threadIdx.x;
  #pragma unroll
  for (int i = 0; i < NN/256; ++i){
    int n = t + 256*i;
    float x0 = xb[n], x1 = xb[NN+n], x2 = xb[2*NN+n];
    float rn = rsqrtf(x0*x0 + x1*x1 + x2*x2);
    u[n][0] = x0*rn; u[n][1] = x1*rn; u[n][2] = x2*rn;
  }
  __syncthreads();
  const int wave = t >> 6, lane = t & 63;
  const int RPB = NN / gridDim.x;
  const int r0 = blockIdx.x * RPB;
  for (int r = r0 + wave; r < r0 + RPB; r += 4){
    float u0 = u[r][0], u1 = u[r][1], u2 = u[r][2];
    float vals[32];
    #pragma unroll
    for (int i = 0; i < 32; ++i){
      int m = lane + 64*i;
      vals[i] = 1.0f - (u0*u[m][0] + u1*u[m][1] + u2*u[m][2]);
    }
    float lmin = vals[0]; int lj = 0;
    #pragma unroll
    for (int i = 1; i < 32; ++i){ if (vals[i] < lmin){ lmin = vals[i]; lj = i; } }
    float sum = 0.0f;
    for (int it = 0; it < 32; ++it){
      float mv = lmin; int mc = (lane << 5) | lj;
      #pragma unroll
      for (int off = 32; off > 0; off >>= 1){
        float ov = __shfl_xor(mv, off);
        int   oc = __shfl_xor(mc, off);
        if (ov < mv || (ov == mv && oc < mc)){ mv = ov; mc = oc; }
      }
      sum += mv;
      if ((mc >> 5) == lane){           // unique winner clears its element, rescans
        int jj = mc & 31;
        #pragma unroll
        for (int i = 0; i < 32; ++i) if (i == jj) vals[i] = 1e30f;
        lmin = vals[0]; lj = 0;
        #pragma unroll
        for (int i = 1; i < 32; ++i){ if (vals[i] < lmin){ lmin = vals[i]; lj = i; } }
      }
    }
    if (lane == 0){
      float iv = 32.0f / sum;           // 1/mean of the 32 smallest
      inv[b*NN + r] = iv;
      atomicMax(maxbits, __float_as_uint(iv));  // positive floats order as uints
    }
  }
}

__global__ void normalize_kernel(float* __restrict__ dens, const unsigned int* __restrict__ maxbits){
  int i = blockIdx.x*256 + threadIdx.x;
  float mx = __uint_as_float(*maxbits);
  dens[i] = dens[i] / mx;
}

// --------- Zinv / csinv: out[r] = 1/(Σ_m exp(s d[r] d[m]) * (w?zinv[m]:1))  (E symmetric) ---------
template<bool WEIGHTED>
__global__ __launch_bounds__(256) void zcol_kernel(const float* __restrict__ dens,
      const float* __restrict__ wqk, int K, const float* __restrict__ win,
      float* __restrict__ out){
  __shared__ float ds[NN];
  __shared__ float zs[WEIGHTED ? NN : 1];
  const int b = blockIdx.y, t = threadIdx.x;
  float s = 0.0f;
  for (int k = 0; k < K; ++k){ float w = wqk[k]; s += w*w; }
  #pragma unroll
  for (int i = 0; i < NN/256; ++i){
    ds[t + 256*i] = dens[b*NN + t + 256*i];
    if (WEIGHTED) zs[t + 256*i] = win[b*NN + t + 256*i];
  }
  __syncthreads();
  const int wave = t >> 6, lane = t & 63;
  const int RPB = NN / gridDim.x;
  const int r0 = blockIdx.x * RPB;
  for (int r = r0 + wave; r < r0 + RPB; r += 4){
    float a = s * ds[r];
    float sum = 0.0f;
    #pragma unroll
    for (int i = 0; i < NN/64; ++i){
      int m = lane + 64*i;
      float e = __expf(a * ds[m]);
      sum += WEIGHTED ? e * zs[m] : e;
    }
    #pragma unroll
    for (int off = 32; off > 0; off >>= 1) sum += __shfl_xor(sum, off);
    if (lane == 0) out[b*NN + r] = WEIGHTED ? 1.0f/(1e-9f + sum) : 1.0f/sum;
  }
}

// --------- raw[c,m] = Σ_n (x[c,n]·zinv[n]) · exp(s d[n] d[m])  — E generated in LDS ---------
template<int C>
__global__ __launch_bounds__(256) void attn_gemm_kernel(const float* __restrict__ x,
      const float* __restrict__ dens, const float* __restrict__ zinv,
      const float* __restrict__ wqk, int K, float* __restrict__ raw){
  __shared__ float xs[32][C+4];
  __shared__ float es[32][68];
  const int b = blockIdx.y, m0 = blockIdx.x*64, t = threadIdx.x;
  float s = 0.0f;
  for (int k = 0; k < K; ++k){ float w = wqk[k]; s += w*w; }
  const float* db = dens + b*NN;
  const float* zb = zinv + b*NN;
  const float* xb = x + (size_t)b*C*NN;
  const int tr = t >> 4, tc = t & 15;
  constexpr int R = C/16;
  float acc[R][4];
  #pragma unroll
  for (int i = 0; i < R; ++i){ acc[i][0]=acc[i][1]=acc[i][2]=acc[i][3]=0.0f; }
  for (int n0 = 0; n0 < NN; n0 += 32){
    __syncthreads();
    #pragma unroll
    for (int i = 0; i < C*32/256; ++i){
      int idx = t + 256*i;
      int cc = idx >> 5, k = idx & 31;
      xs[k][cc] = xb[cc*NN + n0 + k] * zb[n0 + k];
    }
    #pragma unroll
    for (int i = 0; i < 8; ++i){
      int idx = t + 256*i;
      int j = idx & 63, k = idx >> 6;
      es[k][j] = __expf(s * db[n0 + k] * db[m0 + j]);
    }
    __syncthreads();
    #pragma unroll
    for (int k = 0; k < 32; ++k){
      float4 e = *(const float4*)&es[k][tc*4];
      float a[R];
      #pragma unroll
      for (int q = 0; q < R/4; ++q)
        *(float4*)&a[q*4] = *(const float4*)&xs[k][tr*R + q*4];
      #pragma unroll
      for (int i = 0; i < R; ++i){
        acc[i][0] += a[i]*e.x; acc[i][1] += a[i]*e.y;
        acc[i][2] += a[i]*e.z; acc[i][3] += a[i]*e.w;
      }
    }
  }
  #pragma unroll
  for (int i = 0; i < R; ++i){
    int cc = tr*R + i;
    float4 v = make_float4(acc[i][0], acc[i][1], acc[i][2], acc[i][3]);
    *(float4*)&raw[((size_t)b*C + cc)*NN + m0 + tc*4] = v;
  }
}

// --------- out = x + relu(bn(wt·(x - raw·csinv) + bt)) ---------
template<int C>
__global__ __launch_bounds__(256) void attn_post_kernel(const float* __restrict__ x,
      const float* __restrict__ raw, const float* __restrict__ csinv,
      const float* __restrict__ wt, const float* __restrict__ bt,
      const float* __restrict__ bnp, float* __restrict__ out){
  __shared__ float ds[32][68];
  __shared__ float ws[32][C+4];
  const int b = blockIdx.y, m0 = blockIdx.x*64, t = threadIdx.x;
  const float* xb = x + (size_t)b*C*NN;
  const float* rb = raw + (size_t)b*C*NN;
  const float* cb = csinv + b*NN;
  const int tr = t >> 4, tc = t & 15;
  constexpr int R = C/16;
  float acc[R][4];
  #pragma unroll
  for (int i = 0; i < R; ++i){ acc[i][0]=acc[i][1]=acc[i][2]=acc[i][3]=0.0f; }
  for (int c0 = 0; c0 < C; c0 += 32){
    __syncthreads();
    #pragma unroll
    for (int i = 0; i < 8; ++i){
      int idx = t + 256*i;
      int m = idx & 63, cl = idx >> 6;
      int cc = c0 + cl;
      ds[cl][m] = xb[cc*NN + m0 + m] - rb[cc*NN + m0 + m] * cb[m0 + m];
    }
    #pragma unroll
    for (int i = 0; i < C*32/256; ++i){
      int idx = t + 256*i;
      int cl = idx & 31, o = idx >> 5;
      ws[cl][o] = wt[o*C + c0 + cl];
    }
    __syncthreads();
    #pragma unroll
    for (int k = 0; k < 32; ++k){
      float4 e = *(const float4*)&ds[k][tc*4];
      float a[R];
      #pragma unroll
      for (int q = 0; q < R/4; ++q)
        *(float4*)&a[q*4] = *(const float4*)&ws[k][tr*R + q*4];
      #pragma unroll
      for (int i = 0; i < R; ++i){
        acc[i][0] += a[i]*e.x; acc[i][1] += a[i]*e.y;
        acc[i][2] += a[i]*e.z; acc[i][3] += a[i]*e.w;
      }
    }
  }
  #pragma unroll
  for (int i = 0; i < R; ++i){
    int o = tr*R + i;
    float g = bnp[o], be = bnp[C+o], mn = bnp[2*C+o], vv = bnp[3*C+o];
    float sc = g * rsqrtf(vv + BN_EPS_);
    float sh = be - mn*sc;
    float bv = bt[o];
    float4 r;
    float* rp = &r.x;
    #pragma unroll
    for (int j = 0; j < 4; ++j){
      float y = acc[i][j] + bv;
      y = sc*y + sh;
      y = fmaxf(y, 0.0f);
      rp[j] = xb[o*NN + m0 + tc*4 + j] + y;
    }
    *(float4*)&out[((size_t)b*C + o)*NN + m0 + tc*4] = r;
  }
}

// --------- out = relu(bn(w·x)) ---------
template<int CIN, int COUT>
__global__ __launch_bounds__(256) void conv_bn_relu_kernel(const float* __restrict__ x,
      const float* __restrict__ w, const float* __restrict__ bnp, float* __restrict__ out){
  constexpr int CH = (CIN < 32) ? CIN : 32;
  __shared__ float xs[CH][68];
  __shared__ float ws[CH][COUT+4];
  const int b = blockIdx.y, m0 = blockIdx.x*64, t = threadIdx.x;
  const float* xb = x + (size_t)b*CIN*NN;
  const int tr = t >> 4, tc = t & 15;
  constexpr int R = COUT/16;
  float acc[R][4];
  #pragma unroll
  for (int i = 0; i < R; ++i){ acc[i][0]=acc[i][1]=acc[i][2]=acc[i][3]=0.0f; }
  for (int c0 = 0; c0 < CIN; c0 += CH){
    __syncthreads();
    for (int idx = t; idx < CH*64; idx += 256){
      int m = idx & 63, cl = idx >> 6;
      xs[cl][m] = xb[(c0+cl)*NN + m0 + m];
    }
    for (int idx = t; idx < CH*COUT; idx += 256){
      int cl = idx % CH, o = idx / CH;
      ws[cl][o] = w[o*CIN + c0 + cl];
    }
    __syncthreads();
    #pragma unroll
    for (int k = 0; k < CH; ++k){
      float4 e = *(const float4*)&xs[k][tc*4];
      float a[R];
      #pragma unroll
      for (int q = 0; q < R/4; ++q)
        *(float4*)&a[q*4] = *(const float4*)&ws[k][tr*R + q*4];
      #pragma unroll
      for (int i = 0; i < R; ++i){
        acc[i][0] += a[i]*e.x; acc[i][1] += a[i]*e.y;
        acc[i][2] += a[i]*e.z; acc[i][3] += a[i]*e.w;
      }
    }
  }
  #pragma unroll
  for (int i = 0; i < R; ++i){
    int o = tr*R + i;
    float g = bnp[o], be = bnp[COUT+o], mn = bnp[2*COUT+o], vv = bnp[3*COUT+o];
    float sc = g * rsqrtf(vv + BN_EPS_);
    float sh = be - mn*sc;
    float4 r;
    float* rp = &r.x;
    #pragma unroll
    for (int j = 0; j < 4; ++j){
      float y = sc*acc[i][j] + sh;
      rp[j] = fmaxf(y, 0.0f);
    }
    *(float4*)&out[((size_t)b*COUT + o)*NN + m0 + tc*4] = r;
  }
}

// --------- pooled[b,o] = max_n relu(bn(Σ_c w5[o,c] h[c,n]))  (h5 never materialized) ---------
__global__ __launch_bounds__(256) void conv5_pool_kernel(const float* __restrict__ h,
      const float* __restrict__ w5, const float* __restrict__ bnp, float* __restrict__ pooled){
  __shared__ float ws[128][68];
  __shared__ float hs[128][68];
  const int b = blockIdx.y, o0 = blockIdx.x*64, t = threadIdx.x;
  const float* hb = h + (size_t)b*128*NN;
  #pragma unroll
  for (int i = 0; i < 32; ++i){
    int idx = t + 256*i;
    int cc = idx & 127, ol = idx >> 7;
    ws[cc][ol] = w5[(o0+ol)*128 + cc];
  }
  const int tr = t >> 4, tc = t & 15;
  float sc[4], sh[4];
  #pragma unroll
  for (int i = 0; i < 4; ++i){
    int o = o0 + tr*4 + i;
    float g = bnp[o], be = bnp[1024+o], mn = bnp[2*1024+o], vv = bnp[3*1024+o];
    sc[i] = g * rsqrtf(vv + BN_EPS_);
    sh[i] = be - mn*sc[i];
  }
  float vmax[4] = {0.f,0.f,0.f,0.f};   // relu output >= 0, so 0 is a safe identity
  for (int n0 = 0; n0 < NN; n0 += 64){
    __syncthreads();
    #pragma unroll
    for (int i = 0; i < 32; ++i){
      int idx = t + 256*i;
      int nl = idx & 63, cc = idx >> 6;
      hs[cc][nl] = hb[cc*NN + n0 + nl];
    }
    __syncthreads();
    float acc[4][4];
    #pragma unroll
    for (int i = 0; i < 4; ++i){ acc[i][0]=acc[i][1]=acc[i][2]=acc[i][3]=0.0f; }
    #pragma unroll 8
    for (int k = 0; k < 128; ++k){
      float4 a = *(const float4*)&ws[k][tr*4];
      float4 e = *(const float4*)&hs[k][tc*4];
      acc[0][0]+=a.x*e.x; acc[0][1]+=a.x*e.y; acc[0][2]+=a.x*e.z; acc[0][3]+=a.x*e.w;
      acc[1][0]+=a.y*e.x; acc[1][1]+=a.y*e.y; acc[1][2]+=a.y*e.z; acc[1][3]+=a.y*e.w;
      acc[2][0]+=a.z*e.x; acc[2][1]+=a.z*e.y; acc[2][2]+=a.z*e.z; acc[2][3]+=a.z*e.w;
      acc[3][0]+=a.w*e.x; acc[3][1]+=a.w*e.y; acc[3][2]+=a.w*e.z; acc[3][3]+=a.w*e.w;
    }
    #pragma unroll
    for (int i = 0; i < 4; ++i){
      #pragma unroll
      for (int j = 0; j < 4; ++j){
        float y = sc[i]*acc[i][j] + sh[i];
        y = fmaxf(y, 0.0f);
        vmax[i] = fmaxf(vmax[i], y);
      }
    }
  }
  #pragma unroll
  for (int i = 0; i < 4; ++i){
    float v = vmax[i];
    v = fmaxf(v, __shfl_xor(v, 1));
    v = fmaxf(v, __shfl_xor(v, 2));
    v = fmaxf(v, __shfl_xor(v, 4));
    v = fmaxf(v, __shfl_xor(v, 8));
    if (tc == 0) pooled[b*1024 + o0 + tr*4 + i] = v;
  }
}

// --------- lin1 + bn6 + relu ---------
__global__ void lin1_kernel(const float* __restrict__ pooled, const float* __restrict__ w,
      const float* __restrict__ bnp, float* __restrict__ out1){
  int tid = blockIdx.x*256 + threadIdx.x;   // 8192 threads
  int b = tid >> 9, j = tid & 511;
  const float4* p4 = (const float4*)(pooled + b*1024);
  const float4* w4 = (const float4*)(w + j*1024);
  float sum = 0.0f;
  for (int e = 0; e < 256; ++e){
    float4 a = p4[e], c = w4[e];
    sum += a.x*c.x + a.y*c.y + a.z*c.z + a.w*c.w;
  }
  float g = bnp[j], be = bnp[512+j], mn = bnp[2*512+j], vv = bnp[3*512+j];
  float s = g * rsqrtf(vv + BN_EPS_);
  float y = s*sum + (be - mn*s);
  out1[b*512 + j] = fmaxf(y, 0.0f);
}

// --------- lin2 ---------
__global__ void lin2_kernel(const float* __restrict__ h, const float* __restrict__ w,
      const float* __restrict__ bias, float* __restrict__ out){
  int tid = blockIdx.x*64 + threadIdx.x;
  if (tid >= 640) return;
  int b = tid / 40, k = tid % 40;
  const float4* h4 = (const float4*)(h + b*512);
  const float4* w4 = (const float4*)(w + k*512);
  float sum = 0.0f;
  for (int e = 0; e < 128; ++e){
    float4 a = h4[e], c = w4[e];
    sum += a.x*c.x + a.y*c.y + a.z*c.z + a.w*c.w;
  }
  out[tid] = sum + bias[k];
}

extern "C" void kernel_launch(void* const* d_in, const int* in_sizes, int n_in,
                              void* d_out, int out_size, void* d_ws, size_t ws_size,
                              hipStream_t stream){
  (void)in_sizes; (void)n_in; (void)out_size; (void)ws_size;
  const float* x     = (const float*)d_in[0];
  const float* w1    = (const float*)d_in[1];
  const float* w2    = (const float*)d_in[2];
  const float* w3    = (const float*)d_in[3];
  const float* w4    = (const float*)d_in[4];
  const float* w5    = (const float*)d_in[5];
  const float* bn1   = (const float*)d_in[6];
  const float* bn2   = (const float*)d_in[7];
  const float* bn3   = (const float*)d_in[8];
  const float* bn4   = (const float*)d_in[9];
  const float* bn5   = (const float*)d_in[10];
  const float* da_wqk[4] = {(const float*)d_in[11], (const float*)d_in[15], (const float*)d_in[19], (const float*)d_in[23]};
  const float* da_wt[4]  = {(const float*)d_in[12], (const float*)d_in[16], (const float*)d_in[20], (const float*)d_in[24]};
  const float* da_bt[4]  = {(const float*)d_in[13], (const float*)d_in[17], (const float*)d_in[21], (const float*)d_in[25]};
  const float* da_bn[4]  = {(const float*)d_in[14], (const float*)d_in[18], (const float*)d_in[22], (const float*)d_in[26]};
  const float* lin1_w = (const float*)d_in[27];
  const float* bn6    = (const float*)d_in[28];
  const float* lin2_w = (const float*)d_in[29];
  const float* lin2_b = (const float*)d_in[30];

  float* ws = (float*)d_ws;
  unsigned int* maxbits = (unsigned int*)ws;
  float* dens   = ws + 64;
  float* zinv   = dens + BB*NN;
  float* csinv  = zinv + BB*NN;
  float* hA     = csinv + BB*NN;
  float* hB     = hA  + (size_t)BB*64*NN;
  float* h4A    = hB  + (size_t)BB*64*NN;
  float* raw    = h4A + (size_t)BB*128*NN;
  float* pooled = raw + (size_t)BB*128*NN;
  float* l1o    = pooled + BB*1024;
  float* h4B    = hA;   // attn4 output reuses the (hA|hB) region: 16*128*2048 floats

  hipMemsetAsync(maxbits, 0, sizeof(unsigned int), stream);
  density_kernel<<<dim3(32, BB), 256, 0, stream>>>(x, dens, maxbits);
  normalize_kernel<<<dim3(BB*NN/256), 256, 0, stream>>>(dens, maxbits);

  conv_bn_relu_kernel<3,64><<<dim3(32,BB),256,0,stream>>>(x, w1, bn1, hA);

  // attn1: hA -> hB
  zcol_kernel<false><<<dim3(32,BB),256,0,stream>>>(dens, da_wqk[0], 16, nullptr, zinv);
  zcol_kernel<true ><<<dim3(32,BB),256,0,stream>>>(dens, da_wqk[0], 16, zinv, csinv);
  attn_gemm_kernel<64><<<dim3(32,BB),256,0,stream>>>(hA, dens, zinv, da_wqk[0], 16, raw);
  attn_post_kernel<64><<<dim3(32,BB),256,0,stream>>>(hA, raw, csinv, da_wt[0], da_bt[0], da_bn[0], hB);

  conv_bn_relu_kernel<64,64><<<dim3(32,BB),256,0,stream>>>(hB, w2, bn2, hA);

  // attn2: hA -> hB
  zcol_kernel<false><<<dim3(32,BB),256,0,stream>>>(dens, da_wqk[1], 16, nullptr, zinv);
  zcol_kernel<true ><<<dim3(32,BB),256,0,stream>>>(dens, da_wqk[1], 16, zinv, csinv);
  attn_gemm_kernel<64><<<dim3(32,BB),256,0,stream>>>(hA, dens, zinv, da_wqk[1], 16, raw);
  attn_post_kernel<64><<<dim3(32,BB),256,0,stream>>>(hA, raw, csinv, da_wt[1], da_bt[1], da_bn[1], hB);

  conv_bn_relu_kernel<64,64><<<dim3(32,BB),256,0,stream>>>(hB, w3, bn3, hA);

  // attn3: hA -> hB
  zcol_kernel<false><<<dim3(32,BB),256,0,stream>>>(dens, da_wqk[2], 16, nullptr, zinv);
  zcol_kernel<true ><<<dim3(32,BB),256,0,stream>>>(dens, da_wqk[2], 16, zinv, csinv);
  attn_gemm_kernel<64><<<dim3(32,BB),256,0,stream>>>(hA, dens, zinv, da_wqk[2], 16, raw);
  attn_post_kernel<64><<<dim3(32,BB),256,0,stream>>>(hA, raw, csinv, da_wt[2], da_bt[2], da_bn[2], hB);

  conv_bn_relu_kernel<64,128><<<dim3(32,BB),256,0,stream>>>(hB, w4, bn4, h4A);

  // attn4 (C=128): h4A -> h4B
  zcol_kernel<false><<<dim3(32,BB),256,0,stream>>>(dens, da_wqk[3], 32, nullptr, zinv);
  zcol_kernel<true ><<<dim3(32,BB),256,0,stream>>>(dens, da_wqk[3], 32, zinv, csinv);
  attn_gemm_kernel<128><<<dim3(32,BB),256,0,stream>>>(h4A, dens, zinv, da_wqk[3], 32, raw);
  attn_post_kernel<128><<<dim3(32,BB),256,0,stream>>>(h4A, raw, csinv, da_wt[3], da_bt[3], da_bn[3], h4B);

  conv5_pool_kernel<<<dim3(16,BB),256,0,stream>>>(h4B, w5, bn5, pooled);
  lin1_kernel<<<dim3(32),256,0,stream>>>(pooled, lin1_w, bn6, l1o);
  lin2_kernel<<<dim3(10),64,0,stream>>>(l1o, lin2_w, lin2_b, (float*)d_out);
}

// Round 2
// 1538.372 us; speedup vs baseline: 1.0441x; 1.0441x over previous
//
#include <hip/hip_runtime.h>
#include <math.h>

#define BB 16
#define NN 2048
#define BN_EPS_ 1e-5f

// ---------------- normalize points once: u[b][3][n] = xyz/|xyz| ----------------
__global__ __launch_bounds__(256) void normalize_points_kernel(const float* __restrict__ x,
        float* __restrict__ u){
  int idx = blockIdx.x*256 + threadIdx.x;     // BB*NN threads
  int b = idx >> 11, n = idx & (NN-1);
  const float* xb = x + (size_t)b*3*NN;
  float x0 = xb[n], x1 = xb[NN+n], x2 = xb[2*NN+n];
  float rn = rsqrtf(x0*x0 + x1*x1 + x2*x2);
  float* ub = u + (size_t)b*3*NN;
  ub[n] = x0*rn; ub[NN+n] = x1*rn; ub[2*NN+n] = x2*rn;
}

// ---------------- density: inv[b,n] = 1/mean(32 smallest cos-dist), + global max ----------------
// 8 rows/block (2 per wave), 4096 blocks -> ~6 blocks/CU (24KB LDS), latency well hidden.
#define DROWS 8
__global__ __launch_bounds__(256) void density2_kernel(const float* __restrict__ u,
        float* __restrict__ inv, unsigned int* __restrict__ maxbits){
  __shared__ float us0[NN], us1[NN], us2[NN];
  const int b = blockIdx.y;
  const float* ub = u + (size_t)b*3*NN;
  const int t = threadIdx.x;
  #pragma unroll
  for (int i = 0; i < NN/(256*4); ++i){
    int n4 = t + 256*i;
    ((float4*)us0)[n4] = ((const float4*)ub)[n4];
    ((float4*)us1)[n4] = ((const float4*)(ub+NN))[n4];
    ((float4*)us2)[n4] = ((const float4*)(ub+2*NN))[n4];
  }
  __syncthreads();
  const int wave = t >> 6, lane = t & 63;
  const int r0 = blockIdx.x * DROWS;
  #pragma unroll
  for (int j = 0; j < DROWS/4; ++j){
    const int r = r0 + wave + 4*j;
    float u0 = us0[r], u1 = us1[r], u2 = us2[r];
    float vals[32];
    #pragma unroll
    for (int i = 0; i < 32; ++i){
      int m = lane + 64*i;
      vals[i] = 1.0f - (u0*us0[m] + u1*us1[m] + u2*us2[m]);
    }
    float lmin = vals[0]; int lj = 0;
    #pragma unroll
    for (int i = 1; i < 32; ++i){ if (vals[i] < lmin){ lmin = vals[i]; lj = i; } }
    float sum = 0.0f;
    for (int it = 0; it < 32; ++it){
      float mv = lmin;
      #pragma unroll
      for (int off = 32; off > 0; off >>= 1) mv = fminf(mv, __shfl_xor(mv, off));
      sum += mv;
      unsigned long long ball = __ballot(lmin == mv);
      int winner = (int)__ffsll((unsigned long long)ball) - 1;
      if (lane == winner){                 // unique winner clears its element, rescans
        #pragma unroll
        for (int i = 0; i < 32; ++i) if (i == lj) vals[i] = 1e30f;
        lmin = vals[0]; lj = 0;
        #pragma unroll
        for (int i = 1; i < 32; ++i){ if (vals[i] < lmin){ lmin = vals[i]; lj = i; } }
      }
    }
    if (lane == 0){
      float iv = 32.0f / sum;             // 1/mean of the 32 smallest
      inv[b*NN + r] = iv;
      atomicMax(maxbits, __float_as_uint(iv));  // positive floats order as uints
    }
  }
}

__global__ void normalize_kernel(float* __restrict__ dens, const unsigned int* __restrict__ maxbits){
  int i = blockIdx.x*256 + threadIdx.x;
  float mx = __uint_as_float(*maxbits);
  dens[i] = dens[i] / mx;
}

// --------- Zinv / csinv: out[r] = 1/(Σ_m exp(s d[r] d[m]) * (w?zinv[m]:1))  (E symmetric) ---------
template<bool WEIGHTED>
__global__ __launch_bounds__(256) void zcol_kernel(const float* __restrict__ dens,
      const float* __restrict__ wqk, int K, const float* __restrict__ win,
      float* __restrict__ out){
  __shared__ float ds[NN];
  __shared__ float zs[WEIGHTED ? NN : 1];
  const int b = blockIdx.y, t = threadIdx.x;
  float s = 0.0f;
  for (int k = 0; k < K; ++k){ float w = wqk[k]; s += w*w; }
  #pragma unroll
  for (int i = 0; i < NN/256; ++i){
    ds[t + 256*i] = dens[b*NN + t + 256*i];
    if (WEIGHTED) zs[t + 256*i] = win[b*NN + t + 256*i];
  }
  __syncthreads();
  const int wave = t >> 6, lane = t & 63;
  const int RPB = NN / gridDim.x;
  const int r0 = blockIdx.x * RPB;
  for (int r = r0 + wave; r < r0 + RPB; r += 4){
    float a = s * ds[r];
    float sum = 0.0f;
    #pragma unroll
    for (int i = 0; i < NN/64; ++i){
      int m = lane + 64*i;
      float e = __expf(a * ds[m]);
      sum += WEIGHTED ? e * zs[m] : e;
    }
    #pragma unroll
    for (int off = 32; off > 0; off >>= 1) sum += __shfl_xor(sum, off);
    if (lane == 0) out[b*NN + r] = WEIGHTED ? 1.0f/(1e-9f + sum) : 1.0f/sum;
  }
}

// --------- raw[c,m] = Σ_n (x[c,n]·zinv[n]) · exp(s d[n] d[m])  — E generated in LDS ---------
template<int C>
__global__ __launch_bounds__(256) void attn_gemm_kernel(const float* __restrict__ x,
      const float* __restrict__ dens, const float* __restrict__ zinv,
      const float* __restrict__ wqk, int K, float* __restrict__ raw){
  __shared__ float xs[32][C+4];
  __shared__ float es[32][68];
  const int b = blockIdx.y, m0 = blockIdx.x*64, t = threadIdx.x;
  float s = 0.0f;
  for (int k = 0; k < K; ++k){ float w = wqk[k]; s += w*w; }
  const float* db = dens + b*NN;
  const float* zb = zinv + b*NN;
  const float* xb = x + (size_t)b*C*NN;
  const int tr = t >> 4, tc = t & 15;
  constexpr int R = C/16;
  float acc[R][4];
  #pragma unroll
  for (int i = 0; i < R; ++i){ acc[i][0]=acc[i][1]=acc[i][2]=acc[i][3]=0.0f; }
  for (int n0 = 0; n0 < NN; n0 += 32){
    __syncthreads();
    #pragma unroll
    for (int i = 0; i < C*32/256; ++i){
      int idx = t + 256*i;
      int cc = idx >> 5, k = idx & 31;
      xs[k][cc] = xb[cc*NN + n0 + k] * zb[n0 + k];
    }
    #pragma unroll
    for (int i = 0; i < 8; ++i){
      int idx = t + 256*i;
      int j = idx & 63, k = idx >> 6;
      es[k][j] = __expf(s * db[n0 + k] * db[m0 + j]);
    }
    __syncthreads();
    #pragma unroll
    for (int k = 0; k < 32; ++k){
      float4 e = *(const float4*)&es[k][tc*4];
      float a[R];
      #pragma unroll
      for (int q = 0; q < R/4; ++q)
        *(float4*)&a[q*4] = *(const float4*)&xs[k][tr*R + q*4];
      #pragma unroll
      for (int i = 0; i < R; ++i){
        acc[i][0] += a[i]*e.x; acc[i][1] += a[i]*e.y;
        acc[i][2] += a[i]*e.z; acc[i][3] += a[i]*e.w;
      }
    }
  }
  #pragma unroll
  for (int i = 0; i < R; ++i){
    int cc = tr*R + i;
    float4 v = make_float4(acc[i][0], acc[i][1], acc[i][2], acc[i][3]);
    *(float4*)&raw[((size_t)b*C + cc)*NN + m0 + tc*4] = v;
  }
}

// --------- out = x + relu(bn(wt·(x - raw·csinv) + bt)) ---------
template<int C>
__global__ __launch_bounds__(256) void attn_post_kernel(const float* __restrict__ x,
      const float* __restrict__ raw, const float* __restrict__ csinv,
      const float* __restrict__ wt, const float* __restrict__ bt,
      const float* __restrict__ bnp, float* __restrict__ out){
  __shared__ float ds[32][68];
  __shared__ float ws[32][C+4];
  const int b = blockIdx.y, m0 = blockIdx.x*64, t = threadIdx.x;
  const float* xb = x + (size_t)b*C*NN;
  const float* rb = raw + (size_t)b*C*NN;
  const float* cb = csinv + b*NN;
  const int tr = t >> 4, tc = t & 15;
  constexpr int R = C/16;
  float acc[R][4];
  #pragma unroll
  for (int i = 0; i < R; ++i){ acc[i][0]=acc[i][1]=acc[i][2]=acc[i][3]=0.0f; }
  for (int c0 = 0; c0 < C; c0 += 32){
    __syncthreads();
    #pragma unroll
    for (int i = 0; i < 8; ++i){
      int idx = t + 256*i;
      int m = idx & 63, cl = idx >> 6;
      int cc = c0 + cl;
      ds[cl][m] = xb[cc*NN + m0 + m] - rb[cc*NN + m0 + m] * cb[m0 + m];
    }
    #pragma unroll
    for (int i = 0; i < C*32/256; ++i){
      int idx = t + 256*i;
      int cl = idx & 31, o = idx >> 5;
      ws[cl][o] = wt[o*C + c0 + cl];
    }
    __syncthreads();
    #pragma unroll
    for (int k = 0; k < 32; ++k){
      float4 e = *(const float4*)&ds[k][tc*4];
      float a[R];
      #pragma unroll
      for (int q = 0; q < R/4; ++q)
        *(float4*)&a[q*4] = *(const float4*)&ws[k][tr*R + q*4];
      #pragma unroll
      for (int i = 0; i < R; ++i){
        acc[i][0] += a[i]*e.x; acc[i][1] += a[i]*e.y;
        acc[i][2] += a[i]*e.z; acc[i][3] += a[i]*e.w;
      }
    }
  }
  #pragma unroll
  for (int i = 0; i < R; ++i){
    int o = tr*R + i;
    float g = bnp[o], be = bnp[C+o], mn = bnp[2*C+o], vv = bnp[3*C+o];
    float sc = g * rsqrtf(vv + BN_EPS_);
    float sh = be - mn*sc;
    float bv = bt[o];
    float4 r;
    float* rp = &r.x;
    #pragma unroll
    for (int j = 0; j < 4; ++j){
      float y = acc[i][j] + bv;
      y = sc*y + sh;
      y = fmaxf(y, 0.0f);
      rp[j] = xb[o*NN + m0 + tc*4 + j] + y;
    }
    *(float4*)&out[((size_t)b*C + o)*NN + m0 + tc*4] = r;
  }
}

// --------- out = relu(bn(w·x)) ---------
template<int CIN, int COUT>
__global__ __launch_bounds__(256) void conv_bn_relu_kernel(const float* __restrict__ x,
      const float* __restrict__ w, const float* __restrict__ bnp, float* __restrict__ out){
  constexpr int CH = (CIN < 32) ? CIN : 32;
  __shared__ float xs[CH][68];
  __shared__ float ws[CH][COUT+4];
  const int b = blockIdx.y, m0 = blockIdx.x*64, t = threadIdx.x;
  const float* xb = x + (size_t)b*CIN*NN;
  const int tr = t >> 4, tc = t & 15;
  constexpr int R = COUT/16;
  float acc[R][4];
  #pragma unroll
  for (int i = 0; i < R; ++i){ acc[i][0]=acc[i][1]=acc[i][2]=acc[i][3]=0.0f; }
  for (int c0 = 0; c0 < CIN; c0 += CH){
    __syncthreads();
    for (int idx = t; idx < CH*64; idx += 256){
      int m = idx & 63, cl = idx >> 6;
      xs[cl][m] = xb[(c0+cl)*NN + m0 + m];
    }
    for (int idx = t; idx < CH*COUT; idx += 256){
      int cl = idx % CH, o = idx / CH;
      ws[cl][o] = w[o*CIN + c0 + cl];
    }
    __syncthreads();
    #pragma unroll
    for (int k = 0; k < CH; ++k){
      float4 e = *(const float4*)&xs[k][tc*4];
      float a[R];
      #pragma unroll
      for (int q = 0; q < R/4; ++q)
        *(float4*)&a[q*4] = *(const float4*)&ws[k][tr*R + q*4];
      #pragma unroll
      for (int i = 0; i < R; ++i){
        acc[i][0] += a[i]*e.x; acc[i][1] += a[i]*e.y;
        acc[i][2] += a[i]*e.z; acc[i][3] += a[i]*e.w;
      }
    }
  }
  #pragma unroll
  for (int i = 0; i < R; ++i){
    int o = tr*R + i;
    float g = bnp[o], be = bnp[COUT+o], mn = bnp[2*COUT+o], vv = bnp[3*COUT+o];
    float sc = g * rsqrtf(vv + BN_EPS_);
    float sh = be - mn*sc;
    float4 r;
    float* rp = &r.x;
    #pragma unroll
    for (int j = 0; j < 4; ++j){
      float y = sc*acc[i][j] + sh;
      rp[j] = fmaxf(y, 0.0f);
    }
    *(float4*)&out[((size_t)b*COUT + o)*NN + m0 + tc*4] = r;
  }
}

// --------- pooled[b,o] = max_n relu(bn(Σ_c w5[o,c] h[c,n]))  (h5 never materialized) ---------
__global__ __launch_bounds__(256) void conv5_pool_kernel(const float* __restrict__ h,
      const float* __restrict__ w5, const float* __restrict__ bnp, float* __restrict__ pooled){
  __shared__ float ws[128][68];
  __shared__ float hs[128][68];
  const int b = blockIdx.y, o0 = blockIdx.x*64, t = threadIdx.x;
  const float* hb = h + (size_t)b*128*NN;
  #pragma unroll
  for (int i = 0; i < 32; ++i){
    int idx = t + 256*i;
    int cc = idx & 127, ol = idx >> 7;
    ws[cc][ol] = w5[(o0+ol)*128 + cc];
  }
  const int tr = t >> 4, tc = t & 15;
  float sc[4], sh[4];
  #pragma unroll
  for (int i = 0; i < 4; ++i){
    int o = o0 + tr*4 + i;
    float g = bnp[o], be = bnp[1024+o], mn = bnp[2*1024+o], vv = bnp[3*1024+o];
    sc[i] = g * rsqrtf(vv + BN_EPS_);
    sh[i] = be - mn*sc[i];
  }
  float vmax[4] = {0.f,0.f,0.f,0.f};   // relu output >= 0, so 0 is a safe identity
  for (int n0 = 0; n0 < NN; n0 += 64){
    __syncthreads();
    #pragma unroll
    for (int i = 0; i < 32; ++i){
      int idx = t + 256*i;
      int nl = idx & 63, cc = idx >> 6;
      hs[cc][nl] = hb[cc*NN + n0 + nl];
    }
    __syncthreads();
    float acc[4][4];
    #pragma unroll
    for (int i = 0; i < 4; ++i){ acc[i][0]=acc[i][1]=acc[i][2]=acc[i][3]=0.0f; }
    #pragma unroll 8
    for (int k = 0; k < 128; ++k){
      float4 a = *(const float4*)&ws[k][tr*4];
      float4 e = *(const float4*)&hs[k][tc*4];
      acc[0][0]+=a.x*e.x; acc[0][1]+=a.x*e.y; acc[0][2]+=a.x*e.z; acc[0][3]+=a.x*e.w;
      acc[1][0]+=a.y*e.x; acc[1][1]+=a.y*e.y; acc[1][2]+=a.y*e.z; acc[1][3]+=a.y*e.w;
      acc[2][0]+=a.z*e.x; acc[2][1]+=a.z*e.y; acc[2][2]+=a.z*e.z; acc[2][3]+=a.z*e.w;
      acc[3][0]+=a.w*e.x; acc[3][1]+=a.w*e.y; acc[3][2]+=a.w*e.z; acc[3][3]+=a.w*e.w;
    }
    #pragma unroll
    for (int i = 0; i < 4; ++i){
      #pragma unroll
      for (int j = 0; j < 4; ++j){
        float y = sc[i]*acc[i][j] + sh[i];
        y = fmaxf(y, 0.0f);
        vmax[i] = fmaxf(vmax[i], y);
      }
    }
  }
  #pragma unroll
  for (int i = 0; i < 4; ++i){
    float v = vmax[i];
    v = fmaxf(v, __shfl_xor(v, 1));
    v = fmaxf(v, __shfl_xor(v, 2));
    v = fmaxf(v, __shfl_xor(v, 4));
    v = fmaxf(v, __shfl_xor(v, 8));
    if (tc == 0) pooled[b*1024 + o0 + tr*4 + i] = v;
  }
}

// --------- lin1 + bn6 + relu ---------
__global__ void lin1_kernel(const float* __restrict__ pooled, const float* __restrict__ w,
      const float* __restrict__ bnp, float* __restrict__ out1){
  int tid = blockIdx.x*256 + threadIdx.x;   // 8192 threads
  int b = tid >> 9, j = tid & 511;
  const float4* p4 = (const float4*)(pooled + b*1024);
  const float4* w4 = (const float4*)(w + j*1024);
  float sum = 0.0f;
  for (int e = 0; e < 256; ++e){
    float4 a = p4[e], c = w4[e];
    sum += a.x*c.x + a.y*c.y + a.z*c.z + a.w*c.w;
  }
  float g = bnp[j], be = bnp[512+j], mn = bnp[2*512+j], vv = bnp[3*512+j];
  float s = g * rsqrtf(vv + BN_EPS_);
  float y = s*sum + (be - mn*s);
  out1[b*512 + j] = fmaxf(y, 0.0f);
}

// --------- lin2 ---------
__global__ void lin2_kernel(const float* __restrict__ h, const float* __restrict__ w,
      const float* __restrict__ bias, float* __restrict__ out){
  int tid = blockIdx.x*64 + threadIdx.x;
  if (tid >= 640) return;
  int b = tid / 40, k = tid % 40;
  const float4* h4 = (const float4*)(h + b*512);
  const float4* w4 = (const float4*)(w + k*512);
  float sum = 0.0f;
  for (int e = 0; e < 128; ++e){
    float4 a = h4[e], c = w4[e];
    sum += a.x*c.x + a.y*c.y + a.z*c.z + a.w*c.w;
  }
  out[tid] = sum + bias[k];
}

extern "C" void kernel_launch(void* const* d_in, const int* in_sizes, int n_in,
                              void* d_out, int out_size, void* d_ws, size_t ws_size,
                              hipStream_t stream){
  (void)in_sizes; (void)n_in; (void)out_size; (void)ws_size;
  const float* x     = (const float*)d_in[0];
  const float* w1    = (const float*)d_in[1];
  const float* w2    = (const float*)d_in[2];
  const float* w3    = (const float*)d_in[3];
  const float* w4    = (const float*)d_in[4];
  const float* w5    = (const float*)d_in[5];
  const float* bn1   = (const float*)d_in[6];
  const float* bn2   = (const float*)d_in[7];
  const float* bn3   = (const float*)d_in[8];
  const float* bn4   = (const float*)d_in[9];
  const float* bn5   = (const float*)d_in[10];
  const float* da_wqk[4] = {(const float*)d_in[11], (const float*)d_in[15], (const float*)d_in[19], (const float*)d_in[23]};
  const float* da_wt[4]  = {(const float*)d_in[12], (const float*)d_in[16], (const float*)d_in[20], (const float*)d_in[24]};
  const float* da_bt[4]  = {(const float*)d_in[13], (const float*)d_in[17], (const float*)d_in[21], (const float*)d_in[25]};
  const float* da_bn[4]  = {(const float*)d_in[14], (const float*)d_in[18], (const float*)d_in[22], (const float*)d_in[26]};
  const float* lin1_w = (const float*)d_in[27];
  const float* bn6    = (const float*)d_in[28];
  const float* lin2_w = (const float*)d_in[29];
  const float* lin2_b = (const float*)d_in[30];

  float* ws = (float*)d_ws;
  unsigned int* maxbits = (unsigned int*)ws;
  float* dens   = ws + 64;
  float* zinv   = dens + BB*NN;
  float* csinv  = zinv + BB*NN;
  float* hA     = csinv + BB*NN;
  float* hB     = hA  + (size_t)BB*64*NN;
  float* h4A    = hB  + (size_t)BB*64*NN;
  float* raw    = h4A + (size_t)BB*128*NN;
  float* pooled = raw + (size_t)BB*128*NN;
  float* l1o    = pooled + BB*1024;
  float* uvec   = l1o + BB*512;
  float* h4B    = hA;   // attn4 output reuses the (hA|hB) region: 16*128*2048 floats

  hipMemsetAsync(maxbits, 0, sizeof(unsigned int), stream);
  normalize_points_kernel<<<dim3(BB*NN/256), 256, 0, stream>>>(x, uvec);
  density2_kernel<<<dim3(NN/DROWS, BB), 256, 0, stream>>>(uvec, dens, maxbits);
  normalize_kernel<<<dim3(BB*NN/256), 256, 0, stream>>>(dens, maxbits);

  conv_bn_relu_kernel<3,64><<<dim3(32,BB),256,0,stream>>>(x, w1, bn1, hA);

  // attn1: hA -> hB
  zcol_kernel<false><<<dim3(32,BB),256,0,stream>>>(dens, da_wqk[0], 16, nullptr, zinv);
  zcol_kernel<true ><<<dim3(32,BB),256,0,stream>>>(dens, da_wqk[0], 16, zinv, csinv);
  attn_gemm_kernel<64><<<dim3(32,BB),256,0,stream>>>(hA, dens, zinv, da_wqk[0], 16, raw);
  attn_post_kernel<64><<<dim3(32,BB),256,0,stream>>>(hA, raw, csinv, da_wt[0], da_bt[0], da_bn[0], hB);

  conv_bn_relu_kernel<64,64><<<dim3(32,BB),256,0,stream>>>(hB, w2, bn2, hA);

  // attn2: hA -> hB
  zcol_kernel<false><<<dim3(32,BB),256,0,stream>>>(dens, da_wqk[1], 16, nullptr, zinv);
  zcol_kernel<true ><<<dim3(32,BB),256,0,stream>>>(dens, da_wqk[1], 16, zinv, csinv);
  attn_gemm_kernel<64><<<dim3(32,BB),256,0,stream>>>(hA, dens, zinv, da_wqk[1], 16, raw);
  attn_post_kernel<64><<<dim3(32,BB),256,0,stream>>>(hA, raw, csinv, da_wt[1], da_bt[1], da_bn[1], hB);

  conv_bn_relu_kernel<64,64><<<dim3(32,BB),256,0,stream>>>(hB, w3, bn3, hA);

  // attn3: hA -> hB
  zcol_kernel<false><<<dim3(32,BB),256,0,stream>>>(dens, da_wqk[2], 16, nullptr, zinv);
  zcol_kernel<true ><<<dim3(32,BB),256,0,stream>>>(dens, da_wqk[2], 16, zinv, csinv);
  attn_gemm_kernel<64><<<dim3(32,BB),256,0,stream>>>(hA, dens, zinv, da_wqk[2], 16, raw);
  attn_post_kernel<64><<<dim3(32,BB),256,0,stream>>>(hA, raw, csinv, da_wt[2], da_bt[2], da_bn[2], hB);

  conv_bn_relu_kernel<64,128><<<dim3(32,BB),256,0,stream>>>(hB, w4, bn4, h4A);

  // attn4 (C=128): h4A -> h4B
  zcol_kernel<false><<<dim3(32,BB),256,0,stream>>>(dens, da_wqk[3], 32, nullptr, zinv);
  zcol_kernel<true ><<<dim3(32,BB),256,0,stream>>>(dens, da_wqk[3], 32, zinv, csinv);
  attn_gemm_kernel<128><<<dim3(32,BB),256,0,stream>>>(h4A, dens, zinv, da_wqk[3], 32, raw);
  attn_post_kernel<128><<<dim3(32,BB),256,0,stream>>>(h4A, raw, csinv, da_wt[3], da_bt[3], da_bn[3], h4B);

  conv5_pool_kernel<<<dim3(16,BB),256,0,stream>>>(h4B, w5, bn5, pooled);
  lin1_kernel<<<dim3(32),256,0,stream>>>(pooled, lin1_w, bn6, l1o);
  lin2_kernel<<<dim3(10),64,0,stream>>>(l1o, lin2_w, lin2_b, (float*)d_out);
}

// Round 3
// 1454.993 us; speedup vs baseline: 1.1039x; 1.0573x over previous
//
#include <hip/hip_runtime.h>
#include <math.h>

#define BB 16
#define NN 2048
#define BN_EPS_ 1e-5f

// ---------------- normalize points once: u[b][3][n] = xyz/|xyz| ----------------
__global__ __launch_bounds__(256) void normalize_points_kernel(const float* __restrict__ x,
        float* __restrict__ u){
  int idx = blockIdx.x*256 + threadIdx.x;     // BB*NN threads
  int b = idx >> 11, n = idx & (NN-1);
  const float* xb = x + (size_t)b*3*NN;
  float x0 = xb[n], x1 = xb[NN+n], x2 = xb[2*NN+n];
  float rn = rsqrtf(x0*x0 + x1*x1 + x2*x2);
  float* ub = u + (size_t)b*3*NN;
  ub[n] = x0*rn; ub[NN+n] = x1*rn; ub[2*NN+n] = x2*rn;
}

// ---------------- density via histogram rank-select ----------------
// inv[b,n] = 32 / (sum of 32 smallest cos-dists of row n).
// Per row: LDS histogram of q=clamp(int(dist*256),0,511) -> crossing bin B, count C0 below;
// sum(bins<B) exactly + extract r=32-C0 smallest from bin-B candidate buffer (~4 values).
#define DROWS 8
__global__ __launch_bounds__(256) void density3_kernel(const float* __restrict__ u,
        float* __restrict__ inv, unsigned int* __restrict__ maxbits){
  __shared__ float us0[NN], us1[NN], us2[NN];
  __shared__ unsigned int hist[512];
  __shared__ float buf[128];
  __shared__ unsigned int bufcnt;
  __shared__ unsigned int bB, bC0;
  __shared__ float partial[4];
  const int b = blockIdx.y;
  const float* ub = u + (size_t)b*3*NN;
  const int t = threadIdx.x;
  #pragma unroll
  for (int i = 0; i < NN/(256*4); ++i){
    int n4 = t + 256*i;
    ((float4*)us0)[n4] = ((const float4*)ub)[n4];
    ((float4*)us1)[n4] = ((const float4*)(ub+NN))[n4];
    ((float4*)us2)[n4] = ((const float4*)(ub+2*NN))[n4];
  }
  __syncthreads();
  // hoist this thread's column strip into registers (same for every row)
  float m0[8], m1[8], m2[8];
  #pragma unroll
  for (int i = 0; i < 8; ++i){
    int m = t + 256*i;
    m0[i] = us0[m]; m1[i] = us1[m]; m2[i] = us2[m];
  }
  const int wave = t >> 6, lane = t & 63;
  const int r0 = blockIdx.x * DROWS;
  for (int j = 0; j < DROWS; ++j){
    const int r = r0 + j;
    hist[t] = 0u; hist[t+256] = 0u;
    if (t == 0) bufcnt = 0u;
    __syncthreads();
    float u0 = us0[r], u1 = us1[r], u2 = us2[r];
    float dd[8]; int qq[8];
    #pragma unroll
    for (int i = 0; i < 8; ++i){
      float d = 1.0f - (u0*m0[i] + u1*m1[i] + u2*m2[i]);
      dd[i] = d;
      int q = (int)(d * 256.0f);
      q = q < 0 ? 0 : (q > 511 ? 511 : q);
      qq[i] = q;
      atomicAdd(&hist[q], 1u);
    }
    __syncthreads();
    if (wave == 0){
      unsigned int c[8]; unsigned int tl = 0u;
      #pragma unroll
      for (int i = 0; i < 8; ++i){ c[i] = hist[lane*8 + i]; tl += c[i]; }
      unsigned int inc = tl;
      #pragma unroll
      for (int off = 1; off < 64; off <<= 1){
        unsigned int o = __shfl_up(inc, off);
        if (lane >= off) inc += o;
      }
      unsigned int base = inc - tl;          // exclusive prefix
      if (base < 32u && base + tl >= 32u){   // unique crossing lane
        unsigned int cum = base;
        #pragma unroll
        for (int i = 0; i < 8; ++i){
          unsigned int nc = cum + c[i];
          if (cum < 32u && nc >= 32u){ bB = lane*8 + i; bC0 = cum; }
          cum = nc;
        }
      }
    }
    __syncthreads();
    const int B = (int)bB; const unsigned int C0 = bC0;
    float ls = 0.0f;
    #pragma unroll
    for (int i = 0; i < 8; ++i){
      if (qq[i] < B) ls += dd[i];
      else if (qq[i] == B){
        unsigned int slot = atomicAdd(&bufcnt, 1u);
        if (slot < 128u) buf[slot] = dd[i];
      }
    }
    #pragma unroll
    for (int off = 32; off > 0; off >>= 1) ls += __shfl_xor(ls, off);
    if (lane == 0) partial[wave] = ls;
    __syncthreads();
    if (wave == 0){
      float total = partial[0] + partial[1] + partial[2] + partial[3];
      unsigned int cnt = bufcnt; if (cnt > 128u) cnt = 128u;
      float av = (lane        < (int)cnt) ? buf[lane]      : 1e30f;
      float bv = (lane + 64   < (int)cnt) ? buf[lane + 64] : 1e30f;
      int rr = 32 - (int)C0;                 // 1..32, <= cnt on sane data
      for (int it = 0; it < rr; ++it){
        float m = fminf(av, bv);
        float gm = m;
        #pragma unroll
        for (int off = 32; off > 0; off >>= 1) gm = fminf(gm, __shfl_xor(gm, off));
        total += gm;
        unsigned long long ball = __ballot(m == gm);
        int winner = (int)__ffsll(ball) - 1;
        if (lane == winner){ if (av <= bv) av = 1e30f; else bv = 1e30f; }
      }
      if (lane == 0){
        float iv = 32.0f / total;
        inv[b*NN + r] = iv;
        atomicMax(maxbits, __float_as_uint(iv));  // positive floats order as uints
      }
    }
    __syncthreads();
  }
}

__global__ void normalize_kernel(float* __restrict__ dens, const unsigned int* __restrict__ maxbits){
  int i = blockIdx.x*256 + threadIdx.x;
  float mx = __uint_as_float(*maxbits);
  dens[i] = dens[i] / mx;
}

// --------- Zinv / csinv: out[r] = 1/(Σ_m exp(s d[r] d[m]) * (w?zinv[m]:1))  (E symmetric) ---------
template<bool WEIGHTED>
__global__ __launch_bounds__(256) void zcol_kernel(const float* __restrict__ dens,
      const float* __restrict__ wqk, int K, const float* __restrict__ win,
      float* __restrict__ out){
  __shared__ float ds[NN];
  __shared__ float zs[WEIGHTED ? NN : 1];
  const int b = blockIdx.y, t = threadIdx.x;
  float s = 0.0f;
  for (int k = 0; k < K; ++k){ float w = wqk[k]; s += w*w; }
  #pragma unroll
  for (int i = 0; i < NN/256; ++i){
    ds[t + 256*i] = dens[b*NN + t + 256*i];
    if (WEIGHTED) zs[t + 256*i] = win[b*NN + t + 256*i];
  }
  __syncthreads();
  const int wave = t >> 6, lane = t & 63;
  const int RPB = NN / gridDim.x;
  const int r0 = blockIdx.x * RPB;
  for (int r = r0 + wave; r < r0 + RPB; r += 4){
    float a = s * ds[r];
    float sum = 0.0f;
    #pragma unroll
    for (int i = 0; i < NN/64; ++i){
      int m = lane + 64*i;
      float e = __expf(a * ds[m]);
      sum += WEIGHTED ? e * zs[m] : e;
    }
    #pragma unroll
    for (int off = 32; off > 0; off >>= 1) sum += __shfl_xor(sum, off);
    if (lane == 0) out[b*NN + r] = WEIGHTED ? 1.0f/(1e-9f + sum) : 1.0f/sum;
  }
}

// --------- raw[c,m] = Σ_n (x[c,n]·zinv[n]) · exp(s d[n] d[m])  — E generated in LDS ---------
template<int C>
__global__ __launch_bounds__(256) void attn_gemm_kernel(const float* __restrict__ x,
      const float* __restrict__ dens, const float* __restrict__ zinv,
      const float* __restrict__ wqk, int K, float* __restrict__ raw){
  __shared__ float xs[32][C+4];
  __shared__ float es[32][68];
  const int b = blockIdx.y, m0 = blockIdx.x*64, t = threadIdx.x;
  float s = 0.0f;
  for (int k = 0; k < K; ++k){ float w = wqk[k]; s += w*w; }
  const float* db = dens + b*NN;
  const float* zb = zinv + b*NN;
  const float* xb = x + (size_t)b*C*NN;
  const int tr = t >> 4, tc = t & 15;
  constexpr int R = C/16;
  float acc[R][4];
  #pragma unroll
  for (int i = 0; i < R; ++i){ acc[i][0]=acc[i][1]=acc[i][2]=acc[i][3]=0.0f; }
  for (int n0 = 0; n0 < NN; n0 += 32){
    __syncthreads();
    #pragma unroll
    for (int i = 0; i < C*32/256; ++i){
      int idx = t + 256*i;
      int cc = idx >> 5, k = idx & 31;
      xs[k][cc] = xb[cc*NN + n0 + k] * zb[n0 + k];
    }
    #pragma unroll
    for (int i = 0; i < 8; ++i){
      int idx = t + 256*i;
      int j = idx & 63, k = idx >> 6;
      es[k][j] = __expf(s * db[n0 + k] * db[m0 + j]);
    }
    __syncthreads();
    #pragma unroll
    for (int k = 0; k < 32; ++k){
      float4 e = *(const float4*)&es[k][tc*4];
      float a[R];
      #pragma unroll
      for (int q = 0; q < R/4; ++q)
        *(float4*)&a[q*4] = *(const float4*)&xs[k][tr*R + q*4];
      #pragma unroll
      for (int i = 0; i < R; ++i){
        acc[i][0] += a[i]*e.x; acc[i][1] += a[i]*e.y;
        acc[i][2] += a[i]*e.z; acc[i][3] += a[i]*e.w;
      }
    }
  }
  #pragma unroll
  for (int i = 0; i < R; ++i){
    int cc = tr*R + i;
    float4 v = make_float4(acc[i][0], acc[i][1], acc[i][2], acc[i][3]);
    *(float4*)&raw[((size_t)b*C + cc)*NN + m0 + tc*4] = v;
  }
}

// --------- out = x + relu(bn(wt·(x - raw·csinv) + bt)) ---------
template<int C>
__global__ __launch_bounds__(256) void attn_post_kernel(const float* __restrict__ x,
      const float* __restrict__ raw, const float* __restrict__ csinv,
      const float* __restrict__ wt, const float* __restrict__ bt,
      const float* __restrict__ bnp, float* __restrict__ out){
  __shared__ float ds[32][68];
  __shared__ float ws[32][C+4];
  const int b = blockIdx.y, m0 = blockIdx.x*64, t = threadIdx.x;
  const float* xb = x + (size_t)b*C*NN;
  const float* rb = raw + (size_t)b*C*NN;
  const float* cb = csinv + b*NN;
  const int tr = t >> 4, tc = t & 15;
  constexpr int R = C/16;
  float acc[R][4];
  #pragma unroll
  for (int i = 0; i < R; ++i){ acc[i][0]=acc[i][1]=acc[i][2]=acc[i][3]=0.0f; }
  for (int c0 = 0; c0 < C; c0 += 32){
    __syncthreads();
    #pragma unroll
    for (int i = 0; i < 8; ++i){
      int idx = t + 256*i;
      int m = idx & 63, cl = idx >> 6;
      int cc = c0 + cl;
      ds[cl][m] = xb[cc*NN + m0 + m] - rb[cc*NN + m0 + m] * cb[m0 + m];
    }
    #pragma unroll
    for (int i = 0; i < C*32/256; ++i){
      int idx = t + 256*i;
      int cl = idx & 31, o = idx >> 5;
      ws[cl][o] = wt[o*C + c0 + cl];
    }
    __syncthreads();
    #pragma unroll
    for (int k = 0; k < 32; ++k){
      float4 e = *(const float4*)&ds[k][tc*4];
      float a[R];
      #pragma unroll
      for (int q = 0; q < R/4; ++q)
        *(float4*)&a[q*4] = *(const float4*)&ws[k][tr*R + q*4];
      #pragma unroll
      for (int i = 0; i < R; ++i){
        acc[i][0] += a[i]*e.x; acc[i][1] += a[i]*e.y;
        acc[i][2] += a[i]*e.z; acc[i][3] += a[i]*e.w;
      }
    }
  }
  #pragma unroll
  for (int i = 0; i < R; ++i){
    int o = tr*R + i;
    float g = bnp[o], be = bnp[C+o], mn = bnp[2*C+o], vv = bnp[3*C+o];
    float sc = g * rsqrtf(vv + BN_EPS_);
    float sh = be - mn*sc;
    float bv = bt[o];
    float4 r;
    float* rp = &r.x;
    #pragma unroll
    for (int j = 0; j < 4; ++j){
      float y = acc[i][j] + bv;
      y = sc*y + sh;
      y = fmaxf(y, 0.0f);
      rp[j] = xb[o*NN + m0 + tc*4 + j] + y;
    }
    *(float4*)&out[((size_t)b*C + o)*NN + m0 + tc*4] = r;
  }
}

// --------- out = relu(bn(w·x)) ---------
template<int CIN, int COUT>
__global__ __launch_bounds__(256) void conv_bn_relu_kernel(const float* __restrict__ x,
      const float* __restrict__ w, const float* __restrict__ bnp, float* __restrict__ out){
  constexpr int CH = (CIN < 32) ? CIN : 32;
  __shared__ float xs[CH][68];
  __shared__ float ws[CH][COUT+4];
  const int b = blockIdx.y, m0 = blockIdx.x*64, t = threadIdx.x;
  const float* xb = x + (size_t)b*CIN*NN;
  const int tr = t >> 4, tc = t & 15;
  constexpr int R = COUT/16;
  float acc[R][4];
  #pragma unroll
  for (int i = 0; i < R; ++i){ acc[i][0]=acc[i][1]=acc[i][2]=acc[i][3]=0.0f; }
  for (int c0 = 0; c0 < CIN; c0 += CH){
    __syncthreads();
    for (int idx = t; idx < CH*64; idx += 256){
      int m = idx & 63, cl = idx >> 6;
      xs[cl][m] = xb[(c0+cl)*NN + m0 + m];
    }
    for (int idx = t; idx < CH*COUT; idx += 256){
      int cl = idx % CH, o = idx / CH;
      ws[cl][o] = w[o*CIN + c0 + cl];
    }
    __syncthreads();
    #pragma unroll
    for (int k = 0; k < CH; ++k){
      float4 e = *(const float4*)&xs[k][tc*4];
      float a[R];
      #pragma unroll
      for (int q = 0; q < R/4; ++q)
        *(float4*)&a[q*4] = *(const float4*)&ws[k][tr*R + q*4];
      #pragma unroll
      for (int i = 0; i < R; ++i){
        acc[i][0] += a[i]*e.x; acc[i][1] += a[i]*e.y;
        acc[i][2] += a[i]*e.z; acc[i][3] += a[i]*e.w;
      }
    }
  }
  #pragma unroll
  for (int i = 0; i < R; ++i){
    int o = tr*R + i;
    float g = bnp[o], be = bnp[COUT+o], mn = bnp[2*COUT+o], vv = bnp[3*COUT+o];
    float sc = g * rsqrtf(vv + BN_EPS_);
    float sh = be - mn*sc;
    float4 r;
    float* rp = &r.x;
    #pragma unroll
    for (int j = 0; j < 4; ++j){
      float y = sc*acc[i][j] + sh;
      rp[j] = fmaxf(y, 0.0f);
    }
    *(float4*)&out[((size_t)b*COUT + o)*NN + m0 + tc*4] = r;
  }
}

// --------- pooled[b,o] = max_n relu(bn(Σ_c w5[o,c] h[c,n]))  (h5 never materialized) ---------
__global__ __launch_bounds__(256) void conv5_pool_kernel(const float* __restrict__ h,
      const float* __restrict__ w5, const float* __restrict__ bnp, float* __restrict__ pooled){
  __shared__ float ws[128][68];
  __shared__ float hs[128][68];
  const int b = blockIdx.y, o0 = blockIdx.x*64, t = threadIdx.x;
  const float* hb = h + (size_t)b*128*NN;
  #pragma unroll
  for (int i = 0; i < 32; ++i){
    int idx = t + 256*i;
    int cc = idx & 127, ol = idx >> 7;
    ws[cc][ol] = w5[(o0+ol)*128 + cc];
  }
  const int tr = t >> 4, tc = t & 15;
  float sc[4], sh[4];
  #pragma unroll
  for (int i = 0; i < 4; ++i){
    int o = o0 + tr*4 + i;
    float g = bnp[o], be = bnp[1024+o], mn = bnp[2*1024+o], vv = bnp[3*1024+o];
    sc[i] = g * rsqrtf(vv + BN_EPS_);
    sh[i] = be - mn*sc[i];
  }
  float vmax[4] = {0.f,0.f,0.f,0.f};   // relu output >= 0, so 0 is a safe identity
  for (int n0 = 0; n0 < NN; n0 += 64){
    __syncthreads();
    #pragma unroll
    for (int i = 0; i < 32; ++i){
      int idx = t + 256*i;
      int nl = idx & 63, cc = idx >> 6;
      hs[cc][nl] = hb[cc*NN + n0 + nl];
    }
    __syncthreads();
    float acc[4][4];
    #pragma unroll
    for (int i = 0; i < 4; ++i){ acc[i][0]=acc[i][1]=acc[i][2]=acc[i][3]=0.0f; }
    #pragma unroll 8
    for (int k = 0; k < 128; ++k){
      float4 a = *(const float4*)&ws[k][tr*4];
      float4 e = *(const float4*)&hs[k][tc*4];
      acc[0][0]+=a.x*e.x; acc[0][1]+=a.x*e.y; acc[0][2]+=a.x*e.z; acc[0][3]+=a.x*e.w;
      acc[1][0]+=a.y*e.x; acc[1][1]+=a.y*e.y; acc[1][2]+=a.y*e.z; acc[1][3]+=a.y*e.w;
      acc[2][0]+=a.z*e.x; acc[2][1]+=a.z*e.y; acc[2][2]+=a.z*e.z; acc[2][3]+=a.z*e.w;
      acc[3][0]+=a.w*e.x; acc[3][1]+=a.w*e.y; acc[3][2]+=a.w*e.z; acc[3][3]+=a.w*e.w;
    }
    #pragma unroll
    for (int i = 0; i < 4; ++i){
      #pragma unroll
      for (int j = 0; j < 4; ++j){
        float y = sc[i]*acc[i][j] + sh[i];
        y = fmaxf(y, 0.0f);
        vmax[i] = fmaxf(vmax[i], y);
      }
    }
  }
  #pragma unroll
  for (int i = 0; i < 4; ++i){
    float v = vmax[i];
    v = fmaxf(v, __shfl_xor(v, 1));
    v = fmaxf(v, __shfl_xor(v, 2));
    v = fmaxf(v, __shfl_xor(v, 4));
    v = fmaxf(v, __shfl_xor(v, 8));
    if (tc == 0) pooled[b*1024 + o0 + tr*4 + i] = v;
  }
}

// --------- lin1 + bn6 + relu ---------
__global__ void lin1_kernel(const float* __restrict__ pooled, const float* __restrict__ w,
      const float* __restrict__ bnp, float* __restrict__ out1){
  int tid = blockIdx.x*256 + threadIdx.x;   // 8192 threads
  int b = tid >> 9, j = tid & 511;
  const float4* p4 = (const float4*)(pooled + b*1024);
  const float4* w4 = (const float4*)(w + j*1024);
  float sum = 0.0f;
  for (int e = 0; e < 256; ++e){
    float4 a = p4[e], c = w4[e];
    sum += a.x*c.x + a.y*c.y + a.z*c.z + a.w*c.w;
  }
  float g = bnp[j], be = bnp[512+j], mn = bnp[2*512+j], vv = bnp[3*512+j];
  float s = g * rsqrtf(vv + BN_EPS_);
  float y = s*sum + (be - mn*s);
  out1[b*512 + j] = fmaxf(y, 0.0f);
}

// --------- lin2 ---------
__global__ void lin2_kernel(const float* __restrict__ h, const float* __restrict__ w,
      const float* __restrict__ bias, float* __restrict__ out){
  int tid = blockIdx.x*64 + threadIdx.x;
  if (tid >= 640) return;
  int b = tid / 40, k = tid % 40;
  const float4* h4 = (const float4*)(h + b*512);
  const float4* w4 = (const float4*)(w + k*512);
  float sum = 0.0f;
  for (int e = 0; e < 128; ++e){
    float4 a = h4[e], c = w4[e];
    sum += a.x*c.x + a.y*c.y + a.z*c.z + a.w*c.w;
  }
  out[tid] = sum + bias[k];
}

extern "C" void kernel_launch(void* const* d_in, const int* in_sizes, int n_in,
                              void* d_out, int out_size, void* d_ws, size_t ws_size,
                              hipStream_t stream){
  (void)in_sizes; (void)n_in; (void)out_size; (void)ws_size;
  const float* x     = (const float*)d_in[0];
  const float* w1    = (const float*)d_in[1];
  const float* w2    = (const float*)d_in[2];
  const float* w3    = (const float*)d_in[3];
  const float* w4    = (const float*)d_in[4];
  const float* w5    = (const float*)d_in[5];
  const float* bn1   = (const float*)d_in[6];
  const float* bn2   = (const float*)d_in[7];
  const float* bn3   = (const float*)d_in[8];
  const float* bn4   = (const float*)d_in[9];
  const float* bn5   = (const float*)d_in[10];
  const float* da_wqk[4] = {(const float*)d_in[11], (const float*)d_in[15], (const float*)d_in[19], (const float*)d_in[23]};
  const float* da_wt[4]  = {(const float*)d_in[12], (const float*)d_in[16], (const float*)d_in[20], (const float*)d_in[24]};
  const float* da_bt[4]  = {(const float*)d_in[13], (const float*)d_in[17], (const float*)d_in[21], (const float*)d_in[25]};
  const float* da_bn[4]  = {(const float*)d_in[14], (const float*)d_in[18], (const float*)d_in[22], (const float*)d_in[26]};
  const float* lin1_w = (const float*)d_in[27];
  const float* bn6    = (const float*)d_in[28];
  const float* lin2_w = (const float*)d_in[29];
  const float* lin2_b = (const float*)d_in[30];

  float* ws = (float*)d_ws;
  unsigned int* maxbits = (unsigned int*)ws;
  float* dens   = ws + 64;
  float* zinv   = dens + BB*NN;
  float* csinv  = zinv + BB*NN;
  float* hA     = csinv + BB*NN;
  float* hB     = hA  + (size_t)BB*64*NN;
  float* h4A    = hB  + (size_t)BB*64*NN;
  float* raw    = h4A + (size_t)BB*128*NN;
  float* pooled = raw + (size_t)BB*128*NN;
  float* l1o    = pooled + BB*1024;
  float* uvec   = l1o + BB*512;
  float* h4B    = hA;   // attn4 output reuses the (hA|hB) region: 16*128*2048 floats

  hipMemsetAsync(maxbits, 0, sizeof(unsigned int), stream);
  normalize_points_kernel<<<dim3(BB*NN/256), 256, 0, stream>>>(x, uvec);
  density3_kernel<<<dim3(NN/DROWS, BB), 256, 0, stream>>>(uvec, dens, maxbits);
  normalize_kernel<<<dim3(BB*NN/256), 256, 0, stream>>>(dens, maxbits);

  conv_bn_relu_kernel<3,64><<<dim3(32,BB),256,0,stream>>>(x, w1, bn1, hA);

  // attn1: hA -> hB
  zcol_kernel<false><<<dim3(32,BB),256,0,stream>>>(dens, da_wqk[0], 16, nullptr, zinv);
  zcol_kernel<true ><<<dim3(32,BB),256,0,stream>>>(dens, da_wqk[0], 16, zinv, csinv);
  attn_gemm_kernel<64><<<dim3(32,BB),256,0,stream>>>(hA, dens, zinv, da_wqk[0], 16, raw);
  attn_post_kernel<64><<<dim3(32,BB),256,0,stream>>>(hA, raw, csinv, da_wt[0], da_bt[0], da_bn[0], hB);

  conv_bn_relu_kernel<64,64><<<dim3(32,BB),256,0,stream>>>(hB, w2, bn2, hA);

  // attn2: hA -> hB
  zcol_kernel<false><<<dim3(32,BB),256,0,stream>>>(dens, da_wqk[1], 16, nullptr, zinv);
  zcol_kernel<true ><<<dim3(32,BB),256,0,stream>>>(dens, da_wqk[1], 16, zinv, csinv);
  attn_gemm_kernel<64><<<dim3(32,BB),256,0,stream>>>(hA, dens, zinv, da_wqk[1], 16, raw);
  attn_post_kernel<64><<<dim3(32,BB),256,0,stream>>>(hA, raw, csinv, da_wt[1], da_bt[1], da_bn[1], hB);

  conv_bn_relu_kernel<64,64><<<dim3(32,BB),256,0,stream>>>(hB, w3, bn3, hA);

  // attn3: hA -> hB
  zcol_kernel<false><<<dim3(32,BB),256,0,stream>>>(dens, da_wqk[2], 16, nullptr, zinv);
  zcol_kernel<true ><<<dim3(32,BB),256,0,stream>>>(dens, da_wqk[2], 16, zinv, csinv);
  attn_gemm_kernel<64><<<dim3(32,BB),256,0,stream>>>(hA, dens, zinv, da_wqk[2], 16, raw);
  attn_post_kernel<64><<<dim3(32,BB),256,0,stream>>>(hA, raw, csinv, da_wt[2], da_bt[2], da_bn[2], hB);

  conv_bn_relu_kernel<64,128><<<dim3(32,BB),256,0,stream>>>(hB, w4, bn4, h4A);

  // attn4 (C=128): h4A -> h4B
  zcol_kernel<false><<<dim3(32,BB),256,0,stream>>>(dens, da_wqk[3], 32, nullptr, zinv);
  zcol_kernel<true ><<<dim3(32,BB),256,0,stream>>>(dens, da_wqk[3], 32, zinv, csinv);
  attn_gemm_kernel<128><<<dim3(32,BB),256,0,stream>>>(h4A, dens, zinv, da_wqk[3], 32, raw);
  attn_post_kernel<128><<<dim3(32,BB),256,0,stream>>>(h4A, raw, csinv, da_wt[3], da_bt[3], da_bn[3], h4B);

  conv5_pool_kernel<<<dim3(16,BB),256,0,stream>>>(h4B, w5, bn5, pooled);
  lin1_kernel<<<dim3(32),256,0,stream>>>(pooled, lin1_w, bn6, l1o);
  lin2_kernel<<<dim3(10),64,0,stream>>>(l1o, lin2_w, lin2_b, (float*)d_out);
}

// Round 4
// 1450.758 us; speedup vs baseline: 1.1071x; 1.0029x over previous
//
#include <hip/hip_runtime.h>
#include <math.h>

#define BB 16
#define NN 2048
#define BN_EPS_ 1e-5f

// ---------------- normalize points once: u[b][3][n] = xyz/|xyz| ----------------
__global__ __launch_bounds__(256) void normalize_points_kernel(const float* __restrict__ x,
        float* __restrict__ u){
  int idx = blockIdx.x*256 + threadIdx.x;     // BB*NN threads
  int b = idx >> 11, n = idx & (NN-1);
  const float* xb = x + (size_t)b*3*NN;
  float x0 = xb[n], x1 = xb[NN+n], x2 = xb[2*NN+n];
  float rn = rsqrtf(x0*x0 + x1*x1 + x2*x2);
  float* ub = u + (size_t)b*3*NN;
  ub[n] = x0*rn; ub[NN+n] = x1*rn; ub[2*NN+n] = x2*rn;
}

// ---------------- density via batched histogram rank-select ----------------
// inv[b,n] = 32 / (sum of 32 smallest cos-dists of row n).
// 8 rows per block, all phases batched: 4 barriers total, all 4 waves busy in every phase.
#define DG 8
__global__ __launch_bounds__(256) void density4_kernel(const float* __restrict__ u,
        float* __restrict__ inv, unsigned int* __restrict__ maxbits){
  __shared__ float us0[NN], us1[NN], us2[NN];      // 24 KiB
  __shared__ unsigned int hist[DG][256];           // 8 KiB
  __shared__ float buf[DG][128];                   // 4 KiB
  __shared__ unsigned int bufcnt[DG];
  __shared__ unsigned int bB[DG], bC0[DG];
  __shared__ float partial[DG][4];
  const int b = blockIdx.y;
  const float* ub = u + (size_t)b*3*NN;
  const int t = threadIdx.x;
  #pragma unroll
  for (int i = 0; i < NN/(256*4); ++i){
    int n4 = t + 256*i;
    ((float4*)us0)[n4] = ((const float4*)ub)[n4];
    ((float4*)us1)[n4] = ((const float4*)(ub+NN))[n4];
    ((float4*)us2)[n4] = ((const float4*)(ub+2*NN))[n4];
  }
  #pragma unroll
  for (int i = 0; i < DG; ++i) hist[i][t & 255] = 0u;   // 8*256 entries, t covers 256
  if (t < DG) bufcnt[t] = 0u;
  __syncthreads();
  // hoist this thread's column strip + the block's 8 row headers into registers
  float m0[8], m1[8], m2[8];
  #pragma unroll
  for (int i = 0; i < 8; ++i){
    int c = t + 256*i;
    m0[i] = us0[c]; m1[i] = us1[c]; m2[i] = us2[c];
  }
  const int r0 = blockIdx.x * DG;
  float ru0[DG], ru1[DG], ru2[DG];
  #pragma unroll
  for (int j = 0; j < DG; ++j){ ru0[j] = us0[r0+j]; ru1[j] = us1[r0+j]; ru2[j] = us2[r0+j]; }

  // phase 1: histogram all 8 rows; pack bin ids (8 bits each) for exact reuse in phase 3
  unsigned qp[DG][2];
  #pragma unroll
  for (int j = 0; j < DG; ++j){
    unsigned q0 = 0u, q1 = 0u;
    #pragma unroll
    for (int i = 0; i < 8; ++i){
      float d = 1.0f - (ru0[j]*m0[i] + ru1[j]*m1[i] + ru2[j]*m2[i]);
      int q = (int)(d * 128.0f);
      q = q < 0 ? 0 : (q > 255 ? 255 : q);
      if (i < 4) q0 |= (unsigned)q << (8*i); else q1 |= (unsigned)q << (8*(i-4));
      atomicAdd(&hist[j][q], 1u);
    }
    qp[j][0] = q0; qp[j][1] = q1;
  }
  __syncthreads();

  const int wave = t >> 6, lane = t & 63;
  // phase 2: wave w scans histograms of rows 2w, 2w+1 (4 bins/lane, shfl prefix)
  #pragma unroll
  for (int jj = 0; jj < 2; ++jj){
    const int j = 2*wave + jj;
    uint4 cc = *(const uint4*)&hist[j][lane*4];
    unsigned tl = cc.x + cc.y + cc.z + cc.w;
    unsigned inc = tl;
    #pragma unroll
    for (int off = 1; off < 64; off <<= 1){
      unsigned o = __shfl_up(inc, off);
      if (lane >= off) inc += o;
    }
    unsigned base = inc - tl;                 // exclusive prefix
    if (base < 32u && base + tl >= 32u){      // unique crossing lane
      unsigned cum = base;
      if (cum < 32u && cum + cc.x >= 32u){ bB[j] = lane*4 + 0; bC0[j] = cum; } cum += cc.x;
      if (cum < 32u && cum + cc.y >= 32u){ bB[j] = lane*4 + 1; bC0[j] = cum; } cum += cc.y;
      if (cum < 32u && cum + cc.z >= 32u){ bB[j] = lane*4 + 2; bC0[j] = cum; } cum += cc.z;
      if (cum < 32u && cum + cc.w >= 32u){ bB[j] = lane*4 + 3; bC0[j] = cum; } cum += cc.w;
    }
  }
  __syncthreads();

  // phase 3: per-row sum of below-B values + candidate spill (q == B)
  #pragma unroll
  for (int j = 0; j < DG; ++j){
    const int B = (int)bB[j];
    float s = 0.0f;
    #pragma unroll
    for (int i = 0; i < 8; ++i){
      float d = 1.0f - (ru0[j]*m0[i] + ru1[j]*m1[i] + ru2[j]*m2[i]);
      const int q = (int)((qp[j][i>>2] >> (8*(i&3))) & 255u);
      if (q < B) s += d;
      else if (q == B){
        unsigned slot = atomicAdd(&bufcnt[j], 1u);
        if (slot < 128u) buf[j][slot] = d;
      }
    }
    #pragma unroll
    for (int off = 32; off > 0; off >>= 1) s += __shfl_xor(s, off);
    if (lane == 0) partial[j][wave] = s;
  }
  __syncthreads();

  // phase 4: wave w finishes rows 2w, 2w+1 — rank-by-counting selection of rr smallest
  #pragma unroll
  for (int jj = 0; jj < 2; ++jj){
    const int j = 2*wave + jj;
    float total = partial[j][0] + partial[j][1] + partial[j][2] + partial[j][3];
    int cnt = (int)bufcnt[j]; if (cnt > 128) cnt = 128;
    const int rr = 32 - (int)bC0[j];
    float v1 = (lane      < cnt) ? buf[j][lane]      : 0.0f;
    float v2 = (lane + 64 < cnt) ? buf[j][lane + 64] : 0.0f;
    int rk1 = 0, rk2 = 0;
    for (int k = 0; k < cnt; ++k){
      float vk = buf[j][k];
      rk1 += ((vk < v1) || (vk == v1 && k < lane)) ? 1 : 0;
      rk2 += ((vk < v2) || (vk == v2 && k < lane + 64)) ? 1 : 0;
    }
    float contrib = ((lane      < cnt) && (rk1 < rr)) ? v1 : 0.0f;
    contrib      += ((lane + 64 < cnt) && (rk2 < rr)) ? v2 : 0.0f;
    #pragma unroll
    for (int off = 32; off > 0; off >>= 1) contrib += __shfl_xor(contrib, off);
    total += contrib;
    if (lane == 0){
      float iv = 32.0f / total;
      inv[b*NN + r0 + j] = iv;
      atomicMax(maxbits, __float_as_uint(iv));  // positive floats order as uints
    }
  }
}

__global__ void normalize_kernel(float* __restrict__ dens, const unsigned int* __restrict__ maxbits){
  int i = blockIdx.x*256 + threadIdx.x;
  float mx = __uint_as_float(*maxbits);
  dens[i] = dens[i] / mx;
}

// --------- Zinv / csinv: out[r] = 1/(Σ_m exp(s d[r] d[m]) * (w?zinv[m]:1))  (E symmetric) ---------
template<bool WEIGHTED>
__global__ __launch_bounds__(256) void zcol_kernel(const float* __restrict__ dens,
      const float* __restrict__ wqk, int K, const float* __restrict__ win,
      float* __restrict__ out){
  __shared__ float ds[NN];
  __shared__ float zs[WEIGHTED ? NN : 1];
  const int b = blockIdx.y, t = threadIdx.x;
  float s = 0.0f;
  for (int k = 0; k < K; ++k){ float w = wqk[k]; s += w*w; }
  #pragma unroll
  for (int i = 0; i < NN/256; ++i){
    ds[t + 256*i] = dens[b*NN + t + 256*i];
    if (WEIGHTED) zs[t + 256*i] = win[b*NN + t + 256*i];
  }
  __syncthreads();
  const int wave = t >> 6, lane = t & 63;
  const int RPB = NN / gridDim.x;
  const int r0 = blockIdx.x * RPB;
  for (int r = r0 + wave; r < r0 + RPB; r += 4){
    float a = s * ds[r];
    float sum = 0.0f;
    #pragma unroll
    for (int i = 0; i < NN/64; ++i){
      int m = lane + 64*i;
      float e = __expf(a * ds[m]);
      sum += WEIGHTED ? e * zs[m] : e;
    }
    #pragma unroll
    for (int off = 32; off > 0; off >>= 1) sum += __shfl_xor(sum, off);
    if (lane == 0) out[b*NN + r] = WEIGHTED ? 1.0f/(1e-9f + sum) : 1.0f/sum;
  }
}

// --------- raw[c,m] = Σ_n (x[c,n]·zinv[n]) · exp(s d[n] d[m])  — E generated in LDS ---------
template<int C>
__global__ __launch_bounds__(256) void attn_gemm_kernel(const float* __restrict__ x,
      const float* __restrict__ dens, const float* __restrict__ zinv,
      const float* __restrict__ wqk, int K, float* __restrict__ raw){
  __shared__ float xs[32][C+4];
  __shared__ float es[32][68];
  const int b = blockIdx.y, m0 = blockIdx.x*64, t = threadIdx.x;
  float s = 0.0f;
  for (int k = 0; k < K; ++k){ float w = wqk[k]; s += w*w; }
  const float* db = dens + b*NN;
  const float* zb = zinv + b*NN;
  const float* xb = x + (size_t)b*C*NN;
  const int tr = t >> 4, tc = t & 15;
  constexpr int R = C/16;
  float acc[R][4];
  #pragma unroll
  for (int i = 0; i < R; ++i){ acc[i][0]=acc[i][1]=acc[i][2]=acc[i][3]=0.0f; }
  for (int n0 = 0; n0 < NN; n0 += 32){
    __syncthreads();
    #pragma unroll
    for (int i = 0; i < C*32/256; ++i){
      int idx = t + 256*i;
      int cc = idx >> 5, k = idx & 31;
      xs[k][cc] = xb[cc*NN + n0 + k] * zb[n0 + k];
    }
    #pragma unroll
    for (int i = 0; i < 8; ++i){
      int idx = t + 256*i;
      int j = idx & 63, k = idx >> 6;
      es[k][j] = __expf(s * db[n0 + k] * db[m0 + j]);
    }
    __syncthreads();
    #pragma unroll
    for (int k = 0; k < 32; ++k){
      float4 e = *(const float4*)&es[k][tc*4];
      float a[R];
      #pragma unroll
      for (int q = 0; q < R/4; ++q)
        *(float4*)&a[q*4] = *(const float4*)&xs[k][tr*R + q*4];
      #pragma unroll
      for (int i = 0; i < R; ++i){
        acc[i][0] += a[i]*e.x; acc[i][1] += a[i]*e.y;
        acc[i][2] += a[i]*e.z; acc[i][3] += a[i]*e.w;
      }
    }
  }
  #pragma unroll
  for (int i = 0; i < R; ++i){
    int cc = tr*R + i;
    float4 v = make_float4(acc[i][0], acc[i][1], acc[i][2], acc[i][3]);
    *(float4*)&raw[((size_t)b*C + cc)*NN + m0 + tc*4] = v;
  }
}

// --------- out = x + relu(bn(wt·(x - raw·csinv) + bt)) ---------
template<int C>
__global__ __launch_bounds__(256) void attn_post_kernel(const float* __restrict__ x,
      const float* __restrict__ raw, const float* __restrict__ csinv,
      const float* __restrict__ wt, const float* __restrict__ bt,
      const float* __restrict__ bnp, float* __restrict__ out){
  __shared__ float ds[32][68];
  __shared__ float ws[32][C+4];
  const int b = blockIdx.y, m0 = blockIdx.x*64, t = threadIdx.x;
  const float* xb = x + (size_t)b*C*NN;
  const float* rb = raw + (size_t)b*C*NN;
  const float* cb = csinv + b*NN;
  const int tr = t >> 4, tc = t & 15;
  constexpr int R = C/16;
  float acc[R][4];
  #pragma unroll
  for (int i = 0; i < R; ++i){ acc[i][0]=acc[i][1]=acc[i][2]=acc[i][3]=0.0f; }
  for (int c0 = 0; c0 < C; c0 += 32){
    __syncthreads();
    #pragma unroll
    for (int i = 0; i < 8; ++i){
      int idx = t + 256*i;
      int m = idx & 63, cl = idx >> 6;
      int cc = c0 + cl;
      ds[cl][m] = xb[cc*NN + m0 + m] - rb[cc*NN + m0 + m] * cb[m0 + m];
    }
    #pragma unroll
    for (int i = 0; i < C*32/256; ++i){
      int idx = t + 256*i;
      int cl = idx & 31, o = idx >> 5;
      ws[cl][o] = wt[o*C + c0 + cl];
    }
    __syncthreads();
    #pragma unroll
    for (int k = 0; k < 32; ++k){
      float4 e = *(const float4*)&ds[k][tc*4];
      float a[R];
      #pragma unroll
      for (int q = 0; q < R/4; ++q)
        *(float4*)&a[q*4] = *(const float4*)&ws[k][tr*R + q*4];
      #pragma unroll
      for (int i = 0; i < R; ++i){
        acc[i][0] += a[i]*e.x; acc[i][1] += a[i]*e.y;
        acc[i][2] += a[i]*e.z; acc[i][3] += a[i]*e.w;
      }
    }
  }
  #pragma unroll
  for (int i = 0; i < R; ++i){
    int o = tr*R + i;
    float g = bnp[o], be = bnp[C+o], mn = bnp[2*C+o], vv = bnp[3*C+o];
    float sc = g * rsqrtf(vv + BN_EPS_);
    float sh = be - mn*sc;
    float bv = bt[o];
    float4 r;
    float* rp = &r.x;
    #pragma unroll
    for (int j = 0; j < 4; ++j){
      float y = acc[i][j] + bv;
      y = sc*y + sh;
      y = fmaxf(y, 0.0f);
      rp[j] = xb[o*NN + m0 + tc*4 + j] + y;
    }
    *(float4*)&out[((size_t)b*C + o)*NN + m0 + tc*4] = r;
  }
}

// --------- out = relu(bn(w·x)) ---------
template<int CIN, int COUT>
__global__ __launch_bounds__(256) void conv_bn_relu_kernel(const float* __restrict__ x,
      const float* __restrict__ w, const float* __restrict__ bnp, float* __restrict__ out){
  constexpr int CH = (CIN < 32) ? CIN : 32;
  __shared__ float xs[CH][68];
  __shared__ float ws[CH][COUT+4];
  const int b = blockIdx.y, m0 = blockIdx.x*64, t = threadIdx.x;
  const float* xb = x + (size_t)b*CIN*NN;
  const int tr = t >> 4, tc = t & 15;
  constexpr int R = COUT/16;
  float acc[R][4];
  #pragma unroll
  for (int i = 0; i < R; ++i){ acc[i][0]=acc[i][1]=acc[i][2]=acc[i][3]=0.0f; }
  for (int c0 = 0; c0 < CIN; c0 += CH){
    __syncthreads();
    for (int idx = t; idx < CH*64; idx += 256){
      int m = idx & 63, cl = idx >> 6;
      xs[cl][m] = xb[(c0+cl)*NN + m0 + m];
    }
    for (int idx = t; idx < CH*COUT; idx += 256){
      int cl = idx % CH, o = idx / CH;
      ws[cl][o] = w[o*CIN + c0 + cl];
    }
    __syncthreads();
    #pragma unroll
    for (int k = 0; k < CH; ++k){
      float4 e = *(const float4*)&xs[k][tc*4];
      float a[R];
      #pragma unroll
      for (int q = 0; q < R/4; ++q)
        *(float4*)&a[q*4] = *(const float4*)&ws[k][tr*R + q*4];
      #pragma unroll
      for (int i = 0; i < R; ++i){
        acc[i][0] += a[i]*e.x; acc[i][1] += a[i]*e.y;
        acc[i][2] += a[i]*e.z; acc[i][3] += a[i]*e.w;
      }
    }
  }
  #pragma unroll
  for (int i = 0; i < R; ++i){
    int o = tr*R + i;
    float g = bnp[o], be = bnp[COUT+o], mn = bnp[2*COUT+o], vv = bnp[3*COUT+o];
    float sc = g * rsqrtf(vv + BN_EPS_);
    float sh = be - mn*sc;
    float4 r;
    float* rp = &r.x;
    #pragma unroll
    for (int j = 0; j < 4; ++j){
      float y = sc*acc[i][j] + sh;
      rp[j] = fmaxf(y, 0.0f);
    }
    *(float4*)&out[((size_t)b*COUT + o)*NN + m0 + tc*4] = r;
  }
}

// --------- pooled[b,o] = max_n relu(bn(Σ_c w5[o,c] h[c,n]))  (h5 never materialized) ---------
__global__ __launch_bounds__(256) void conv5_pool_kernel(const float* __restrict__ h,
      const float* __restrict__ w5, const float* __restrict__ bnp, float* __restrict__ pooled){
  __shared__ float ws[128][68];
  __shared__ float hs[128][68];
  const int b = blockIdx.y, o0 = blockIdx.x*64, t = threadIdx.x;
  const float* hb = h + (size_t)b*128*NN;
  #pragma unroll
  for (int i = 0; i < 32; ++i){
    int idx = t + 256*i;
    int cc = idx & 127, ol = idx >> 7;
    ws[cc][ol] = w5[(o0+ol)*128 + cc];
  }
  const int tr = t >> 4, tc = t & 15;
  float sc[4], sh[4];
  #pragma unroll
  for (int i = 0; i < 4; ++i){
    int o = o0 + tr*4 + i;
    float g = bnp[o], be = bnp[1024+o], mn = bnp[2*1024+o], vv = bnp[3*1024+o];
    sc[i] = g * rsqrtf(vv + BN_EPS_);
    sh[i] = be - mn*sc[i];
  }
  float vmax[4] = {0.f,0.f,0.f,0.f};   // relu output >= 0, so 0 is a safe identity
  for (int n0 = 0; n0 < NN; n0 += 64){
    __syncthreads();
    #pragma unroll
    for (int i = 0; i < 32; ++i){
      int idx = t + 256*i;
      int nl = idx & 63, cc = idx >> 6;
      hs[cc][nl] = hb[cc*NN + n0 + nl];
    }
    __syncthreads();
    float acc[4][4];
    #pragma unroll
    for (int i = 0; i < 4; ++i){ acc[i][0]=acc[i][1]=acc[i][2]=acc[i][3]=0.0f; }
    #pragma unroll 8
    for (int k = 0; k < 128; ++k){
      float4 a = *(const float4*)&ws[k][tr*4];
      float4 e = *(const float4*)&hs[k][tc*4];
      acc[0][0]+=a.x*e.x; acc[0][1]+=a.x*e.y; acc[0][2]+=a.x*e.z; acc[0][3]+=a.x*e.w;
      acc[1][0]+=a.y*e.x; acc[1][1]+=a.y*e.y; acc[1][2]+=a.y*e.z; acc[1][3]+=a.y*e.w;
      acc[2][0]+=a.z*e.x; acc[2][1]+=a.z*e.y; acc[2][2]+=a.z*e.z; acc[2][3]+=a.z*e.w;
      acc[3][0]+=a.w*e.x; acc[3][1]+=a.w*e.y; acc[3][2]+=a.w*e.z; acc[3][3]+=a.w*e.w;
    }
    #pragma unroll
    for (int i = 0; i < 4; ++i){
      #pragma unroll
      for (int j = 0; j < 4; ++j){
        float y = sc[i]*acc[i][j] + sh[i];
        y = fmaxf(y, 0.0f);
        vmax[i] = fmaxf(vmax[i], y);
      }
    }
  }
  #pragma unroll
  for (int i = 0; i < 4; ++i){
    float v = vmax[i];
    v = fmaxf(v, __shfl_xor(v, 1));
    v = fmaxf(v, __shfl_xor(v, 2));
    v = fmaxf(v, __shfl_xor(v, 4));
    v = fmaxf(v, __shfl_xor(v, 8));
    if (tc == 0) pooled[b*1024 + o0 + tr*4 + i] = v;
  }
}

// --------- lin1 + bn6 + relu ---------
__global__ void lin1_kernel(const float* __restrict__ pooled, const float* __restrict__ w,
      const float* __restrict__ bnp, float* __restrict__ out1){
  int tid = blockIdx.x*256 + threadIdx.x;   // 8192 threads
  int b = tid >> 9, j = tid & 511;
  const float4* p4 = (const float4*)(pooled + b*1024);
  const float4* w4 = (const float4*)(w + j*1024);
  float sum = 0.0f;
  for (int e = 0; e < 256; ++e){
    float4 a = p4[e], c = w4[e];
    sum += a.x*c.x + a.y*c.y + a.z*c.z + a.w*c.w;
  }
  float g = bnp[j], be = bnp[512+j], mn = bnp[2*512+j], vv = bnp[3*512+j];
  float s = g * rsqrtf(vv + BN_EPS_);
  float y = s*sum + (be - mn*s);
  out1[b*512 + j] = fmaxf(y, 0.0f);
}

// --------- lin2 ---------
__global__ void lin2_kernel(const float* __restrict__ h, const float* __restrict__ w,
      const float* __restrict__ bias, float* __restrict__ out){
  int tid = blockIdx.x*64 + threadIdx.x;
  if (tid >= 640) return;
  int b = tid / 40, k = tid % 40;
  const float4* h4 = (const float4*)(h + b*512);
  const float4* w4 = (const float4*)(w + k*512);
  float sum = 0.0f;
  for (int e = 0; e < 128; ++e){
    float4 a = h4[e], c = w4[e];
    sum += a.x*c.x + a.y*c.y + a.z*c.z + a.w*c.w;
  }
  out[tid] = sum + bias[k];
}

extern "C" void kernel_launch(void* const* d_in, const int* in_sizes, int n_in,
                              void* d_out, int out_size, void* d_ws, size_t ws_size,
                              hipStream_t stream){
  (void)in_sizes; (void)n_in; (void)out_size; (void)ws_size;
  const float* x     = (const float*)d_in[0];
  const float* w1    = (const float*)d_in[1];
  const float* w2    = (const float*)d_in[2];
  const float* w3    = (const float*)d_in[3];
  const float* w4    = (const float*)d_in[4];
  const float* w5    = (const float*)d_in[5];
  const float* bn1   = (const float*)d_in[6];
  const float* bn2   = (const float*)d_in[7];
  const float* bn3   = (const float*)d_in[8];
  const float* bn4   = (const float*)d_in[9];
  const float* bn5   = (const float*)d_in[10];
  const float* da_wqk[4] = {(const float*)d_in[11], (const float*)d_in[15], (const float*)d_in[19], (const float*)d_in[23]};
  const float* da_wt[4]  = {(const float*)d_in[12], (const float*)d_in[16], (const float*)d_in[20], (const float*)d_in[24]};
  const float* da_bt[4]  = {(const float*)d_in[13], (const float*)d_in[17], (const float*)d_in[21], (const float*)d_in[25]};
  const float* da_bn[4]  = {(const float*)d_in[14], (const float*)d_in[18], (const float*)d_in[22], (const float*)d_in[26]};
  const float* lin1_w = (const float*)d_in[27];
  const float* bn6    = (const float*)d_in[28];
  const float* lin2_w = (const float*)d_in[29];
  const float* lin2_b = (const float*)d_in[30];

  float* ws = (float*)d_ws;
  unsigned int* maxbits = (unsigned int*)ws;
  float* dens   = ws + 64;
  float* zinv   = dens + BB*NN;
  float* csinv  = zinv + BB*NN;
  float* hA     = csinv + BB*NN;
  float* hB     = hA  + (size_t)BB*64*NN;
  float* h4A    = hB  + (size_t)BB*64*NN;
  float* raw    = h4A + (size_t)BB*128*NN;
  float* pooled = raw + (size_t)BB*128*NN;
  float* l1o    = pooled + BB*1024;
  float* uvec   = l1o + BB*512;
  float* h4B    = hA;   // attn4 output reuses the (hA|hB) region: 16*128*2048 floats

  hipMemsetAsync(maxbits, 0, sizeof(unsigned int), stream);
  normalize_points_kernel<<<dim3(BB*NN/256), 256, 0, stream>>>(x, uvec);
  density4_kernel<<<dim3(NN/DG, BB), 256, 0, stream>>>(uvec, dens, maxbits);
  normalize_kernel<<<dim3(BB*NN/256), 256, 0, stream>>>(dens, maxbits);

  conv_bn_relu_kernel<3,64><<<dim3(32,BB),256,0,stream>>>(x, w1, bn1, hA);

  // attn1: hA -> hB
  zcol_kernel<false><<<dim3(32,BB),256,0,stream>>>(dens, da_wqk[0], 16, nullptr, zinv);
  zcol_kernel<true ><<<dim3(32,BB),256,0,stream>>>(dens, da_wqk[0], 16, zinv, csinv);
  attn_gemm_kernel<64><<<dim3(32,BB),256,0,stream>>>(hA, dens, zinv, da_wqk[0], 16, raw);
  attn_post_kernel<64><<<dim3(32,BB),256,0,stream>>>(hA, raw, csinv, da_wt[0], da_bt[0], da_bn[0], hB);

  conv_bn_relu_kernel<64,64><<<dim3(32,BB),256,0,stream>>>(hB, w2, bn2, hA);

  // attn2: hA -> hB
  zcol_kernel<false><<<dim3(32,BB),256,0,stream>>>(dens, da_wqk[1], 16, nullptr, zinv);
  zcol_kernel<true ><<<dim3(32,BB),256,0,stream>>>(dens, da_wqk[1], 16, zinv, csinv);
  attn_gemm_kernel<64><<<dim3(32,BB),256,0,stream>>>(hA, dens, zinv, da_wqk[1], 16, raw);
  attn_post_kernel<64><<<dim3(32,BB),256,0,stream>>>(hA, raw, csinv, da_wt[1], da_bt[1], da_bn[1], hB);

  conv_bn_relu_kernel<64,64><<<dim3(32,BB),256,0,stream>>>(hB, w3, bn3, hA);

  // attn3: hA -> hB
  zcol_kernel<false><<<dim3(32,BB),256,0,stream>>>(dens, da_wqk[2], 16, nullptr, zinv);
  zcol_kernel<true ><<<dim3(32,BB),256,0,stream>>>(dens, da_wqk[2], 16, zinv, csinv);
  attn_gemm_kernel<64><<<dim3(32,BB),256,0,stream>>>(hA, dens, zinv, da_wqk[2], 16, raw);
  attn_post_kernel<64><<<dim3(32,BB),256,0,stream>>>(hA, raw, csinv, da_wt[2], da_bt[2], da_bn[2], hB);

  conv_bn_relu_kernel<64,128><<<dim3(32,BB),256,0,stream>>>(hB, w4, bn4, h4A);

  // attn4 (C=128): h4A -> h4B
  zcol_kernel<false><<<dim3(32,BB),256,0,stream>>>(dens, da_wqk[3], 32, nullptr, zinv);
  zcol_kernel<true ><<<dim3(32,BB),256,0,stream>>>(dens, da_wqk[3], 32, zinv, csinv);
  attn_gemm_kernel<128><<<dim3(32,BB),256,0,stream>>>(h4A, dens, zinv, da_wqk[3], 32, raw);
  attn_post_kernel<128><<<dim3(32,BB),256,0,stream>>>(h4A, raw, csinv, da_wt[3], da_bt[3], da_bn[3], h4B);

  conv5_pool_kernel<<<dim3(16,BB),256,0,stream>>>(h4B, w5, bn5, pooled);
  lin1_kernel<<<dim3(32),256,0,stream>>>(pooled, lin1_w, bn6, l1o);
  lin2_kernel<<<dim3(10),64,0,stream>>>(l1o, lin2_w, lin2_b, (float*)d_out);
}

// Round 5
// 1134.002 us; speedup vs baseline: 1.4164x; 1.2793x over previous
//
#include <hip/hip_runtime.h>
#include <math.h>

#define BB 16
#define NN 2048
#define BN_EPS_ 1e-5f

// ---------------- normalize points once: u[b][3][n] = xyz/|xyz| ----------------
__global__ __launch_bounds__(256) void normalize_points_kernel(const float* __restrict__ x,
        float* __restrict__ u){
  int idx = blockIdx.x*256 + threadIdx.x;     // BB*NN threads
  int b = idx >> 11, n = idx & (NN-1);
  const float* xb = x + (size_t)b*3*NN;
  float x0 = xb[n], x1 = xb[NN+n], x2 = xb[2*NN+n];
  float rn = rsqrtf(x0*x0 + x1*x1 + x2*x2);
  float* ub = u + (size_t)b*3*NN;
  ub[n] = x0*rn; ub[NN+n] = x1*rn; ub[2*NN+n] = x2*rn;
}

// ---------------- density via batched histogram rank-select ----------------
// inv[b,n] = 32 / (sum of 32 smallest cos-dists of row n).
// 8 rows per block, all phases batched. NO global atomics: per-block max -> blockmax[].
#define DG 8
__global__ __launch_bounds__(256) void density5_kernel(const float* __restrict__ u,
        float* __restrict__ inv, float* __restrict__ blockmax){
  __shared__ float us0[NN], us1[NN], us2[NN];      // 24 KiB
  __shared__ unsigned int hist[DG][256];           // 8 KiB
  __shared__ float buf[DG][128];                   // 4 KiB
  __shared__ unsigned int bufcnt[DG];
  __shared__ unsigned int bB[DG], bC0[DG];
  __shared__ float partial[DG][4];
  __shared__ float rowiv[DG];
  const int b = blockIdx.y;
  const float* ub = u + (size_t)b*3*NN;
  const int t = threadIdx.x;
  #pragma unroll
  for (int i = 0; i < NN/(256*4); ++i){
    int n4 = t + 256*i;
    ((float4*)us0)[n4] = ((const float4*)ub)[n4];
    ((float4*)us1)[n4] = ((const float4*)(ub+NN))[n4];
    ((float4*)us2)[n4] = ((const float4*)(ub+2*NN))[n4];
  }
  #pragma unroll
  for (int i = 0; i < DG; ++i) hist[i][t & 255] = 0u;
  if (t < DG) bufcnt[t] = 0u;
  __syncthreads();
  // hoist this thread's column strip + the block's 8 row headers into registers
  float m0[8], m1[8], m2[8];
  #pragma unroll
  for (int i = 0; i < 8; ++i){
    int c = t + 256*i;
    m0[i] = us0[c]; m1[i] = us1[c]; m2[i] = us2[c];
  }
  const int r0 = blockIdx.x * DG;
  float ru0[DG], ru1[DG], ru2[DG];
  #pragma unroll
  for (int j = 0; j < DG; ++j){ ru0[j] = us0[r0+j]; ru1[j] = us1[r0+j]; ru2[j] = us2[r0+j]; }

  // phase 1: histogram all 8 rows; pack bin ids (8 bits each) for exact reuse in phase 3
  unsigned qp[DG][2];
  #pragma unroll
  for (int j = 0; j < DG; ++j){
    unsigned q0 = 0u, q1 = 0u;
    #pragma unroll
    for (int i = 0; i < 8; ++i){
      float d = 1.0f - (ru0[j]*m0[i] + ru1[j]*m1[i] + ru2[j]*m2[i]);
      int q = (int)(d * 128.0f);
      q = q < 0 ? 0 : (q > 255 ? 255 : q);
      if (i < 4) q0 |= (unsigned)q << (8*i); else q1 |= (unsigned)q << (8*(i-4));
      atomicAdd(&hist[j][q], 1u);
    }
    qp[j][0] = q0; qp[j][1] = q1;
  }
  __syncthreads();

  const int wave = t >> 6, lane = t & 63;
  // phase 2: wave w scans histograms of rows 2w, 2w+1 (4 bins/lane, shfl prefix)
  #pragma unroll
  for (int jj = 0; jj < 2; ++jj){
    const int j = 2*wave + jj;
    uint4 cc = *(const uint4*)&hist[j][lane*4];
    unsigned tl = cc.x + cc.y + cc.z + cc.w;
    unsigned inc = tl;
    #pragma unroll
    for (int off = 1; off < 64; off <<= 1){
      unsigned o = __shfl_up(inc, off);
      if (lane >= off) inc += o;
    }
    unsigned base = inc - tl;                 // exclusive prefix
    if (base < 32u && base + tl >= 32u){      // unique crossing lane
      unsigned cum = base;
      if (cum < 32u && cum + cc.x >= 32u){ bB[j] = lane*4 + 0; bC0[j] = cum; } cum += cc.x;
      if (cum < 32u && cum + cc.y >= 32u){ bB[j] = lane*4 + 1; bC0[j] = cum; } cum += cc.y;
      if (cum < 32u && cum + cc.z >= 32u){ bB[j] = lane*4 + 2; bC0[j] = cum; } cum += cc.z;
      if (cum < 32u && cum + cc.w >= 32u){ bB[j] = lane*4 + 3; bC0[j] = cum; } cum += cc.w;
    }
  }
  __syncthreads();

  // phase 3: per-row sum of below-B values + candidate spill (q == B)
  #pragma unroll
  for (int j = 0; j < DG; ++j){
    const int B = (int)bB[j];
    float s = 0.0f;
    #pragma unroll
    for (int i = 0; i < 8; ++i){
      float d = 1.0f - (ru0[j]*m0[i] + ru1[j]*m1[i] + ru2[j]*m2[i]);
      const int q = (int)((qp[j][i>>2] >> (8*(i&3))) & 255u);
      if (q < B) s += d;
      else if (q == B){
        unsigned slot = atomicAdd(&bufcnt[j], 1u);
        if (slot < 128u) buf[j][slot] = d;
      }
    }
    #pragma unroll
    for (int off = 32; off > 0; off >>= 1) s += __shfl_xor(s, off);
    if (lane == 0) partial[j][wave] = s;
  }
  __syncthreads();

  // phase 4: wave w finishes rows 2w, 2w+1 — rank-by-counting selection of rr smallest
  #pragma unroll
  for (int jj = 0; jj < 2; ++jj){
    const int j = 2*wave + jj;
    float total = partial[j][0] + partial[j][1] + partial[j][2] + partial[j][3];
    int cnt = (int)bufcnt[j]; if (cnt > 128) cnt = 128;
    const int rr = 32 - (int)bC0[j];
    float v1 = (lane      < cnt) ? buf[j][lane]      : 0.0f;
    float v2 = (lane + 64 < cnt) ? buf[j][lane + 64] : 0.0f;
    int rk1 = 0, rk2 = 0;
    for (int k = 0; k < cnt; ++k){
      float vk = buf[j][k];
      rk1 += ((vk < v1) || (vk == v1 && k < lane)) ? 1 : 0;
      rk2 += ((vk < v2) || (vk == v2 && k < lane + 64)) ? 1 : 0;
    }
    float contrib = ((lane      < cnt) && (rk1 < rr)) ? v1 : 0.0f;
    contrib      += ((lane + 64 < cnt) && (rk2 < rr)) ? v2 : 0.0f;
    #pragma unroll
    for (int off = 32; off > 0; off >>= 1) contrib += __shfl_xor(contrib, off);
    total += contrib;
    if (lane == 0){
      float iv = 32.0f / total;
      inv[b*NN + r0 + j] = iv;
      rowiv[j] = iv;
    }
  }
  __syncthreads();
  if (t == 0){
    float m = rowiv[0];
    #pragma unroll
    for (int j = 1; j < DG; ++j) m = fmaxf(m, rowiv[j]);
    blockmax[blockIdx.y * gridDim.x + blockIdx.x] = m;
  }
}

// ---------------- reduce 4096 block maxima -> single max (no contended atomics) ----------------
__global__ __launch_bounds__(256) void finalize_max_kernel(const float* __restrict__ blockmax,
        float* __restrict__ maxout){
  __shared__ float pw[4];
  const int t = threadIdx.x;
  float m = 0.0f;                             // inv values are positive
  #pragma unroll
  for (int i = 0; i < 16; ++i) m = fmaxf(m, blockmax[t + 256*i]);
  #pragma unroll
  for (int off = 32; off > 0; off >>= 1) m = fmaxf(m, __shfl_xor(m, off));
  if ((t & 63) == 0) pw[t >> 6] = m;
  __syncthreads();
  if (t == 0) *maxout = fmaxf(fmaxf(pw[0], pw[1]), fmaxf(pw[2], pw[3]));
}

__global__ void normalize_kernel(float* __restrict__ dens, const float* __restrict__ maxval){
  int i = blockIdx.x*256 + threadIdx.x;
  float mx = *maxval;
  dens[i] = dens[i] / mx;
}

// --------- Zinv / csinv: out[r] = 1/(Σ_m exp(s d[r] d[m]) * (w?zinv[m]:1))  (E symmetric) ---------
template<bool WEIGHTED>
__global__ __launch_bounds__(256) void zcol_kernel(const float* __restrict__ dens,
      const float* __restrict__ wqk, int K, const float* __restrict__ win,
      float* __restrict__ out){
  __shared__ float ds[NN];
  __shared__ float zs[WEIGHTED ? NN : 1];
  const int b = blockIdx.y, t = threadIdx.x;
  float s = 0.0f;
  for (int k = 0; k < K; ++k){ float w = wqk[k]; s += w*w; }
  #pragma unroll
  for (int i = 0; i < NN/256; ++i){
    ds[t + 256*i] = dens[b*NN + t + 256*i];
    if (WEIGHTED) zs[t + 256*i] = win[b*NN + t + 256*i];
  }
  __syncthreads();
  const int wave = t >> 6, lane = t & 63;
  const int RPB = NN / gridDim.x;
  const int r0 = blockIdx.x * RPB;
  for (int r = r0 + wave; r < r0 + RPB; r += 4){
    float a = s * ds[r];
    float sum = 0.0f;
    #pragma unroll
    for (int i = 0; i < NN/64; ++i){
      int m = lane + 64*i;
      float e = __expf(a * ds[m]);
      sum += WEIGHTED ? e * zs[m] : e;
    }
    #pragma unroll
    for (int off = 32; off > 0; off >>= 1) sum += __shfl_xor(sum, off);
    if (lane == 0) out[b*NN + r] = WEIGHTED ? 1.0f/(1e-9f + sum) : 1.0f/sum;
  }
}

// --------- raw[c,m] = Σ_n (x[c,n]·zinv[n]) · exp(s d[n] d[m])  — E generated in LDS ---------
template<int C>
__global__ __launch_bounds__(256) void attn_gemm_kernel(const float* __restrict__ x,
      const float* __restrict__ dens, const float* __restrict__ zinv,
      const float* __restrict__ wqk, int K, float* __restrict__ raw){
  __shared__ float xs[32][C+4];
  __shared__ float es[32][68];
  const int b = blockIdx.y, m0 = blockIdx.x*64, t = threadIdx.x;
  float s = 0.0f;
  for (int k = 0; k < K; ++k){ float w = wqk[k]; s += w*w; }
  const float* db = dens + b*NN;
  const float* zb = zinv + b*NN;
  const float* xb = x + (size_t)b*C*NN;
  const int tr = t >> 4, tc = t & 15;
  constexpr int R = C/16;
  float acc[R][4];
  #pragma unroll
  for (int i = 0; i < R; ++i){ acc[i][0]=acc[i][1]=acc[i][2]=acc[i][3]=0.0f; }
  for (int n0 = 0; n0 < NN; n0 += 32){
    __syncthreads();
    #pragma unroll
    for (int i = 0; i < C*32/256; ++i){
      int idx = t + 256*i;
      int cc = idx >> 5, k = idx & 31;
      xs[k][cc] = xb[cc*NN + n0 + k] * zb[n0 + k];
    }
    #pragma unroll
    for (int i = 0; i < 8; ++i){
      int idx = t + 256*i;
      int j = idx & 63, k = idx >> 6;
      es[k][j] = __expf(s * db[n0 + k] * db[m0 + j]);
    }
    __syncthreads();
    #pragma unroll
    for (int k = 0; k < 32; ++k){
      float4 e = *(const float4*)&es[k][tc*4];
      float a[R];
      #pragma unroll
      for (int q = 0; q < R/4; ++q)
        *(float4*)&a[q*4] = *(const float4*)&xs[k][tr*R + q*4];
      #pragma unroll
      for (int i = 0; i < R; ++i){
        acc[i][0] += a[i]*e.x; acc[i][1] += a[i]*e.y;
        acc[i][2] += a[i]*e.z; acc[i][3] += a[i]*e.w;
      }
    }
  }
  #pragma unroll
  for (int i = 0; i < R; ++i){
    int cc = tr*R + i;
    float4 v = make_float4(acc[i][0], acc[i][1], acc[i][2], acc[i][3]);
    *(float4*)&raw[((size_t)b*C + cc)*NN + m0 + tc*4] = v;
  }
}

// --------- out = x + relu(bn(wt·(x - raw·csinv) + bt)) ---------
template<int C>
__global__ __launch_bounds__(256) void attn_post_kernel(const float* __restrict__ x,
      const float* __restrict__ raw, const float* __restrict__ csinv,
      const float* __restrict__ wt, const float* __restrict__ bt,
      const float* __restrict__ bnp, float* __restrict__ out){
  __shared__ float ds[32][68];
  __shared__ float ws[32][C+4];
  const int b = blockIdx.y, m0 = blockIdx.x*64, t = threadIdx.x;
  const float* xb = x + (size_t)b*C*NN;
  const float* rb = raw + (size_t)b*C*NN;
  const float* cb = csinv + b*NN;
  const int tr = t >> 4, tc = t & 15;
  constexpr int R = C/16;
  float acc[R][4];
  #pragma unroll
  for (int i = 0; i < R; ++i){ acc[i][0]=acc[i][1]=acc[i][2]=acc[i][3]=0.0f; }
  for (int c0 = 0; c0 < C; c0 += 32){
    __syncthreads();
    #pragma unroll
    for (int i = 0; i < 8; ++i){
      int idx = t + 256*i;
      int m = idx & 63, cl = idx >> 6;
      int cc = c0 + cl;
      ds[cl][m] = xb[cc*NN + m0 + m] - rb[cc*NN + m0 + m] * cb[m0 + m];
    }
    #pragma unroll
    for (int i = 0; i < C*32/256; ++i){
      int idx = t + 256*i;
      int cl = idx & 31, o = idx >> 5;
      ws[cl][o] = wt[o*C + c0 + cl];
    }
    __syncthreads();
    #pragma unroll
    for (int k = 0; k < 32; ++k){
      float4 e = *(const float4*)&ds[k][tc*4];
      float a[R];
      #pragma unroll
      for (int q = 0; q < R/4; ++q)
        *(float4*)&a[q*4] = *(const float4*)&ws[k][tr*R + q*4];
      #pragma unroll
      for (int i = 0; i < R; ++i){
        acc[i][0] += a[i]*e.x; acc[i][1] += a[i]*e.y;
        acc[i][2] += a[i]*e.z; acc[i][3] += a[i]*e.w;
      }
    }
  }
  #pragma unroll
  for (int i = 0; i < R; ++i){
    int o = tr*R + i;
    float g = bnp[o], be = bnp[C+o], mn = bnp[2*C+o], vv = bnp[3*C+o];
    float sc = g * rsqrtf(vv + BN_EPS_);
    float sh = be - mn*sc;
    float bv = bt[o];
    float4 r;
    float* rp = &r.x;
    #pragma unroll
    for (int j = 0; j < 4; ++j){
      float y = acc[i][j] + bv;
      y = sc*y + sh;
      y = fmaxf(y, 0.0f);
      rp[j] = xb[o*NN + m0 + tc*4 + j] + y;
    }
    *(float4*)&out[((size_t)b*C + o)*NN + m0 + tc*4] = r;
  }
}

// --------- out = relu(bn(w·x)) ---------
template<int CIN, int COUT>
__global__ __launch_bounds__(256) void conv_bn_relu_kernel(const float* __restrict__ x,
      const float* __restrict__ w, const float* __restrict__ bnp, float* __restrict__ out){
  constexpr int CH = (CIN < 32) ? CIN : 32;
  __shared__ float xs[CH][68];
  __shared__ float ws[CH][COUT+4];
  const int b = blockIdx.y, m0 = blockIdx.x*64, t = threadIdx.x;
  const float* xb = x + (size_t)b*CIN*NN;
  const int tr = t >> 4, tc = t & 15;
  constexpr int R = COUT/16;
  float acc[R][4];
  #pragma unroll
  for (int i = 0; i < R; ++i){ acc[i][0]=acc[i][1]=acc[i][2]=acc[i][3]=0.0f; }
  for (int c0 = 0; c0 < CIN; c0 += CH){
    __syncthreads();
    for (int idx = t; idx < CH*64; idx += 256){
      int m = idx & 63, cl = idx >> 6;
      xs[cl][m] = xb[(c0+cl)*NN + m0 + m];
    }
    for (int idx = t; idx < CH*COUT; idx += 256){
      int cl = idx % CH, o = idx / CH;
      ws[cl][o] = w[o*CIN + c0 + cl];
    }
    __syncthreads();
    #pragma unroll
    for (int k = 0; k < CH; ++k){
      float4 e = *(const float4*)&xs[k][tc*4];
      float a[R];
      #pragma unroll
      for (int q = 0; q < R/4; ++q)
        *(float4*)&a[q*4] = *(const float4*)&ws[k][tr*R + q*4];
      #pragma unroll
      for (int i = 0; i < R; ++i){
        acc[i][0] += a[i]*e.x; acc[i][1] += a[i]*e.y;
        acc[i][2] += a[i]*e.z; acc[i][3] += a[i]*e.w;
      }
    }
  }
  #pragma unroll
  for (int i = 0; i < R; ++i){
    int o = tr*R + i;
    float g = bnp[o], be = bnp[COUT+o], mn = bnp[2*COUT+o], vv = bnp[3*COUT+o];
    float sc = g * rsqrtf(vv + BN_EPS_);
    float sh = be - mn*sc;
    float4 r;
    float* rp = &r.x;
    #pragma unroll
    for (int j = 0; j < 4; ++j){
      float y = sc*acc[i][j] + sh;
      rp[j] = fmaxf(y, 0.0f);
    }
    *(float4*)&out[((size_t)b*COUT + o)*NN + m0 + tc*4] = r;
  }
}

// --------- pooled[b,o] = max_n relu(bn(Σ_c w5[o,c] h[c,n]))  (h5 never materialized) ---------
__global__ __launch_bounds__(256) void conv5_pool_kernel(const float* __restrict__ h,
      const float* __restrict__ w5, const float* __restrict__ bnp, float* __restrict__ pooled){
  __shared__ float ws[128][68];
  __shared__ float hs[128][68];
  const int b = blockIdx.y, o0 = blockIdx.x*64, t = threadIdx.x;
  const float* hb = h + (size_t)b*128*NN;
  #pragma unroll
  for (int i = 0; i < 32; ++i){
    int idx = t + 256*i;
    int cc = idx & 127, ol = idx >> 7;
    ws[cc][ol] = w5[(o0+ol)*128 + cc];
  }
  const int tr = t >> 4, tc = t & 15;
  float sc[4], sh[4];
  #pragma unroll
  for (int i = 0; i < 4; ++i){
    int o = o0 + tr*4 + i;
    float g = bnp[o], be = bnp[1024+o], mn = bnp[2*1024+o], vv = bnp[3*1024+o];
    sc[i] = g * rsqrtf(vv + BN_EPS_);
    sh[i] = be - mn*sc[i];
  }
  float vmax[4] = {0.f,0.f,0.f,0.f};   // relu output >= 0, so 0 is a safe identity
  for (int n0 = 0; n0 < NN; n0 += 64){
    __syncthreads();
    #pragma unroll
    for (int i = 0; i < 32; ++i){
      int idx = t + 256*i;
      int nl = idx & 63, cc = idx >> 6;
      hs[cc][nl] = hb[cc*NN + n0 + nl];
    }
    __syncthreads();
    float acc[4][4];
    #pragma unroll
    for (int i = 0; i < 4; ++i){ acc[i][0]=acc[i][1]=acc[i][2]=acc[i][3]=0.0f; }
    #pragma unroll 8
    for (int k = 0; k < 128; ++k){
      float4 a = *(const float4*)&ws[k][tr*4];
      float4 e = *(const float4*)&hs[k][tc*4];
      acc[0][0]+=a.x*e.x; acc[0][1]+=a.x*e.y; acc[0][2]+=a.x*e.z; acc[0][3]+=a.x*e.w;
      acc[1][0]+=a.y*e.x; acc[1][1]+=a.y*e.y; acc[1][2]+=a.y*e.z; acc[1][3]+=a.y*e.w;
      acc[2][0]+=a.z*e.x; acc[2][1]+=a.z*e.y; acc[2][2]+=a.z*e.z; acc[2][3]+=a.z*e.w;
      acc[3][0]+=a.w*e.x; acc[3][1]+=a.w*e.y; acc[3][2]+=a.w*e.z; acc[3][3]+=a.w*e.w;
    }
    #pragma unroll
    for (int i = 0; i < 4; ++i){
      #pragma unroll
      for (int j = 0; j < 4; ++j){
        float y = sc[i]*acc[i][j] + sh[i];
        y = fmaxf(y, 0.0f);
        vmax[i] = fmaxf(vmax[i], y);
      }
    }
  }
  #pragma unroll
  for (int i = 0; i < 4; ++i){
    float v = vmax[i];
    v = fmaxf(v, __shfl_xor(v, 1));
    v = fmaxf(v, __shfl_xor(v, 2));
    v = fmaxf(v, __shfl_xor(v, 4));
    v = fmaxf(v, __shfl_xor(v, 8));
    if (tc == 0) pooled[b*1024 + o0 + tr*4 + i] = v;
  }
}

// --------- lin1 + bn6 + relu ---------
__global__ void lin1_kernel(const float* __restrict__ pooled, const float* __restrict__ w,
      const float* __restrict__ bnp, float* __restrict__ out1){
  int tid = blockIdx.x*256 + threadIdx.x;   // 8192 threads
  int b = tid >> 9, j = tid & 511;
  const float4* p4 = (const float4*)(pooled + b*1024);
  const float4* w4 = (const float4*)(w + j*1024);
  float sum = 0.0f;
  for (int e = 0; e < 256; ++e){
    float4 a = p4[e], c = w4[e];
    sum += a.x*c.x + a.y*c.y + a.z*c.z + a.w*c.w;
  }
  float g = bnp[j], be = bnp[512+j], mn = bnp[2*512+j], vv = bnp[3*512+j];
  float s = g * rsqrtf(vv + BN_EPS_);
  float y = s*sum + (be - mn*s);
  out1[b*512 + j] = fmaxf(y, 0.0f);
}

// --------- lin2 ---------
__global__ void lin2_kernel(const float* __restrict__ h, const float* __restrict__ w,
      const float* __restrict__ bias, float* __restrict__ out){
  int tid = blockIdx.x*64 + threadIdx.x;
  if (tid >= 640) return;
  int b = tid / 40, k = tid % 40;
  const float4* h4 = (const float4*)(h + b*512);
  const float4* w4 = (const float4*)(w + k*512);
  float sum = 0.0f;
  for (int e = 0; e < 128; ++e){
    float4 a = h4[e], c = w4[e];
    sum += a.x*c.x + a.y*c.y + a.z*c.z + a.w*c.w;
  }
  out[tid] = sum + bias[k];
}

extern "C" void kernel_launch(void* const* d_in, const int* in_sizes, int n_in,
                              void* d_out, int out_size, void* d_ws, size_t ws_size,
                              hipStream_t stream){
  (void)in_sizes; (void)n_in; (void)out_size; (void)ws_size;
  const float* x     = (const float*)d_in[0];
  const float* w1    = (const float*)d_in[1];
  const float* w2    = (const float*)d_in[2];
  const float* w3    = (const float*)d_in[3];
  const float* w4    = (const float*)d_in[4];
  const float* w5    = (const float*)d_in[5];
  const float* bn1   = (const float*)d_in[6];
  const float* bn2   = (const float*)d_in[7];
  const float* bn3   = (const float*)d_in[8];
  const float* bn4   = (const float*)d_in[9];
  const float* bn5   = (const float*)d_in[10];
  const float* da_wqk[4] = {(const float*)d_in[11], (const float*)d_in[15], (const float*)d_in[19], (const float*)d_in[23]};
  const float* da_wt[4]  = {(const float*)d_in[12], (const float*)d_in[16], (const float*)d_in[20], (const float*)d_in[24]};
  const float* da_bt[4]  = {(const float*)d_in[13], (const float*)d_in[17], (const float*)d_in[21], (const float*)d_in[25]};
  const float* da_bn[4]  = {(const float*)d_in[14], (const float*)d_in[18], (const float*)d_in[22], (const float*)d_in[26]};
  const float* lin1_w = (const float*)d_in[27];
  const float* bn6    = (const float*)d_in[28];
  const float* lin2_w = (const float*)d_in[29];
  const float* lin2_b = (const float*)d_in[30];

  float* ws = (float*)d_ws;
  float* maxval = ws;                   // 1 float (padded to 64)
  float* dens   = ws + 64;
  float* zinv   = dens + BB*NN;
  float* csinv  = zinv + BB*NN;
  float* hA     = csinv + BB*NN;
  float* hB     = hA  + (size_t)BB*64*NN;
  float* h4A    = hB  + (size_t)BB*64*NN;
  float* raw    = h4A + (size_t)BB*128*NN;
  float* pooled = raw + (size_t)BB*128*NN;
  float* l1o    = pooled + BB*1024;
  float* uvec   = l1o + BB*512;
  float* blockmax = uvec + (size_t)BB*3*NN;   // 4096 floats
  float* h4B    = hA;   // attn4 output reuses the (hA|hB) region: 16*128*2048 floats

  normalize_points_kernel<<<dim3(BB*NN/256), 256, 0, stream>>>(x, uvec);
  density5_kernel<<<dim3(NN/DG, BB), 256, 0, stream>>>(uvec, dens, blockmax);
  finalize_max_kernel<<<dim3(1), 256, 0, stream>>>(blockmax, maxval);
  normalize_kernel<<<dim3(BB*NN/256), 256, 0, stream>>>(dens, maxval);

  conv_bn_relu_kernel<3,64><<<dim3(32,BB),256,0,stream>>>(x, w1, bn1, hA);

  // attn1: hA -> hB
  zcol_kernel<false><<<dim3(32,BB),256,0,stream>>>(dens, da_wqk[0], 16, nullptr, zinv);
  zcol_kernel<true ><<<dim3(32,BB),256,0,stream>>>(dens, da_wqk[0], 16, zinv, csinv);
  attn_gemm_kernel<64><<<dim3(32,BB),256,0,stream>>>(hA, dens, zinv, da_wqk[0], 16, raw);
  attn_post_kernel<64><<<dim3(32,BB),256,0,stream>>>(hA, raw, csinv, da_wt[0], da_bt[0], da_bn[0], hB);

  conv_bn_relu_kernel<64,64><<<dim3(32,BB),256,0,stream>>>(hB, w2, bn2, hA);

  // attn2: hA -> hB
  zcol_kernel<false><<<dim3(32,BB),256,0,stream>>>(dens, da_wqk[1], 16, nullptr, zinv);
  zcol_kernel<true ><<<dim3(32,BB),256,0,stream>>>(dens, da_wqk[1], 16, zinv, csinv);
  attn_gemm_kernel<64><<<dim3(32,BB),256,0,stream>>>(hA, dens, zinv, da_wqk[1], 16, raw);
  attn_post_kernel<64><<<dim3(32,BB),256,0,stream>>>(hA, raw, csinv, da_wt[1], da_bt[1], da_bn[1], hB);

  conv_bn_relu_kernel<64,64><<<dim3(32,BB),256,0,stream>>>(hB, w3, bn3, hA);

  // attn3: hA -> hB
  zcol_kernel<false><<<dim3(32,BB),256,0,stream>>>(dens, da_wqk[2], 16, nullptr, zinv);
  zcol_kernel<true ><<<dim3(32,BB),256,0,stream>>>(dens, da_wqk[2], 16, zinv, csinv);
  attn_gemm_kernel<64><<<dim3(32,BB),256,0,stream>>>(hA, dens, zinv, da_wqk[2], 16, raw);
  attn_post_kernel<64><<<dim3(32,BB),256,0,stream>>>(hA, raw, csinv, da_wt[2], da_bt[2], da_bn[2], hB);

  conv_bn_relu_kernel<64,128><<<dim3(32,BB),256,0,stream>>>(hB, w4, bn4, h4A);

  // attn4 (C=128): h4A -> h4B
  zcol_kernel<false><<<dim3(32,BB),256,0,stream>>>(dens, da_wqk[3], 32, nullptr, zinv);
  zcol_kernel<true ><<<dim3(32,BB),256,0,stream>>>(dens, da_wqk[3], 32, zinv, csinv);
  attn_gemm_kernel<128><<<dim3(32,BB),256,0,stream>>>(h4A, dens, zinv, da_wqk[3], 32, raw);
  attn_post_kernel<128><<<dim3(32,BB),256,0,stream>>>(h4A, raw, csinv, da_wt[3], da_bt[3], da_bn[3], h4B);

  conv5_pool_kernel<<<dim3(16,BB),256,0,stream>>>(h4B, w5, bn5, pooled);
  lin1_kernel<<<dim3(32),256,0,stream>>>(pooled, lin1_w, bn6, l1o);
  lin2_kernel<<<dim3(10),64,0,stream>>>(l1o, lin2_w, lin2_b, (float*)d_out);
}

// Round 6
// 906.492 us; speedup vs baseline: 1.7719x; 1.2510x over previous
//
#include <hip/hip_runtime.h>
#include <math.h>

#define BB 16
#define NN 2048
#define BN_EPS_ 1e-5f

typedef __attribute__((ext_vector_type(8))) short short8v;   // 8 bf16 (4 VGPRs)
typedef __attribute__((ext_vector_type(4))) float f32x4;

__device__ __forceinline__ unsigned short f2bf(float x){
  unsigned u = __float_as_uint(x);
  u += 0x7fffu + ((u >> 16) & 1u);          // round-to-nearest-even
  return (unsigned short)(u >> 16);
}
__device__ __forceinline__ float bf2f(unsigned short h){
  return __uint_as_float(((unsigned)h) << 16);
}

// ---------------- normalize points once: u[b][3][n] = xyz/|xyz| ----------------
__global__ __launch_bounds__(256) void normalize_points_kernel(const float* __restrict__ x,
        float* __restrict__ u){
  int idx = blockIdx.x*256 + threadIdx.x;     // BB*NN threads
  int b = idx >> 11, n = idx & (NN-1);
  const float* xb = x + (size_t)b*3*NN;
  float x0 = xb[n], x1 = xb[NN+n], x2 = xb[2*NN+n];
  float rn = rsqrtf(x0*x0 + x1*x1 + x2*x2);
  float* ub = u + (size_t)b*3*NN;
  ub[n] = x0*rn; ub[NN+n] = x1*rn; ub[2*NN+n] = x2*rn;
}

// ---------------- density via batched histogram rank-select (no global atomics) ----------------
#define DG 8
__global__ __launch_bounds__(256) void density5_kernel(const float* __restrict__ u,
        float* __restrict__ inv, float* __restrict__ blockmax){
  __shared__ float us0[NN], us1[NN], us2[NN];      // 24 KiB
  __shared__ unsigned int hist[DG][256];           // 8 KiB
  __shared__ float buf[DG][128];                   // 4 KiB
  __shared__ unsigned int bufcnt[DG];
  __shared__ unsigned int bB[DG], bC0[DG];
  __shared__ float partial[DG][4];
  __shared__ float rowiv[DG];
  const int b = blockIdx.y;
  const float* ub = u + (size_t)b*3*NN;
  const int t = threadIdx.x;
  #pragma unroll
  for (int i = 0; i < NN/(256*4); ++i){
    int n4 = t + 256*i;
    ((float4*)us0)[n4] = ((const float4*)ub)[n4];
    ((float4*)us1)[n4] = ((const float4*)(ub+NN))[n4];
    ((float4*)us2)[n4] = ((const float4*)(ub+2*NN))[n4];
  }
  #pragma unroll
  for (int i = 0; i < DG; ++i) hist[i][t & 255] = 0u;
  if (t < DG) bufcnt[t] = 0u;
  __syncthreads();
  float m0[8], m1[8], m2[8];
  #pragma unroll
  for (int i = 0; i < 8; ++i){
    int c = t + 256*i;
    m0[i] = us0[c]; m1[i] = us1[c]; m2[i] = us2[c];
  }
  const int r0 = blockIdx.x * DG;
  float ru0[DG], ru1[DG], ru2[DG];
  #pragma unroll
  for (int j = 0; j < DG; ++j){ ru0[j] = us0[r0+j]; ru1[j] = us1[r0+j]; ru2[j] = us2[r0+j]; }

  unsigned qp[DG][2];
  #pragma unroll
  for (int j = 0; j < DG; ++j){
    unsigned q0 = 0u, q1 = 0u;
    #pragma unroll
    for (int i = 0; i < 8; ++i){
      float d = 1.0f - (ru0[j]*m0[i] + ru1[j]*m1[i] + ru2[j]*m2[i]);
      int q = (int)(d * 128.0f);
      q = q < 0 ? 0 : (q > 255 ? 255 : q);
      if (i < 4) q0 |= (unsigned)q << (8*i); else q1 |= (unsigned)q << (8*(i-4));
      atomicAdd(&hist[j][q], 1u);
    }
    qp[j][0] = q0; qp[j][1] = q1;
  }
  __syncthreads();

  const int wave = t >> 6, lane = t & 63;
  #pragma unroll
  for (int jj = 0; jj < 2; ++jj){
    const int j = 2*wave + jj;
    uint4 cc = *(const uint4*)&hist[j][lane*4];
    unsigned tl = cc.x + cc.y + cc.z + cc.w;
    unsigned inc = tl;
    #pragma unroll
    for (int off = 1; off < 64; off <<= 1){
      unsigned o = __shfl_up(inc, off);
      if (lane >= off) inc += o;
    }
    unsigned base = inc - tl;
    if (base < 32u && base + tl >= 32u){
      unsigned cum = base;
      if (cum < 32u && cum + cc.x >= 32u){ bB[j] = lane*4 + 0; bC0[j] = cum; } cum += cc.x;
      if (cum < 32u && cum + cc.y >= 32u){ bB[j] = lane*4 + 1; bC0[j] = cum; } cum += cc.y;
      if (cum < 32u && cum + cc.z >= 32u){ bB[j] = lane*4 + 2; bC0[j] = cum; } cum += cc.z;
      if (cum < 32u && cum + cc.w >= 32u){ bB[j] = lane*4 + 3; bC0[j] = cum; } cum += cc.w;
    }
  }
  __syncthreads();

  #pragma unroll
  for (int j = 0; j < DG; ++j){
    const int B = (int)bB[j];
    float s = 0.0f;
    #pragma unroll
    for (int i = 0; i < 8; ++i){
      float d = 1.0f - (ru0[j]*m0[i] + ru1[j]*m1[i] + ru2[j]*m2[i]);
      const int q = (int)((qp[j][i>>2] >> (8*(i&3))) & 255u);
      if (q < B) s += d;
      else if (q == B){
        unsigned slot = atomicAdd(&bufcnt[j], 1u);
        if (slot < 128u) buf[j][slot] = d;
      }
    }
    #pragma unroll
    for (int off = 32; off > 0; off >>= 1) s += __shfl_xor(s, off);
    if (lane == 0) partial[j][wave] = s;
  }
  __syncthreads();

  #pragma unroll
  for (int jj = 0; jj < 2; ++jj){
    const int j = 2*wave + jj;
    float total = partial[j][0] + partial[j][1] + partial[j][2] + partial[j][3];
    int cnt = (int)bufcnt[j]; if (cnt > 128) cnt = 128;
    const int rr = 32 - (int)bC0[j];
    float v1 = (lane      < cnt) ? buf[j][lane]      : 0.0f;
    float v2 = (lane + 64 < cnt) ? buf[j][lane + 64] : 0.0f;
    int rk1 = 0, rk2 = 0;
    for (int k = 0; k < cnt; ++k){
      float vk = buf[j][k];
      rk1 += ((vk < v1) || (vk == v1 && k < lane)) ? 1 : 0;
      rk2 += ((vk < v2) || (vk == v2 && k < lane + 64)) ? 1 : 0;
    }
    float contrib = ((lane      < cnt) && (rk1 < rr)) ? v1 : 0.0f;
    contrib      += ((lane + 64 < cnt) && (rk2 < rr)) ? v2 : 0.0f;
    #pragma unroll
    for (int off = 32; off > 0; off >>= 1) contrib += __shfl_xor(contrib, off);
    total += contrib;
    if (lane == 0){
      float iv = 32.0f / total;
      inv[b*NN + r0 + j] = iv;
      rowiv[j] = iv;
    }
  }
  __syncthreads();
  if (t == 0){
    float m = rowiv[0];
    #pragma unroll
    for (int j = 1; j < DG; ++j) m = fmaxf(m, rowiv[j]);
    blockmax[blockIdx.y * gridDim.x + blockIdx.x] = m;
  }
}

__global__ __launch_bounds__(256) void finalize_max_kernel(const float* __restrict__ blockmax,
        float* __restrict__ maxout){
  __shared__ float pw[4];
  const int t = threadIdx.x;
  float m = 0.0f;
  #pragma unroll
  for (int i = 0; i < 16; ++i) m = fmaxf(m, blockmax[t + 256*i]);
  #pragma unroll
  for (int off = 32; off > 0; off >>= 1) m = fmaxf(m, __shfl_xor(m, off));
  if ((t & 63) == 0) pw[t >> 6] = m;
  __syncthreads();
  if (t == 0) *maxout = fmaxf(fmaxf(pw[0], pw[1]), fmaxf(pw[2], pw[3]));
}

__global__ void normalize_kernel(float* __restrict__ dens, const float* __restrict__ maxval){
  int i = blockIdx.x*256 + threadIdx.x;
  float mx = *maxval;
  dens[i] = dens[i] / mx;
}

// --------- Zinv: out[r] = 1/Σ_m exp(s d[r] d[m]) ---------
__global__ __launch_bounds__(256) void zrow_kernel(const float* __restrict__ dens,
      const float* __restrict__ wqk, int K, float* __restrict__ out){
  __shared__ float ds[NN];
  const int b = blockIdx.y, t = threadIdx.x;
  float s = 0.0f;
  for (int k = 0; k < K; ++k){ float w = wqk[k]; s += w*w; }
  #pragma unroll
  for (int i = 0; i < NN/256; ++i) ds[t + 256*i] = dens[b*NN + t + 256*i];
  __syncthreads();
  const int wave = t >> 6, lane = t & 63;
  const int RPB = NN / gridDim.x;
  const int r0 = blockIdx.x * RPB;
  for (int r = r0 + wave; r < r0 + RPB; r += 4){
    float a = s * ds[r];
    float sum = 0.0f;
    #pragma unroll
    for (int i = 0; i < NN/64; ++i){
      int m = lane + 64*i;
      sum += __expf(a * ds[m]);
    }
    #pragma unroll
    for (int off = 32; off > 0; off >>= 1) sum += __shfl_xor(sum, off);
    if (lane == 0) out[b*NN + r] = 1.0f/sum;
  }
}

// --------- MFMA attention GEMM: raw[c,m] = Σ_n xz[c,n]·E[n,m], row C = Σ_n zinv[n]·E[n,m] ---------
// Split-bf16 (hi+lo, 3 MFMAs) for ~fp32 accuracy; E generated on the fly into LDS.
template<int C>
__global__ __launch_bounds__(256) void attn_mfma_kernel(const float* __restrict__ x,
      const float* __restrict__ dens, const float* __restrict__ zinv,
      const float* __restrict__ wqk, int K, float* __restrict__ raw){
  constexpr int RA = C + 16;     // +16: zinv row (at C) + zero pad
  constexpr int RT = RA / 16;
  constexpr int KP = 72;         // padded K-tile (bank-uniform for b128 r/w)
  __shared__ unsigned short ah[RA][KP], al[RA][KP];
  __shared__ unsigned short eh[64][KP], el[64][KP];
  const int b = blockIdx.y, m0 = blockIdx.x * 64, t = threadIdx.x;
  float s = 0.0f;
  for (int k = 0; k < K; ++k){ float w = wqk[k]; s += w*w; }
  const float* db = dens + b*NN;
  const float* zb = zinv + b*NN;
  const float* xb = x + (size_t)b*C*NN;
  const int ej = t >> 2, ekq = (t & 3) * 16;       // E-gen: row (m) / k-quarter
  const float dmj = db[m0 + ej];
  const int ar = t >> 4, ak4 = (t & 15) * 4;       // A-stage: row-in-16 / k4
  const int l = t & 63, w = t >> 6;                // MFMA: wave owns 16 cols
  const int fc = l & 15, g = l >> 4;
  f32x4 acc[RT];
  #pragma unroll
  for (int i = 0; i < RT; ++i) acc[i] = (f32x4){0.f,0.f,0.f,0.f};

  for (int n0 = 0; n0 < NN; n0 += 64){
    __syncthreads();
    // ---- stage A tile (rows: 0..C-1 = x*zinv, C = zinv, >C = 0), hi/lo split
    float4 zv = *(const float4*)(zb + n0 + ak4);
    #pragma unroll
    for (int i = 0; i < RT; ++i){
      int c = i*16 + ar;
      float4 v;
      if (c < C){
        float4 xv = *(const float4*)(xb + (size_t)c*NN + n0 + ak4);
        v.x = xv.x*zv.x; v.y = xv.y*zv.y; v.z = xv.z*zv.z; v.w = xv.w*zv.w;
      } else if (c == C){ v = zv; }
      else { v.x = v.y = v.z = v.w = 0.0f; }
      unsigned short h0=f2bf(v.x), h1=f2bf(v.y), h2=f2bf(v.z), h3=f2bf(v.w);
      uint2 hp, lp;
      hp.x = (unsigned)h0 | ((unsigned)h1<<16);
      hp.y = (unsigned)h2 | ((unsigned)h3<<16);
      lp.x = (unsigned)f2bf(v.x-bf2f(h0)) | ((unsigned)f2bf(v.y-bf2f(h1))<<16);
      lp.y = (unsigned)f2bf(v.z-bf2f(h2)) | ((unsigned)f2bf(v.w-bf2f(h3))<<16);
      *(uint2*)&ah[c][ak4] = hp;
      *(uint2*)&al[c][ak4] = lp;
    }
    // ---- stage E tile: eh/el[j][k] = split(exp(s·d[n0+k]·d[m0+j])), 16 k per thread
    {
      unsigned hp[8], lp[8];
      #pragma unroll
      for (int u = 0; u < 4; ++u){
        float4 dn = *(const float4*)(db + n0 + ekq + u*4);
        float e0 = __expf(s*dn.x*dmj), e1 = __expf(s*dn.y*dmj);
        float e2 = __expf(s*dn.z*dmj), e3 = __expf(s*dn.w*dmj);
        unsigned short a0=f2bf(e0), a1=f2bf(e1), a2=f2bf(e2), a3=f2bf(e3);
        hp[u*2+0] = (unsigned)a0 | ((unsigned)a1<<16);
        hp[u*2+1] = (unsigned)a2 | ((unsigned)a3<<16);
        lp[u*2+0] = (unsigned)f2bf(e0-bf2f(a0)) | ((unsigned)f2bf(e1-bf2f(a1))<<16);
        lp[u*2+1] = (unsigned)f2bf(e2-bf2f(a2)) | ((unsigned)f2bf(e3-bf2f(a3))<<16);
      }
      *(uint4*)&eh[ej][ekq]   = make_uint4(hp[0],hp[1],hp[2],hp[3]);
      *(uint4*)&eh[ej][ekq+8] = make_uint4(hp[4],hp[5],hp[6],hp[7]);
      *(uint4*)&el[ej][ekq]   = make_uint4(lp[0],lp[1],lp[2],lp[3]);
      *(uint4*)&el[ej][ekq+8] = make_uint4(lp[4],lp[5],lp[6],lp[7]);
    }
    __syncthreads();
    // ---- MFMA: D(16x16) += A(16x32)·B(32x16); 3-term split product
    #pragma unroll
    for (int kk = 0; kk < 2; ++kk){
      short8v bh = *(const short8v*)&eh[w*16 + fc][kk*32 + g*8];
      short8v bl = *(const short8v*)&el[w*16 + fc][kk*32 + g*8];
      #pragma unroll
      for (int i = 0; i < RT; ++i){
        short8v ai = *(const short8v*)&ah[i*16 + fc][kk*32 + g*8];
        short8v au = *(const short8v*)&al[i*16 + fc][kk*32 + g*8];
        acc[i] = __builtin_amdgcn_mfma_f32_16x16x32_bf16(ai, bh, acc[i], 0, 0, 0);
        acc[i] = __builtin_amdgcn_mfma_f32_16x16x32_bf16(ai, bl, acc[i], 0, 0, 0);
        acc[i] = __builtin_amdgcn_mfma_f32_16x16x32_bf16(au, bh, acc[i], 0, 0, 0);
      }
    }
  }
  // ---- epilogue: D layout col=lane&15, row=(lane>>4)*4+r  [verified layout]
  float* rb = raw + (size_t)b*RA*NN + m0 + w*16 + fc;
  #pragma unroll
  for (int i = 0; i < RT; ++i){
    #pragma unroll
    for (int r = 0; r < 4; ++r){
      int row = i*16 + g*4 + r;
      rb[(size_t)row*NN] = acc[i][r];
    }
  }
}

// --------- out = x + relu(bn(wt·(x - raw·csinv) + bt)); csinv from raw row C ---------
template<int C>
__global__ __launch_bounds__(256) void attn_post_kernel(const float* __restrict__ x,
      const float* __restrict__ raw, const float* __restrict__ wt,
      const float* __restrict__ bt, const float* __restrict__ bnp,
      float* __restrict__ out){
  constexpr int RA = C + 16;
  __shared__ float ds[32][68];
  __shared__ float ws[32][C+4];
  __shared__ float cbs[64];
  const int b = blockIdx.y, m0 = blockIdx.x*64, t = threadIdx.x;
  const float* xb = x + (size_t)b*C*NN;
  const float* rb = raw + (size_t)b*RA*NN;
  if (t < 64) cbs[t] = 1.0f / (1e-9f + rb[(size_t)C*NN + m0 + t]);
  const int tr = t >> 4, tc = t & 15;
  constexpr int R = C/16;
  float acc[R][4];
  #pragma unroll
  for (int i = 0; i < R; ++i){ acc[i][0]=acc[i][1]=acc[i][2]=acc[i][3]=0.0f; }
  for (int c0 = 0; c0 < C; c0 += 32){
    __syncthreads();
    #pragma unroll
    for (int i = 0; i < 8; ++i){
      int idx = t + 256*i;
      int m = idx & 63, cl = idx >> 6;
      int cc = c0 + cl;
      ds[cl][m] = xb[cc*NN + m0 + m] - rb[cc*NN + m0 + m] * cbs[m];
    }
    #pragma unroll
    for (int i = 0; i < C*32/256; ++i){
      int idx = t + 256*i;
      int cl = idx & 31, o = idx >> 5;
      ws[cl][o] = wt[o*C + c0 + cl];
    }
    __syncthreads();
    #pragma unroll
    for (int k = 0; k < 32; ++k){
      float4 e = *(const float4*)&ds[k][tc*4];
      float a[R];
      #pragma unroll
      for (int q = 0; q < R/4; ++q)
        *(float4*)&a[q*4] = *(const float4*)&ws[k][tr*R + q*4];
      #pragma unroll
      for (int i = 0; i < R; ++i){
        acc[i][0] += a[i]*e.x; acc[i][1] += a[i]*e.y;
        acc[i][2] += a[i]*e.z; acc[i][3] += a[i]*e.w;
      }
    }
  }
  #pragma unroll
  for (int i = 0; i < R; ++i){
    int o = tr*R + i;
    float g = bnp[o], be = bnp[C+o], mn = bnp[2*C+o], vv = bnp[3*C+o];
    float sc = g * rsqrtf(vv + BN_EPS_);
    float sh = be - mn*sc;
    float bv = bt[o];
    float4 r;
    float* rp = &r.x;
    #pragma unroll
    for (int j = 0; j < 4; ++j){
      float y = acc[i][j] + bv;
      y = sc*y + sh;
      y = fmaxf(y, 0.0f);
      rp[j] = xb[o*NN + m0 + tc*4 + j] + y;
    }
    *(float4*)&out[((size_t)b*C + o)*NN + m0 + tc*4] = r;
  }
}

// --------- out = relu(bn(w·x)) ---------
template<int CIN, int COUT>
__global__ __launch_bounds__(256) void conv_bn_relu_kernel(const float* __restrict__ x,
      const float* __restrict__ w, const float* __restrict__ bnp, float* __restrict__ out){
  constexpr int CH = (CIN < 32) ? CIN : 32;
  __shared__ float xs[CH][68];
  __shared__ float ws[CH][COUT+4];
  const int b = blockIdx.y, m0 = blockIdx.x*64, t = threadIdx.x;
  const float* xb = x + (size_t)b*CIN*NN;
  const int tr = t >> 4, tc = t & 15;
  constexpr int R = COUT/16;
  float acc[R][4];
  #pragma unroll
  for (int i = 0; i < R; ++i){ acc[i][0]=acc[i][1]=acc[i][2]=acc[i][3]=0.0f; }
  for (int c0 = 0; c0 < CIN; c0 += CH){
    __syncthreads();
    for (int idx = t; idx < CH*64; idx += 256){
      int m = idx & 63, cl = idx >> 6;
      xs[cl][m] = xb[(c0+cl)*NN + m0 + m];
    }
    for (int idx = t; idx < CH*COUT; idx += 256){
      int cl = idx % CH, o = idx / CH;
      ws[cl][o] = w[o*CIN + c0 + cl];
    }
    __syncthreads();
    #pragma unroll
    for (int k = 0; k < CH; ++k){
      float4 e = *(const float4*)&xs[k][tc*4];
      float a[R];
      #pragma unroll
      for (int q = 0; q < R/4; ++q)
        *(float4*)&a[q*4] = *(const float4*)&ws[k][tr*R + q*4];
      #pragma unroll
      for (int i = 0; i < R; ++i){
        acc[i][0] += a[i]*e.x; acc[i][1] += a[i]*e.y;
        acc[i][2] += a[i]*e.z; acc[i][3] += a[i]*e.w;
      }
    }
  }
  #pragma unroll
  for (int i = 0; i < R; ++i){
    int o = tr*R + i;
    float g = bnp[o], be = bnp[COUT+o], mn = bnp[2*COUT+o], vv = bnp[3*COUT+o];
    float sc = g * rsqrtf(vv + BN_EPS_);
    float sh = be - mn*sc;
    float4 r;
    float* rp = &r.x;
    #pragma unroll
    for (int j = 0; j < 4; ++j){
      float y = sc*acc[i][j] + sh;
      rp[j] = fmaxf(y, 0.0f);
    }
    *(float4*)&out[((size_t)b*COUT + o)*NN + m0 + tc*4] = r;
  }
}

// --------- pooled[b,o] = max_n relu(bn(Σ_c w5[o,c] h[c,n])) ---------
__global__ __launch_bounds__(256) void conv5_pool_kernel(const float* __restrict__ h,
      const float* __restrict__ w5, const float* __restrict__ bnp, float* __restrict__ pooled){
  __shared__ float ws[128][68];
  __shared__ float hs[128][68];
  const int b = blockIdx.y, o0 = blockIdx.x*64, t = threadIdx.x;
  const float* hb = h + (size_t)b*128*NN;
  #pragma unroll
  for (int i = 0; i < 32; ++i){
    int idx = t + 256*i;
    int cc = idx & 127, ol = idx >> 7;
    ws[cc][ol] = w5[(o0+ol)*128 + cc];
  }
  const int tr = t >> 4, tc = t & 15;
  float sc[4], sh[4];
  #pragma unroll
  for (int i = 0; i < 4; ++i){
    int o = o0 + tr*4 + i;
    float g = bnp[o], be = bnp[1024+o], mn = bnp[2*1024+o], vv = bnp[3*1024+o];
    sc[i] = g * rsqrtf(vv + BN_EPS_);
    sh[i] = be - mn*sc[i];
  }
  float vmax[4] = {0.f,0.f,0.f,0.f};
  for (int n0 = 0; n0 < NN; n0 += 64){
    __syncthreads();
    #pragma unroll
    for (int i = 0; i < 32; ++i){
      int idx = t + 256*i;
      int nl = idx & 63, cc = idx >> 6;
      hs[cc][nl] = hb[cc*NN + n0 + nl];
    }
    __syncthreads();
    float acc[4][4];
    #pragma unroll
    for (int i = 0; i < 4; ++i){ acc[i][0]=acc[i][1]=acc[i][2]=acc[i][3]=0.0f; }
    #pragma unroll 8
    for (int k = 0; k < 128; ++k){
      float4 a = *(const float4*)&ws[k][tr*4];
      float4 e = *(const float4*)&hs[k][tc*4];
      acc[0][0]+=a.x*e.x; acc[0][1]+=a.x*e.y; acc[0][2]+=a.x*e.z; acc[0][3]+=a.x*e.w;
      acc[1][0]+=a.y*e.x; acc[1][1]+=a.y*e.y; acc[1][2]+=a.y*e.z; acc[1][3]+=a.y*e.w;
      acc[2][0]+=a.z*e.x; acc[2][1]+=a.z*e.y; acc[2][2]+=a.z*e.z; acc[2][3]+=a.z*e.w;
      acc[3][0]+=a.w*e.x; acc[3][1]+=a.w*e.y; acc[3][2]+=a.w*e.z; acc[3][3]+=a.w*e.w;
    }
    #pragma unroll
    for (int i = 0; i < 4; ++i){
      #pragma unroll
      for (int j = 0; j < 4; ++j){
        float y = sc[i]*acc[i][j] + sh[i];
        y = fmaxf(y, 0.0f);
        vmax[i] = fmaxf(vmax[i], y);
      }
    }
  }
  #pragma unroll
  for (int i = 0; i < 4; ++i){
    float v = vmax[i];
    v = fmaxf(v, __shfl_xor(v, 1));
    v = fmaxf(v, __shfl_xor(v, 2));
    v = fmaxf(v, __shfl_xor(v, 4));
    v = fmaxf(v, __shfl_xor(v, 8));
    if (tc == 0) pooled[b*1024 + o0 + tr*4 + i] = v;
  }
}

// --------- lin1 + bn6 + relu ---------
__global__ void lin1_kernel(const float* __restrict__ pooled, const float* __restrict__ w,
      const float* __restrict__ bnp, float* __restrict__ out1){
  int tid = blockIdx.x*256 + threadIdx.x;
  int b = tid >> 9, j = tid & 511;
  const float4* p4 = (const float4*)(pooled + b*1024);
  const float4* w4 = (const float4*)(w + j*1024);
  float sum = 0.0f;
  for (int e = 0; e < 256; ++e){
    float4 a = p4[e], c = w4[e];
    sum += a.x*c.x + a.y*c.y + a.z*c.z + a.w*c.w;
  }
  float g = bnp[j], be = bnp[512+j], mn = bnp[2*512+j], vv = bnp[3*512+j];
  float s = g * rsqrtf(vv + BN_EPS_);
  float y = s*sum + (be - mn*s);
  out1[b*512 + j] = fmaxf(y, 0.0f);
}

// --------- lin2 ---------
__global__ void lin2_kernel(const float* __restrict__ h, const float* __restrict__ w,
      const float* __restrict__ bias, float* __restrict__ out){
  int tid = blockIdx.x*64 + threadIdx.x;
  if (tid >= 640) return;
  int b = tid / 40, k = tid % 40;
  const float4* h4 = (const float4*)(h + b*512);
  const float4* w4 = (const float4*)(w + k*512);
  float sum = 0.0f;
  for (int e = 0; e < 128; ++e){
    float4 a = h4[e], c = w4[e];
    sum += a.x*c.x + a.y*c.y + a.z*c.z + a.w*c.w;
  }
  out[tid] = sum + bias[k];
}

extern "C" void kernel_launch(void* const* d_in, const int* in_sizes, int n_in,
                              void* d_out, int out_size, void* d_ws, size_t ws_size,
                              hipStream_t stream){
  (void)in_sizes; (void)n_in; (void)out_size; (void)ws_size;
  const float* x     = (const float*)d_in[0];
  const float* w1    = (const float*)d_in[1];
  const float* w2    = (const float*)d_in[2];
  const float* w3    = (const float*)d_in[3];
  const float* w4    = (const float*)d_in[4];
  const float* w5    = (const float*)d_in[5];
  const float* bn1   = (const float*)d_in[6];
  const float* bn2   = (const float*)d_in[7];
  const float* bn3   = (const float*)d_in[8];
  const float* bn4   = (const float*)d_in[9];
  const float* bn5   = (const float*)d_in[10];
  const float* da_wqk[4] = {(const float*)d_in[11], (const float*)d_in[15], (const float*)d_in[19], (const float*)d_in[23]};
  const float* da_wt[4]  = {(const float*)d_in[12], (const float*)d_in[16], (const float*)d_in[20], (const float*)d_in[24]};
  const float* da_bt[4]  = {(const float*)d_in[13], (const float*)d_in[17], (const float*)d_in[21], (const float*)d_in[25]};
  const float* da_bn[4]  = {(const float*)d_in[14], (const float*)d_in[18], (const float*)d_in[22], (const float*)d_in[26]};
  const float* lin1_w = (const float*)d_in[27];
  const float* bn6    = (const float*)d_in[28];
  const float* lin2_w = (const float*)d_in[29];
  const float* lin2_b = (const float*)d_in[30];

  float* ws = (float*)d_ws;
  float* maxval = ws;                   // 1 float (padded to 64)
  float* dens   = ws + 64;
  float* zinv   = dens + BB*NN;
  float* hA     = zinv + BB*NN;
  float* hB     = hA  + (size_t)BB*64*NN;
  float* h4A    = hB  + (size_t)BB*64*NN;
  float* raw    = h4A + (size_t)BB*128*NN;      // sized for RA=144 rows
  float* pooled = raw + (size_t)BB*144*NN;
  float* l1o    = pooled + BB*1024;
  float* uvec   = l1o + BB*512;
  float* blockmax = uvec + (size_t)BB*3*NN;     // 4096 floats
  float* h4B    = hA;   // attn4 output reuses the (hA|hB) region

  normalize_points_kernel<<<dim3(BB*NN/256), 256, 0, stream>>>(x, uvec);
  density5_kernel<<<dim3(NN/DG, BB), 256, 0, stream>>>(uvec, dens, blockmax);
  finalize_max_kernel<<<dim3(1), 256, 0, stream>>>(blockmax, maxval);
  normalize_kernel<<<dim3(BB*NN/256), 256, 0, stream>>>(dens, maxval);

  conv_bn_relu_kernel<3,64><<<dim3(32,BB),256,0,stream>>>(x, w1, bn1, hA);

  // attn1: hA -> hB
  zrow_kernel<<<dim3(32,BB),256,0,stream>>>(dens, da_wqk[0], 16, zinv);
  attn_mfma_kernel<64><<<dim3(32,BB),256,0,stream>>>(hA, dens, zinv, da_wqk[0], 16, raw);
  attn_post_kernel<64><<<dim3(32,BB),256,0,stream>>>(hA, raw, da_wt[0], da_bt[0], da_bn[0], hB);

  conv_bn_relu_kernel<64,64><<<dim3(32,BB),256,0,stream>>>(hB, w2, bn2, hA);

  // attn2: hA -> hB
  zrow_kernel<<<dim3(32,BB),256,0,stream>>>(dens, da_wqk[1], 16, zinv);
  attn_mfma_kernel<64><<<dim3(32,BB),256,0,stream>>>(hA, dens, zinv, da_wqk[1], 16, raw);
  attn_post_kernel<64><<<dim3(32,BB),256,0,stream>>>(hA, raw, da_wt[1], da_bt[1], da_bn[1], hB);

  conv_bn_relu_kernel<64,64><<<dim3(32,BB),256,0,stream>>>(hB, w3, bn3, hA);

  // attn3: hA -> hB
  zrow_kernel<<<dim3(32,BB),256,0,stream>>>(dens, da_wqk[2], 16, zinv);
  attn_mfma_kernel<64><<<dim3(32,BB),256,0,stream>>>(hA, dens, zinv, da_wqk[2], 16, raw);
  attn_post_kernel<64><<<dim3(32,BB),256,0,stream>>>(hA, raw, da_wt[2], da_bt[2], da_bn[2], hB);

  conv_bn_relu_kernel<64,128><<<dim3(32,BB),256,0,stream>>>(hB, w4, bn4, h4A);

  // attn4 (C=128): h4A -> h4B
  zrow_kernel<<<dim3(32,BB),256,0,stream>>>(dens, da_wqk[3], 32, zinv);
  attn_mfma_kernel<128><<<dim3(32,BB),256,0,stream>>>(h4A, dens, zinv, da_wqk[3], 32, raw);
  attn_post_kernel<128><<<dim3(32,BB),256,0,stream>>>(h4A, raw, da_wt[3], da_bt[3], da_bn[3], h4B);

  conv5_pool_kernel<<<dim3(16,BB),256,0,stream>>>(h4B, w5, bn5, pooled);
  lin1_kernel<<<dim3(32),256,0,stream>>>(pooled, lin1_w, bn6, l1o);
  lin2_kernel<<<dim3(10),64,0,stream>>>(l1o, lin2_w, lin2_b, (float*)d_out);
}

// Round 7
// 855.307 us; speedup vs baseline: 1.8779x; 1.0598x over previous
//
#include <hip/hip_runtime.h>
#include <math.h>

#define BB 16
#define NN 2048
#define BN_EPS_ 1e-5f

typedef __attribute__((ext_vector_type(8))) short short8v;   // 8 bf16 (4 VGPRs)
typedef __attribute__((ext_vector_type(4))) float f32x4;

__device__ __forceinline__ unsigned short f2bf(float x){
  unsigned u = __float_as_uint(x);
  u += 0x7fffu + ((u >> 16) & 1u);          // round-to-nearest-even
  return (unsigned short)(u >> 16);
}
__device__ __forceinline__ float bf2f(unsigned short h){
  return __uint_as_float(((unsigned)h) << 16);
}

// ---------------- normalize points once: u[b][3][n] = xyz/|xyz| ----------------
__global__ __launch_bounds__(256) void normalize_points_kernel(const float* __restrict__ x,
        float* __restrict__ u){
  int idx = blockIdx.x*256 + threadIdx.x;     // BB*NN threads
  int b = idx >> 11, n = idx & (NN-1);
  const float* xb = x + (size_t)b*3*NN;
  float x0 = xb[n], x1 = xb[NN+n], x2 = xb[2*NN+n];
  float rn = rsqrtf(x0*x0 + x1*x1 + x2*x2);
  float* ub = u + (size_t)b*3*NN;
  ub[n] = x0*rn; ub[NN+n] = x1*rn; ub[2*NN+n] = x2*rn;
}

// ---------------- density via batched histogram rank-select (no global atomics) ----------------
#define DG 8
__global__ __launch_bounds__(256) void density5_kernel(const float* __restrict__ u,
        float* __restrict__ inv, float* __restrict__ blockmax){
  __shared__ float us0[NN], us1[NN], us2[NN];      // 24 KiB
  __shared__ unsigned int hist[DG][256];           // 8 KiB
  __shared__ float buf[DG][128];                   // 4 KiB
  __shared__ unsigned int bufcnt[DG];
  __shared__ unsigned int bB[DG], bC0[DG];
  __shared__ float partial[DG][4];
  __shared__ float rowiv[DG];
  const int b = blockIdx.y;
  const float* ub = u + (size_t)b*3*NN;
  const int t = threadIdx.x;
  #pragma unroll
  for (int i = 0; i < NN/(256*4); ++i){
    int n4 = t + 256*i;
    ((float4*)us0)[n4] = ((const float4*)ub)[n4];
    ((float4*)us1)[n4] = ((const float4*)(ub+NN))[n4];
    ((float4*)us2)[n4] = ((const float4*)(ub+2*NN))[n4];
  }
  #pragma unroll
  for (int i = 0; i < DG; ++i) hist[i][t & 255] = 0u;
  if (t < DG) bufcnt[t] = 0u;
  __syncthreads();
  float m0[8], m1[8], m2[8];
  #pragma unroll
  for (int i = 0; i < 8; ++i){
    int c = t + 256*i;
    m0[i] = us0[c]; m1[i] = us1[c]; m2[i] = us2[c];
  }
  const int r0 = blockIdx.x * DG;
  float ru0[DG], ru1[DG], ru2[DG];
  #pragma unroll
  for (int j = 0; j < DG; ++j){ ru0[j] = us0[r0+j]; ru1[j] = us1[r0+j]; ru2[j] = us2[r0+j]; }

  unsigned qp[DG][2];
  #pragma unroll
  for (int j = 0; j < DG; ++j){
    unsigned q0 = 0u, q1 = 0u;
    #pragma unroll
    for (int i = 0; i < 8; ++i){
      float d = 1.0f - (ru0[j]*m0[i] + ru1[j]*m1[i] + ru2[j]*m2[i]);
      int q = (int)(d * 128.0f);
      q = q < 0 ? 0 : (q > 255 ? 255 : q);
      if (i < 4) q0 |= (unsigned)q << (8*i); else q1 |= (unsigned)q << (8*(i-4));
      atomicAdd(&hist[j][q], 1u);
    }
    qp[j][0] = q0; qp[j][1] = q1;
  }
  __syncthreads();

  const int wave = t >> 6, lane = t & 63;
  #pragma unroll
  for (int jj = 0; jj < 2; ++jj){
    const int j = 2*wave + jj;
    uint4 cc = *(const uint4*)&hist[j][lane*4];
    unsigned tl = cc.x + cc.y + cc.z + cc.w;
    unsigned inc = tl;
    #pragma unroll
    for (int off = 1; off < 64; off <<= 1){
      unsigned o = __shfl_up(inc, off);
      if (lane >= off) inc += o;
    }
    unsigned base = inc - tl;
    if (base < 32u && base + tl >= 32u){
      unsigned cum = base;
      if (cum < 32u && cum + cc.x >= 32u){ bB[j] = lane*4 + 0; bC0[j] = cum; } cum += cc.x;
      if (cum < 32u && cum + cc.y >= 32u){ bB[j] = lane*4 + 1; bC0[j] = cum; } cum += cc.y;
      if (cum < 32u && cum + cc.z >= 32u){ bB[j] = lane*4 + 2; bC0[j] = cum; } cum += cc.z;
      if (cum < 32u && cum + cc.w >= 32u){ bB[j] = lane*4 + 3; bC0[j] = cum; } cum += cc.w;
    }
  }
  __syncthreads();

  #pragma unroll
  for (int j = 0; j < DG; ++j){
    const int B = (int)bB[j];
    float s = 0.0f;
    #pragma unroll
    for (int i = 0; i < 8; ++i){
      float d = 1.0f - (ru0[j]*m0[i] + ru1[j]*m1[i] + ru2[j]*m2[i]);
      const int q = (int)((qp[j][i>>2] >> (8*(i&3))) & 255u);
      if (q < B) s += d;
      else if (q == B){
        unsigned slot = atomicAdd(&bufcnt[j], 1u);
        if (slot < 128u) buf[j][slot] = d;
      }
    }
    #pragma unroll
    for (int off = 32; off > 0; off >>= 1) s += __shfl_xor(s, off);
    if (lane == 0) partial[j][wave] = s;
  }
  __syncthreads();

  #pragma unroll
  for (int jj = 0; jj < 2; ++jj){
    const int j = 2*wave + jj;
    float total = partial[j][0] + partial[j][1] + partial[j][2] + partial[j][3];
    int cnt = (int)bufcnt[j]; if (cnt > 128) cnt = 128;
    const int rr = 32 - (int)bC0[j];
    float v1 = (lane      < cnt) ? buf[j][lane]      : 0.0f;
    float v2 = (lane + 64 < cnt) ? buf[j][lane + 64] : 0.0f;
    int rk1 = 0, rk2 = 0;
    for (int k = 0; k < cnt; ++k){
      float vk = buf[j][k];
      rk1 += ((vk < v1) || (vk == v1 && k < lane)) ? 1 : 0;
      rk2 += ((vk < v2) || (vk == v2 && k < lane + 64)) ? 1 : 0;
    }
    float contrib = ((lane      < cnt) && (rk1 < rr)) ? v1 : 0.0f;
    contrib      += ((lane + 64 < cnt) && (rk2 < rr)) ? v2 : 0.0f;
    #pragma unroll
    for (int off = 32; off > 0; off >>= 1) contrib += __shfl_xor(contrib, off);
    total += contrib;
    if (lane == 0){
      float iv = 32.0f / total;
      inv[b*NN + r0 + j] = iv;
      rowiv[j] = iv;
    }
  }
  __syncthreads();
  if (t == 0){
    float m = rowiv[0];
    #pragma unroll
    for (int j = 1; j < DG; ++j) m = fmaxf(m, rowiv[j]);
    blockmax[blockIdx.y * gridDim.x + blockIdx.x] = m;
  }
}

__global__ __launch_bounds__(256) void finalize_max_kernel(const float* __restrict__ blockmax,
        float* __restrict__ maxout){
  __shared__ float pw[4];
  const int t = threadIdx.x;
  float m = 0.0f;
  #pragma unroll
  for (int i = 0; i < 16; ++i) m = fmaxf(m, blockmax[t + 256*i]);
  #pragma unroll
  for (int off = 32; off > 0; off >>= 1) m = fmaxf(m, __shfl_xor(m, off));
  if ((t & 63) == 0) pw[t >> 6] = m;
  __syncthreads();
  if (t == 0) *maxout = fmaxf(fmaxf(pw[0], pw[1]), fmaxf(pw[2], pw[3]));
}

__global__ void normalize_kernel(float* __restrict__ dens, const float* __restrict__ maxval){
  int i = blockIdx.x*256 + threadIdx.x;
  float mx = *maxval;
  dens[i] = dens[i] / mx;
}

// --------- Zinv: out[r] = 1/Σ_m exp(s d[r] d[m]) ---------
__global__ __launch_bounds__(256) void zrow_kernel(const float* __restrict__ dens,
      const float* __restrict__ wqk, int K, float* __restrict__ out){
  __shared__ float ds[NN];
  const int b = blockIdx.y, t = threadIdx.x;
  float s = 0.0f;
  for (int k = 0; k < K; ++k){ float w = wqk[k]; s += w*w; }
  #pragma unroll
  for (int i = 0; i < NN/256; ++i) ds[t + 256*i] = dens[b*NN + t + 256*i];
  __syncthreads();
  const int wave = t >> 6, lane = t & 63;
  const int RPB = NN / gridDim.x;
  const int r0 = blockIdx.x * RPB;
  for (int r = r0 + wave; r < r0 + RPB; r += 4){
    float a = s * ds[r];
    float sum = 0.0f;
    #pragma unroll
    for (int i = 0; i < NN/64; ++i){
      int m = lane + 64*i;
      sum += __expf(a * ds[m]);
    }
    #pragma unroll
    for (int off = 32; off > 0; off >>= 1) sum += __shfl_xor(sum, off);
    if (lane == 0) out[b*NN + r] = 1.0f/sum;
  }
}

// --------- MFMA attention GEMM: raw[c,m] = Σ_n xz[c,n]·E[n,m], row C = Σ_n zinv[n]·E[n,m] ---------
// Split-bf16 (hi+lo, 3 MFMAs). KP=64 (128B stride) + XOR swizzle (byte ^= (row&7)<<4)
// on both stage-write and frag-read: 16 lanes/frag spread over 8 bank-groups (2-way = free).
template<int C>
__global__ __launch_bounds__(256) void attn_mfma_kernel(const float* __restrict__ x,
      const float* __restrict__ dens, const float* __restrict__ zinv,
      const float* __restrict__ wqk, int K, float* __restrict__ raw){
  constexpr int RA = C + 16;     // +16: zinv row (at C) + zero pad
  constexpr int RT = RA / 16;
  __shared__ __align__(16) unsigned short ah[RA][64], al[RA][64];
  __shared__ __align__(16) unsigned short eh[64][64], el[64][64];
  const int b = blockIdx.y, m0 = blockIdx.x * 64, t = threadIdx.x;
  float s = 0.0f;
  for (int k = 0; k < K; ++k){ float w = wqk[k]; s += w*w; }
  const float* db = dens + b*NN;
  const float* zb = zinv + b*NN;
  const float* xb = x + (size_t)b*C*NN;
  const int ej = t >> 2, ekq = (t & 3) * 16;       // E-gen: row (m) / k-quarter
  const float dmj = db[m0 + ej];
  const unsigned swe = (unsigned)((ej & 7) << 4);  // E write swizzle
  const int ar = t >> 4, ak4 = (t & 15) * 4;       // A-stage: row-in-16 / k4
  const int l = t & 63, w = t >> 6;                // MFMA: wave owns 16 cols
  const int fc = l & 15, g = l >> 4;
  const unsigned swr = (unsigned)((fc & 7) << 4);  // frag read swizzle (row&7 == fc&7)
  f32x4 acc[RT];
  #pragma unroll
  for (int i = 0; i < RT; ++i) acc[i] = (f32x4){0.f,0.f,0.f,0.f};

  for (int n0 = 0; n0 < NN; n0 += 64){
    __syncthreads();
    // ---- stage A tile (rows: 0..C-1 = x*zinv, C = zinv, >C = 0), hi/lo split, swizzled
    float4 zv = *(const float4*)(zb + n0 + ak4);
    #pragma unroll
    for (int i = 0; i < RT; ++i){
      int c = i*16 + ar;
      float4 v;
      if (c < C){
        float4 xv = *(const float4*)(xb + (size_t)c*NN + n0 + ak4);
        v.x = xv.x*zv.x; v.y = xv.y*zv.y; v.z = xv.z*zv.z; v.w = xv.w*zv.w;
      } else if (c == C){ v = zv; }
      else { v.x = v.y = v.z = v.w = 0.0f; }
      unsigned short h0=f2bf(v.x), h1=f2bf(v.y), h2=f2bf(v.z), h3=f2bf(v.w);
      uint2 hp, lp;
      hp.x = (unsigned)h0 | ((unsigned)h1<<16);
      hp.y = (unsigned)h2 | ((unsigned)h3<<16);
      lp.x = (unsigned)f2bf(v.x-bf2f(h0)) | ((unsigned)f2bf(v.y-bf2f(h1))<<16);
      lp.y = (unsigned)f2bf(v.z-bf2f(h2)) | ((unsigned)f2bf(v.w-bf2f(h3))<<16);
      unsigned off = (unsigned)(c*128) + (((unsigned)(ak4*2)) ^ ((unsigned)((c&7)<<4)));
      *(uint2*)((char*)ah + off) = hp;
      *(uint2*)((char*)al + off) = lp;
    }
    // ---- stage E tile: eh/el[j][k] = split(exp(s·d[n0+k]·d[m0+j])), 16 k per thread, swizzled
    {
      unsigned hp[8], lp[8];
      #pragma unroll
      for (int u = 0; u < 4; ++u){
        float4 dn = *(const float4*)(db + n0 + ekq + u*4);
        float e0 = __expf(s*dn.x*dmj), e1 = __expf(s*dn.y*dmj);
        float e2 = __expf(s*dn.z*dmj), e3 = __expf(s*dn.w*dmj);
        unsigned short a0=f2bf(e0), a1=f2bf(e1), a2=f2bf(e2), a3=f2bf(e3);
        hp[u*2+0] = (unsigned)a0 | ((unsigned)a1<<16);
        hp[u*2+1] = (unsigned)a2 | ((unsigned)a3<<16);
        lp[u*2+0] = (unsigned)f2bf(e0-bf2f(a0)) | ((unsigned)f2bf(e1-bf2f(a1))<<16);
        lp[u*2+1] = (unsigned)f2bf(e2-bf2f(a2)) | ((unsigned)f2bf(e3-bf2f(a3))<<16);
      }
      unsigned row = (unsigned)(ej*128);
      unsigned o1 = row + (((unsigned)(ekq*2))      ^ swe);
      unsigned o2 = row + (((unsigned)(ekq*2 + 16)) ^ swe);
      *(uint4*)((char*)eh + o1) = make_uint4(hp[0],hp[1],hp[2],hp[3]);
      *(uint4*)((char*)eh + o2) = make_uint4(hp[4],hp[5],hp[6],hp[7]);
      *(uint4*)((char*)el + o1) = make_uint4(lp[0],lp[1],lp[2],lp[3]);
      *(uint4*)((char*)el + o2) = make_uint4(lp[4],lp[5],lp[6],lp[7]);
    }
    __syncthreads();
    // ---- MFMA: D(16x16) += A(16x32)·B(32x16); 3-term split product
    #pragma unroll
    for (int kk = 0; kk < 2; ++kk){
      unsigned ko = ((unsigned)((kk*32 + g*8)*2)) ^ swr;
      unsigned eoff = (unsigned)((w*16 + fc)*128) + ko;
      short8v bh = *(const short8v*)((const char*)eh + eoff);
      short8v bl = *(const short8v*)((const char*)el + eoff);
      #pragma unroll
      for (int i = 0; i < RT; ++i){
        unsigned aoff = (unsigned)((i*16 + fc)*128) + ko;
        short8v ai = *(const short8v*)((const char*)ah + aoff);
        short8v au = *(const short8v*)((const char*)al + aoff);
        acc[i] = __builtin_amdgcn_mfma_f32_16x16x32_bf16(ai, bh, acc[i], 0, 0, 0);
        acc[i] = __builtin_amdgcn_mfma_f32_16x16x32_bf16(ai, bl, acc[i], 0, 0, 0);
        acc[i] = __builtin_amdgcn_mfma_f32_16x16x32_bf16(au, bh, acc[i], 0, 0, 0);
      }
    }
  }
  // ---- epilogue: D layout col=lane&15, row=(lane>>4)*4+r
  float* rb = raw + (size_t)b*RA*NN + m0 + w*16 + fc;
  #pragma unroll
  for (int i = 0; i < RT; ++i){
    #pragma unroll
    for (int r = 0; r < 4; ++r){
      int row = i*16 + g*4 + r;
      rb[(size_t)row*NN] = acc[i][r];
    }
  }
}

// --------- out = x + relu(bn(wt·(x - raw·csinv) + bt)); csinv from raw row C ---------
template<int C>
__global__ __launch_bounds__(256) void attn_post_kernel(const float* __restrict__ x,
      const float* __restrict__ raw, const float* __restrict__ wt,
      const float* __restrict__ bt, const float* __restrict__ bnp,
      float* __restrict__ out){
  constexpr int RA = C + 16;
  __shared__ float ds[32][68];
  __shared__ float ws[32][C+4];
  __shared__ float cbs[64];
  const int b = blockIdx.y, m0 = blockIdx.x*64, t = threadIdx.x;
  const float* xb = x + (size_t)b*C*NN;
  const float* rb = raw + (size_t)b*RA*NN;
  if (t < 64) cbs[t] = 1.0f / (1e-9f + rb[(size_t)C*NN + m0 + t]);
  const int tr = t >> 4, tc = t & 15;
  constexpr int R = C/16;
  float acc[R][4];
  #pragma unroll
  for (int i = 0; i < R; ++i){ acc[i][0]=acc[i][1]=acc[i][2]=acc[i][3]=0.0f; }
  for (int c0 = 0; c0 < C; c0 += 32){
    __syncthreads();
    #pragma unroll
    for (int i = 0; i < 8; ++i){
      int idx = t + 256*i;
      int m = idx & 63, cl = idx >> 6;
      int cc = c0 + cl;
      ds[cl][m] = xb[cc*NN + m0 + m] - rb[cc*NN + m0 + m] * cbs[m];
    }
    #pragma unroll
    for (int i = 0; i < C*32/256; ++i){
      int idx = t + 256*i;
      int cl = idx & 31, o = idx >> 5;
      ws[cl][o] = wt[o*C + c0 + cl];
    }
    __syncthreads();
    #pragma unroll
    for (int k = 0; k < 32; ++k){
      float4 e = *(const float4*)&ds[k][tc*4];
      float a[R];
      #pragma unroll
      for (int q = 0; q < R/4; ++q)
        *(float4*)&a[q*4] = *(const float4*)&ws[k][tr*R + q*4];
      #pragma unroll
      for (int i = 0; i < R; ++i){
        acc[i][0] += a[i]*e.x; acc[i][1] += a[i]*e.y;
        acc[i][2] += a[i]*e.z; acc[i][3] += a[i]*e.w;
      }
    }
  }
  #pragma unroll
  for (int i = 0; i < R; ++i){
    int o = tr*R + i;
    float g = bnp[o], be = bnp[C+o], mn = bnp[2*C+o], vv = bnp[3*C+o];
    float sc = g * rsqrtf(vv + BN_EPS_);
    float sh = be - mn*sc;
    float bv = bt[o];
    float4 r;
    float* rp = &r.x;
    #pragma unroll
    for (int j = 0; j < 4; ++j){
      float y = acc[i][j] + bv;
      y = sc*y + sh;
      y = fmaxf(y, 0.0f);
      rp[j] = xb[o*NN + m0 + tc*4 + j] + y;
    }
    *(float4*)&out[((size_t)b*C + o)*NN + m0 + tc*4] = r;
  }
}

// --------- out = relu(bn(w·x)) ---------
template<int CIN, int COUT>
__global__ __launch_bounds__(256) void conv_bn_relu_kernel(const float* __restrict__ x,
      const float* __restrict__ w, const float* __restrict__ bnp, float* __restrict__ out){
  constexpr int CH = (CIN < 32) ? CIN : 32;
  __shared__ float xs[CH][68];
  __shared__ float ws[CH][COUT+4];
  const int b = blockIdx.y, m0 = blockIdx.x*64, t = threadIdx.x;
  const float* xb = x + (size_t)b*CIN*NN;
  const int tr = t >> 4, tc = t & 15;
  constexpr int R = COUT/16;
  float acc[R][4];
  #pragma unroll
  for (int i = 0; i < R; ++i){ acc[i][0]=acc[i][1]=acc[i][2]=acc[i][3]=0.0f; }
  for (int c0 = 0; c0 < CIN; c0 += CH){
    __syncthreads();
    for (int idx = t; idx < CH*64; idx += 256){
      int m = idx & 63, cl = idx >> 6;
      xs[cl][m] = xb[(c0+cl)*NN + m0 + m];
    }
    for (int idx = t; idx < CH*COUT; idx += 256){
      int cl = idx % CH, o = idx / CH;
      ws[cl][o] = w[o*CIN + c0 + cl];
    }
    __syncthreads();
    #pragma unroll
    for (int k = 0; k < CH; ++k){
      float4 e = *(const float4*)&xs[k][tc*4];
      float a[R];
      #pragma unroll
      for (int q = 0; q < R/4; ++q)
        *(float4*)&a[q*4] = *(const float4*)&ws[k][tr*R + q*4];
      #pragma unroll
      for (int i = 0; i < R; ++i){
        acc[i][0] += a[i]*e.x; acc[i][1] += a[i]*e.y;
        acc[i][2] += a[i]*e.z; acc[i][3] += a[i]*e.w;
      }
    }
  }
  #pragma unroll
  for (int i = 0; i < R; ++i){
    int o = tr*R + i;
    float g = bnp[o], be = bnp[COUT+o], mn = bnp[2*COUT+o], vv = bnp[3*COUT+o];
    float sc = g * rsqrtf(vv + BN_EPS_);
    float sh = be - mn*sc;
    float4 r;
    float* rp = &r.x;
    #pragma unroll
    for (int j = 0; j < 4; ++j){
      float y = sc*acc[i][j] + sh;
      rp[j] = fmaxf(y, 0.0f);
    }
    *(float4*)&out[((size_t)b*COUT + o)*NN + m0 + tc*4] = r;
  }
}

// --------- pooled[b,o] = max_n relu(bn(Σ_c w5[o,c] h[c,n])); n split 4-ways, atomicMax merge ---------
__global__ __launch_bounds__(256) void conv5_pool_kernel(const float* __restrict__ h,
      const float* __restrict__ w5, const float* __restrict__ bnp, float* __restrict__ pooled){
  __shared__ float ws[128][68];
  __shared__ float hs[128][68];
  const int b = blockIdx.z, o0 = blockIdx.x*64, t = threadIdx.x;
  const int nb = blockIdx.y * (NN/4);
  const float* hb = h + (size_t)b*128*NN;
  #pragma unroll
  for (int i = 0; i < 32; ++i){
    int idx = t + 256*i;
    int cc = idx & 127, ol = idx >> 7;
    ws[cc][ol] = w5[(o0+ol)*128 + cc];
  }
  const int tr = t >> 4, tc = t & 15;
  float sc[4], sh[4];
  #pragma unroll
  for (int i = 0; i < 4; ++i){
    int o = o0 + tr*4 + i;
    float g = bnp[o], be = bnp[1024+o], mn = bnp[2*1024+o], vv = bnp[3*1024+o];
    sc[i] = g * rsqrtf(vv + BN_EPS_);
    sh[i] = be - mn*sc[i];
  }
  float vmax[4] = {0.f,0.f,0.f,0.f};
  for (int n0 = nb; n0 < nb + NN/4; n0 += 64){
    __syncthreads();
    #pragma unroll
    for (int i = 0; i < 32; ++i){
      int idx = t + 256*i;
      int nl = idx & 63, cc = idx >> 6;
      hs[cc][nl] = hb[cc*NN + n0 + nl];
    }
    __syncthreads();
    float acc[4][4];
    #pragma unroll
    for (int i = 0; i < 4; ++i){ acc[i][0]=acc[i][1]=acc[i][2]=acc[i][3]=0.0f; }
    #pragma unroll 8
    for (int k = 0; k < 128; ++k){
      float4 a = *(const float4*)&ws[k][tr*4];
      float4 e = *(const float4*)&hs[k][tc*4];
      acc[0][0]+=a.x*e.x; acc[0][1]+=a.x*e.y; acc[0][2]+=a.x*e.z; acc[0][3]+=a.x*e.w;
      acc[1][0]+=a.y*e.x; acc[1][1]+=a.y*e.y; acc[1][2]+=a.y*e.z; acc[1][3]+=a.y*e.w;
      acc[2][0]+=a.z*e.x; acc[2][1]+=a.z*e.y; acc[2][2]+=a.z*e.z; acc[2][3]+=a.z*e.w;
      acc[3][0]+=a.w*e.x; acc[3][1]+=a.w*e.y; acc[3][2]+=a.w*e.z; acc[3][3]+=a.w*e.w;
    }
    #pragma unroll
    for (int i = 0; i < 4; ++i){
      #pragma unroll
      for (int j = 0; j < 4; ++j){
        float y = sc[i]*acc[i][j] + sh[i];
        y = fmaxf(y, 0.0f);
        vmax[i] = fmaxf(vmax[i], y);
      }
    }
  }
  #pragma unroll
  for (int i = 0; i < 4; ++i){
    float v = vmax[i];
    v = fmaxf(v, __shfl_xor(v, 1));
    v = fmaxf(v, __shfl_xor(v, 2));
    v = fmaxf(v, __shfl_xor(v, 4));
    v = fmaxf(v, __shfl_xor(v, 8));
    if (tc == 0)
      atomicMax((unsigned int*)&pooled[b*1024 + o0 + tr*4 + i], __float_as_uint(v));
  }
}

// --------- lin1 + bn6 + relu ---------
__global__ void lin1_kernel(const float* __restrict__ pooled, const float* __restrict__ w,
      const float* __restrict__ bnp, float* __restrict__ out1){
  int tid = blockIdx.x*256 + threadIdx.x;
  int b = tid >> 9, j = tid & 511;
  const float4* p4 = (const float4*)(pooled + b*1024);
  const float4* w4 = (const float4*)(w + j*1024);
  float sum = 0.0f;
  for (int e = 0; e < 256; ++e){
    float4 a = p4[e], c = w4[e];
    sum += a.x*c.x + a.y*c.y + a.z*c.z + a.w*c.w;
  }
  float g = bnp[j], be = bnp[512+j], mn = bnp[2*512+j], vv = bnp[3*512+j];
  float s = g * rsqrtf(vv + BN_EPS_);
  float y = s*sum + (be - mn*s);
  out1[b*512 + j] = fmaxf(y, 0.0f);
}

// --------- lin2 ---------
__global__ void lin2_kernel(const float* __restrict__ h, const float* __restrict__ w,
      const float* __restrict__ bias, float* __restrict__ out){
  int tid = blockIdx.x*64 + threadIdx.x;
  if (tid >= 640) return;
  int b = tid / 40, k = tid % 40;
  const float4* h4 = (const float4*)(h + b*512);
  const float4* w4 = (const float4*)(w + k*512);
  float sum = 0.0f;
  for (int e = 0; e < 128; ++e){
    float4 a = h4[e], c = w4[e];
    sum += a.x*c.x + a.y*c.y + a.z*c.z + a.w*c.w;
  }
  out[tid] = sum + bias[k];
}

extern "C" void kernel_launch(void* const* d_in, const int* in_sizes, int n_in,
                              void* d_out, int out_size, void* d_ws, size_t ws_size,
                              hipStream_t stream){
  (void)in_sizes; (void)n_in; (void)out_size; (void)ws_size;
  const float* x     = (const float*)d_in[0];
  const float* w1    = (const float*)d_in[1];
  const float* w2    = (const float*)d_in[2];
  const float* w3    = (const float*)d_in[3];
  const float* w4    = (const float*)d_in[4];
  const float* w5    = (const float*)d_in[5];
  const float* bn1   = (const float*)d_in[6];
  const float* bn2   = (const float*)d_in[7];
  const float* bn3   = (const float*)d_in[8];
  const float* bn4   = (const float*)d_in[9];
  const float* bn5   = (const float*)d_in[10];
  const float* da_wqk[4] = {(const float*)d_in[11], (const float*)d_in[15], (const float*)d_in[19], (const float*)d_in[23]};
  const float* da_wt[4]  = {(const float*)d_in[12], (const float*)d_in[16], (const float*)d_in[20], (const float*)d_in[24]};
  const float* da_bt[4]  = {(const float*)d_in[13], (const float*)d_in[17], (const float*)d_in[21], (const float*)d_in[25]};
  const float* da_bn[4]  = {(const float*)d_in[14], (const float*)d_in[18], (const float*)d_in[22], (const float*)d_in[26]};
  const float* lin1_w = (const float*)d_in[27];
  const float* bn6    = (const float*)d_in[28];
  const float* lin2_w = (const float*)d_in[29];
  const float* lin2_b = (const float*)d_in[30];

  float* ws = (float*)d_ws;
  float* maxval = ws;                   // 1 float (padded to 64)
  float* dens   = ws + 64;
  float* zinv   = dens + BB*NN;
  float* hA     = zinv + BB*NN;
  float* hB     = hA  + (size_t)BB*64*NN;
  float* h4A    = hB  + (size_t)BB*64*NN;
  float* raw    = h4A + (size_t)BB*128*NN;      // sized for RA=144 rows
  float* pooled = raw + (size_t)BB*144*NN;
  float* l1o    = pooled + BB*1024;
  float* uvec   = l1o + BB*512;
  float* blockmax = uvec + (size_t)BB*3*NN;     // 4096 floats
  float* h4B    = hA;   // attn4 output reuses the (hA|hB) region

  normalize_points_kernel<<<dim3(BB*NN/256), 256, 0, stream>>>(x, uvec);
  density5_kernel<<<dim3(NN/DG, BB), 256, 0, stream>>>(uvec, dens, blockmax);
  finalize_max_kernel<<<dim3(1), 256, 0, stream>>>(blockmax, maxval);
  normalize_kernel<<<dim3(BB*NN/256), 256, 0, stream>>>(dens, maxval);

  conv_bn_relu_kernel<3,64><<<dim3(32,BB),256,0,stream>>>(x, w1, bn1, hA);

  // attn1: hA -> hB
  zrow_kernel<<<dim3(32,BB),256,0,stream>>>(dens, da_wqk[0], 16, zinv);
  attn_mfma_kernel<64><<<dim3(32,BB),256,0,stream>>>(hA, dens, zinv, da_wqk[0], 16, raw);
  attn_post_kernel<64><<<dim3(32,BB),256,0,stream>>>(hA, raw, da_wt[0], da_bt[0], da_bn[0], hB);

  conv_bn_relu_kernel<64,64><<<dim3(32,BB),256,0,stream>>>(hB, w2, bn2, hA);

  // attn2: hA -> hB
  zrow_kernel<<<dim3(32,BB),256,0,stream>>>(dens, da_wqk[1], 16, zinv);
  attn_mfma_kernel<64><<<dim3(32,BB),256,0,stream>>>(hA, dens, zinv, da_wqk[1], 16, raw);
  attn_post_kernel<64><<<dim3(32,BB),256,0,stream>>>(hA, raw, da_wt[1], da_bt[1], da_bn[1], hB);

  conv_bn_relu_kernel<64,64><<<dim3(32,BB),256,0,stream>>>(hB, w3, bn3, hA);

  // attn3: hA -> hB
  zrow_kernel<<<dim3(32,BB),256,0,stream>>>(dens, da_wqk[2], 16, zinv);
  attn_mfma_kernel<64><<<dim3(32,BB),256,0,stream>>>(hA, dens, zinv, da_wqk[2], 16, raw);
  attn_post_kernel<64><<<dim3(32,BB),256,0,stream>>>(hA, raw, da_wt[2], da_bt[2], da_bn[2], hB);

  conv_bn_relu_kernel<64,128><<<dim3(32,BB),256,0,stream>>>(hB, w4, bn4, h4A);

  // attn4 (C=128): h4A -> h4B
  zrow_kernel<<<dim3(32,BB),256,0,stream>>>(dens, da_wqk[3], 32, zinv);
  attn_mfma_kernel<128><<<dim3(32,BB),256,0,stream>>>(h4A, dens, zinv, da_wqk[3], 32, raw);
  attn_post_kernel<128><<<dim3(32,BB),256,0,stream>>>(h4A, raw, da_wt[3], da_bt[3], da_bn[3], h4B);

  hipMemsetAsync(pooled, 0, BB*1024*sizeof(float), stream);
  conv5_pool_kernel<<<dim3(16,4,BB),256,0,stream>>>(h4B, w5, bn5, pooled);
  lin1_kernel<<<dim3(32),256,0,stream>>>(pooled, lin1_w, bn6, l1o);
  lin2_kernel<<<dim3(10),64,0,stream>>>(l1o, lin2_w, lin2_b, (float*)d_out);
}

// Round 8
// 832.729 us; speedup vs baseline: 1.9288x; 1.0271x over previous
//
#include <hip/hip_runtime.h>
#include <math.h>

#define BB 16
#define NN 2048
#define BN_EPS_ 1e-5f

typedef __attribute__((ext_vector_type(8))) short short8v;   // 8 bf16 (4 VGPRs)
typedef __attribute__((ext_vector_type(4))) float f32x4;

__device__ __forceinline__ unsigned short f2bf(float x){
  unsigned u = __float_as_uint(x);
  u += 0x7fffu + ((u >> 16) & 1u);          // round-to-nearest-even
  return (unsigned short)(u >> 16);
}
__device__ __forceinline__ float bf2f(unsigned short h){
  return __uint_as_float(((unsigned)h) << 16);
}

// ---------------- normalize points once: u[b][3][n] = xyz/|xyz| ----------------
__global__ __launch_bounds__(256) void normalize_points_kernel(const float* __restrict__ x,
        float* __restrict__ u){
  int idx = blockIdx.x*256 + threadIdx.x;     // BB*NN threads
  int b = idx >> 11, n = idx & (NN-1);
  const float* xb = x + (size_t)b*3*NN;
  float x0 = xb[n], x1 = xb[NN+n], x2 = xb[2*NN+n];
  float rn = rsqrtf(x0*x0 + x1*x1 + x2*x2);
  float* ub = u + (size_t)b*3*NN;
  ub[n] = x0*rn; ub[NN+n] = x1*rn; ub[2*NN+n] = x2*rn;
}

// ---------------- density via batched histogram rank-select (no global atomics) ----------------
#define DG 8
__global__ __launch_bounds__(256) void density5_kernel(const float* __restrict__ u,
        float* __restrict__ inv, float* __restrict__ blockmax){
  __shared__ float us0[NN], us1[NN], us2[NN];      // 24 KiB
  __shared__ unsigned int hist[DG][256];           // 8 KiB
  __shared__ float buf[DG][128];                   // 4 KiB
  __shared__ unsigned int bufcnt[DG];
  __shared__ unsigned int bB[DG], bC0[DG];
  __shared__ float partial[DG][4];
  __shared__ float rowiv[DG];
  const int b = blockIdx.y;
  const float* ub = u + (size_t)b*3*NN;
  const int t = threadIdx.x;
  #pragma unroll
  for (int i = 0; i < NN/(256*4); ++i){
    int n4 = t + 256*i;
    ((float4*)us0)[n4] = ((const float4*)ub)[n4];
    ((float4*)us1)[n4] = ((const float4*)(ub+NN))[n4];
    ((float4*)us2)[n4] = ((const float4*)(ub+2*NN))[n4];
  }
  #pragma unroll
  for (int i = 0; i < DG; ++i) hist[i][t & 255] = 0u;
  if (t < DG) bufcnt[t] = 0u;
  __syncthreads();
  float m0[8], m1[8], m2[8];
  #pragma unroll
  for (int i = 0; i < 8; ++i){
    int c = t + 256*i;
    m0[i] = us0[c]; m1[i] = us1[c]; m2[i] = us2[c];
  }
  const int r0 = blockIdx.x * DG;
  float ru0[DG], ru1[DG], ru2[DG];
  #pragma unroll
  for (int j = 0; j < DG; ++j){ ru0[j] = us0[r0+j]; ru1[j] = us1[r0+j]; ru2[j] = us2[r0+j]; }

  unsigned qp[DG][2];
  #pragma unroll
  for (int j = 0; j < DG; ++j){
    unsigned q0 = 0u, q1 = 0u;
    #pragma unroll
    for (int i = 0; i < 8; ++i){
      float d = 1.0f - (ru0[j]*m0[i] + ru1[j]*m1[i] + ru2[j]*m2[i]);
      int q = (int)(d * 128.0f);
      q = q < 0 ? 0 : (q > 255 ? 255 : q);
      if (i < 4) q0 |= (unsigned)q << (8*i); else q1 |= (unsigned)q << (8*(i-4));
      atomicAdd(&hist[j][q], 1u);
    }
    qp[j][0] = q0; qp[j][1] = q1;
  }
  __syncthreads();

  const int wave = t >> 6, lane = t & 63;
  #pragma unroll
  for (int jj = 0; jj < 2; ++jj){
    const int j = 2*wave + jj;
    uint4 cc = *(const uint4*)&hist[j][lane*4];
    unsigned tl = cc.x + cc.y + cc.z + cc.w;
    unsigned inc = tl;
    #pragma unroll
    for (int off = 1; off < 64; off <<= 1){
      unsigned o = __shfl_up(inc, off);
      if (lane >= off) inc += o;
    }
    unsigned base = inc - tl;
    if (base < 32u && base + tl >= 32u){
      unsigned cum = base;
      if (cum < 32u && cum + cc.x >= 32u){ bB[j] = lane*4 + 0; bC0[j] = cum; } cum += cc.x;
      if (cum < 32u && cum + cc.y >= 32u){ bB[j] = lane*4 + 1; bC0[j] = cum; } cum += cc.y;
      if (cum < 32u && cum + cc.z >= 32u){ bB[j] = lane*4 + 2; bC0[j] = cum; } cum += cc.z;
      if (cum < 32u && cum + cc.w >= 32u){ bB[j] = lane*4 + 3; bC0[j] = cum; } cum += cc.w;
    }
  }
  __syncthreads();

  #pragma unroll
  for (int j = 0; j < DG; ++j){
    const int B = (int)bB[j];
    float s = 0.0f;
    #pragma unroll
    for (int i = 0; i < 8; ++i){
      float d = 1.0f - (ru0[j]*m0[i] + ru1[j]*m1[i] + ru2[j]*m2[i]);
      const int q = (int)((qp[j][i>>2] >> (8*(i&3))) & 255u);
      if (q < B) s += d;
      else if (q == B){
        unsigned slot = atomicAdd(&bufcnt[j], 1u);
        if (slot < 128u) buf[j][slot] = d;
      }
    }
    #pragma unroll
    for (int off = 32; off > 0; off >>= 1) s += __shfl_xor(s, off);
    if (lane == 0) partial[j][wave] = s;
  }
  __syncthreads();

  #pragma unroll
  for (int jj = 0; jj < 2; ++jj){
    const int j = 2*wave + jj;
    float total = partial[j][0] + partial[j][1] + partial[j][2] + partial[j][3];
    int cnt = (int)bufcnt[j]; if (cnt > 128) cnt = 128;
    const int rr = 32 - (int)bC0[j];
    float v1 = (lane      < cnt) ? buf[j][lane]      : 0.0f;
    float v2 = (lane + 64 < cnt) ? buf[j][lane + 64] : 0.0f;
    int rk1 = 0, rk2 = 0;
    for (int k = 0; k < cnt; ++k){
      float vk = buf[j][k];
      rk1 += ((vk < v1) || (vk == v1 && k < lane)) ? 1 : 0;
      rk2 += ((vk < v2) || (vk == v2 && k < lane + 64)) ? 1 : 0;
    }
    float contrib = ((lane      < cnt) && (rk1 < rr)) ? v1 : 0.0f;
    contrib      += ((lane + 64 < cnt) && (rk2 < rr)) ? v2 : 0.0f;
    #pragma unroll
    for (int off = 32; off > 0; off >>= 1) contrib += __shfl_xor(contrib, off);
    total += contrib;
    if (lane == 0){
      float iv = 32.0f / total;
      inv[b*NN + r0 + j] = iv;
      rowiv[j] = iv;
    }
  }
  __syncthreads();
  if (t == 0){
    float m = rowiv[0];
    #pragma unroll
    for (int j = 1; j < DG; ++j) m = fmaxf(m, rowiv[j]);
    blockmax[blockIdx.y * gridDim.x + blockIdx.x] = m;
  }
}

__global__ __launch_bounds__(256) void finalize_max_kernel(const float* __restrict__ blockmax,
        float* __restrict__ maxout){
  __shared__ float pw[4];
  const int t = threadIdx.x;
  float m = 0.0f;
  #pragma unroll
  for (int i = 0; i < 16; ++i) m = fmaxf(m, blockmax[t + 256*i]);
  #pragma unroll
  for (int off = 32; off > 0; off >>= 1) m = fmaxf(m, __shfl_xor(m, off));
  if ((t & 63) == 0) pw[t >> 6] = m;
  __syncthreads();
  if (t == 0) *maxout = fmaxf(fmaxf(pw[0], pw[1]), fmaxf(pw[2], pw[3]));
}

__global__ void normalize_kernel(float* __restrict__ dens, const float* __restrict__ maxval){
  int i = blockIdx.x*256 + threadIdx.x;
  float mx = *maxval;
  dens[i] = dens[i] / mx;
}

// --------- Zinv: out[r] = 1/Σ_m exp(s d[r] d[m]) ---------
__global__ __launch_bounds__(256) void zrow_kernel(const float* __restrict__ dens,
      const float* __restrict__ wqk, int K, float* __restrict__ out){
  __shared__ float ds[NN];
  const int b = blockIdx.y, t = threadIdx.x;
  float s = 0.0f;
  for (int k = 0; k < K; ++k){ float w = wqk[k]; s += w*w; }
  #pragma unroll
  for (int i = 0; i < NN/256; ++i) ds[t + 256*i] = dens[b*NN + t + 256*i];
  __syncthreads();
  const int wave = t >> 6, lane = t & 63;
  const int RPB = NN / gridDim.x;
  const int r0 = blockIdx.x * RPB;
  for (int r = r0 + wave; r < r0 + RPB; r += 4){
    float a = s * ds[r];
    float sum = 0.0f;
    #pragma unroll
    for (int i = 0; i < NN/64; ++i){
      int m = lane + 64*i;
      sum += __expf(a * ds[m]);
    }
    #pragma unroll
    for (int off = 32; off > 0; off >>= 1) sum += __shfl_xor(sum, off);
    if (lane == 0) out[b*NN + r] = 1.0f/sum;
  }
}

// --------- MFMA attention GEMM: raw[c,m] = Σ_n xz[c,n]·E[n,m], row C = Σ_n zinv[n]·E[n,m] ---------
// Split-bf16 (hi+lo, 3 MFMAs), XOR-swizzled LDS (0 bank conflicts).
// XCD-swizzled 1-D grid (512): all 32 m-blocks of batch b land on XCD b%8 so A stays in that L2.
template<int C>
__global__ __launch_bounds__(256) void attn_mfma_kernel(const float* __restrict__ x,
      const float* __restrict__ dens, const float* __restrict__ zinv,
      const float* __restrict__ wqk, int K, float* __restrict__ raw){
  constexpr int RA = C + 16;     // +16: zinv row (at C) + zero pad
  constexpr int RT = RA / 16;
  __shared__ __align__(16) unsigned short ah[RA][64], al[RA][64];
  __shared__ __align__(16) unsigned short eh[64][64], el[64][64];
  const int id = blockIdx.x;                       // id = (b%8) + 8*j + 256*(b/8)
  const int b  = (id & 7) + ((id >> 8) << 3);
  const int m0 = ((id >> 3) & 31) * 64;
  const int t = threadIdx.x;
  float s = 0.0f;
  for (int k = 0; k < K; ++k){ float w = wqk[k]; s += w*w; }
  const float* db = dens + b*NN;
  const float* zb = zinv + b*NN;
  const float* xb = x + (size_t)b*C*NN;
  const int ej = t >> 2, ekq = (t & 3) * 16;       // E-gen: row (m) / k-quarter
  const float dmj = db[m0 + ej];
  const unsigned swe = (unsigned)((ej & 7) << 4);  // E write swizzle
  const int ar = t >> 4, ak4 = (t & 15) * 4;       // A-stage: row-in-16 / k4
  const int l = t & 63, w = t >> 6;                // MFMA: wave owns 16 cols
  const int fc = l & 15, g = l >> 4;
  const unsigned swr = (unsigned)((fc & 7) << 4);  // frag read swizzle (row&7 == fc&7)
  f32x4 acc[RT];
  #pragma unroll
  for (int i = 0; i < RT; ++i) acc[i] = (f32x4){0.f,0.f,0.f,0.f};

  for (int n0 = 0; n0 < NN; n0 += 64){
    __syncthreads();
    // ---- stage A tile (rows: 0..C-1 = x*zinv, C = zinv, >C = 0), hi/lo split, swizzled
    float4 zv = *(const float4*)(zb + n0 + ak4);
    #pragma unroll
    for (int i = 0; i < RT; ++i){
      int c = i*16 + ar;
      float4 v;
      if (c < C){
        float4 xv = *(const float4*)(xb + (size_t)c*NN + n0 + ak4);
        v.x = xv.x*zv.x; v.y = xv.y*zv.y; v.z = xv.z*zv.z; v.w = xv.w*zv.w;
      } else if (c == C){ v = zv; }
      else { v.x = v.y = v.z = v.w = 0.0f; }
      unsigned short h0=f2bf(v.x), h1=f2bf(v.y), h2=f2bf(v.z), h3=f2bf(v.w);
      uint2 hp, lp;
      hp.x = (unsigned)h0 | ((unsigned)h1<<16);
      hp.y = (unsigned)h2 | ((unsigned)h3<<16);
      lp.x = (unsigned)f2bf(v.x-bf2f(h0)) | ((unsigned)f2bf(v.y-bf2f(h1))<<16);
      lp.y = (unsigned)f2bf(v.z-bf2f(h2)) | ((unsigned)f2bf(v.w-bf2f(h3))<<16);
      unsigned off = (unsigned)(c*128) + (((unsigned)(ak4*2)) ^ ((unsigned)((c&7)<<4)));
      *(uint2*)((char*)ah + off) = hp;
      *(uint2*)((char*)al + off) = lp;
    }
    // ---- stage E tile: eh/el[j][k] = split(exp(s·d[n0+k]·d[m0+j])), 16 k per thread, swizzled
    {
      unsigned hp[8], lp[8];
      #pragma unroll
      for (int u = 0; u < 4; ++u){
        float4 dn = *(const float4*)(db + n0 + ekq + u*4);
        float e0 = __expf(s*dn.x*dmj), e1 = __expf(s*dn.y*dmj);
        float e2 = __expf(s*dn.z*dmj), e3 = __expf(s*dn.w*dmj);
        unsigned short a0=f2bf(e0), a1=f2bf(e1), a2=f2bf(e2), a3=f2bf(e3);
        hp[u*2+0] = (unsigned)a0 | ((unsigned)a1<<16);
        hp[u*2+1] = (unsigned)a2 | ((unsigned)a3<<16);
        lp[u*2+0] = (unsigned)f2bf(e0-bf2f(a0)) | ((unsigned)f2bf(e1-bf2f(a1))<<16);
        lp[u*2+1] = (unsigned)f2bf(e2-bf2f(a2)) | ((unsigned)f2bf(e3-bf2f(a3))<<16);
      }
      unsigned row = (unsigned)(ej*128);
      unsigned o1 = row + (((unsigned)(ekq*2))      ^ swe);
      unsigned o2 = row + (((unsigned)(ekq*2 + 16)) ^ swe);
      *(uint4*)((char*)eh + o1) = make_uint4(hp[0],hp[1],hp[2],hp[3]);
      *(uint4*)((char*)eh + o2) = make_uint4(hp[4],hp[5],hp[6],hp[7]);
      *(uint4*)((char*)el + o1) = make_uint4(lp[0],lp[1],lp[2],lp[3]);
      *(uint4*)((char*)el + o2) = make_uint4(lp[4],lp[5],lp[6],lp[7]);
    }
    __syncthreads();
    // ---- MFMA: D(16x16) += A(16x32)·B(32x16); 3-term split product
    #pragma unroll
    for (int kk = 0; kk < 2; ++kk){
      unsigned ko = ((unsigned)((kk*32 + g*8)*2)) ^ swr;
      unsigned eoff = (unsigned)((w*16 + fc)*128) + ko;
      short8v bh = *(const short8v*)((const char*)eh + eoff);
      short8v bl = *(const short8v*)((const char*)el + eoff);
      #pragma unroll
      for (int i = 0; i < RT; ++i){
        unsigned aoff = (unsigned)((i*16 + fc)*128) + ko;
        short8v ai = *(const short8v*)((const char*)ah + aoff);
        short8v au = *(const short8v*)((const char*)al + aoff);
        acc[i] = __builtin_amdgcn_mfma_f32_16x16x32_bf16(ai, bh, acc[i], 0, 0, 0);
        acc[i] = __builtin_amdgcn_mfma_f32_16x16x32_bf16(ai, bl, acc[i], 0, 0, 0);
        acc[i] = __builtin_amdgcn_mfma_f32_16x16x32_bf16(au, bh, acc[i], 0, 0, 0);
      }
    }
  }
  // ---- epilogue: D layout col=lane&15, row=(lane>>4)*4+r
  float* rb = raw + (size_t)b*RA*NN + m0 + w*16 + fc;
  #pragma unroll
  for (int i = 0; i < RT; ++i){
    #pragma unroll
    for (int r = 0; r < 4; ++r){
      int row = i*16 + g*4 + r;
      rb[(size_t)row*NN] = acc[i][r];
    }
  }
}

// --------- out = x + relu(bn(wt·(x - raw·csinv) + bt)); csinv from raw row C ---------
template<int C>
__global__ __launch_bounds__(256) void attn_post_kernel(const float* __restrict__ x,
      const float* __restrict__ raw, const float* __restrict__ wt,
      const float* __restrict__ bt, const float* __restrict__ bnp,
      float* __restrict__ out){
  constexpr int RA = C + 16;
  __shared__ float ds[32][68];
  __shared__ float ws[32][C+4];
  __shared__ float cbs[64];
  const int b = blockIdx.y, m0 = blockIdx.x*64, t = threadIdx.x;
  const float* xb = x + (size_t)b*C*NN;
  const float* rb = raw + (size_t)b*RA*NN;
  if (t < 64) cbs[t] = 1.0f / (1e-9f + rb[(size_t)C*NN + m0 + t]);
  const int tr = t >> 4, tc = t & 15;
  constexpr int R = C/16;
  float acc[R][4];
  #pragma unroll
  for (int i = 0; i < R; ++i){ acc[i][0]=acc[i][1]=acc[i][2]=acc[i][3]=0.0f; }
  for (int c0 = 0; c0 < C; c0 += 32){
    __syncthreads();
    #pragma unroll
    for (int i = 0; i < 8; ++i){
      int idx = t + 256*i;
      int m = idx & 63, cl = idx >> 6;
      int cc = c0 + cl;
      ds[cl][m] = xb[cc*NN + m0 + m] - rb[cc*NN + m0 + m] * cbs[m];
    }
    #pragma unroll
    for (int i = 0; i < C*32/256; ++i){
      int idx = t + 256*i;
      int cl = idx & 31, o = idx >> 5;
      ws[cl][o] = wt[o*C + c0 + cl];
    }
    __syncthreads();
    #pragma unroll
    for (int k = 0; k < 32; ++k){
      float4 e = *(const float4*)&ds[k][tc*4];
      float a[R];
      #pragma unroll
      for (int q = 0; q < R/4; ++q)
        *(float4*)&a[q*4] = *(const float4*)&ws[k][tr*R + q*4];
      #pragma unroll
      for (int i = 0; i < R; ++i){
        acc[i][0] += a[i]*e.x; acc[i][1] += a[i]*e.y;
        acc[i][2] += a[i]*e.z; acc[i][3] += a[i]*e.w;
      }
    }
  }
  #pragma unroll
  for (int i = 0; i < R; ++i){
    int o = tr*R + i;
    float g = bnp[o], be = bnp[C+o], mn = bnp[2*C+o], vv = bnp[3*C+o];
    float sc = g * rsqrtf(vv + BN_EPS_);
    float sh = be - mn*sc;
    float bv = bt[o];
    float4 r;
    float* rp = &r.x;
    #pragma unroll
    for (int j = 0; j < 4; ++j){
      float y = acc[i][j] + bv;
      y = sc*y + sh;
      y = fmaxf(y, 0.0f);
      rp[j] = xb[o*NN + m0 + tc*4 + j] + y;
    }
    *(float4*)&out[((size_t)b*C + o)*NN + m0 + tc*4] = r;
  }
}

// --------- out = relu(bn(w·x)) ---------
template<int CIN, int COUT>
__global__ __launch_bounds__(256) void conv_bn_relu_kernel(const float* __restrict__ x,
      const float* __restrict__ w, const float* __restrict__ bnp, float* __restrict__ out){
  constexpr int CH = (CIN < 32) ? CIN : 32;
  __shared__ float xs[CH][68];
  __shared__ float ws[CH][COUT+4];
  const int b = blockIdx.y, m0 = blockIdx.x*64, t = threadIdx.x;
  const float* xb = x + (size_t)b*CIN*NN;
  const int tr = t >> 4, tc = t & 15;
  constexpr int R = COUT/16;
  float acc[R][4];
  #pragma unroll
  for (int i = 0; i < R; ++i){ acc[i][0]=acc[i][1]=acc[i][2]=acc[i][3]=0.0f; }
  for (int c0 = 0; c0 < CIN; c0 += CH){
    __syncthreads();
    for (int idx = t; idx < CH*64; idx += 256){
      int m = idx & 63, cl = idx >> 6;
      xs[cl][m] = xb[(c0+cl)*NN + m0 + m];
    }
    for (int idx = t; idx < CH*COUT; idx += 256){
      int cl = idx % CH, o = idx / CH;
      ws[cl][o] = w[o*CIN + c0 + cl];
    }
    __syncthreads();
    #pragma unroll
    for (int k = 0; k < CH; ++k){
      float4 e = *(const float4*)&xs[k][tc*4];
      float a[R];
      #pragma unroll
      for (int q = 0; q < R/4; ++q)
        *(float4*)&a[q*4] = *(const float4*)&ws[k][tr*R + q*4];
      #pragma unroll
      for (int i = 0; i < R; ++i){
        acc[i][0] += a[i]*e.x; acc[i][1] += a[i]*e.y;
        acc[i][2] += a[i]*e.z; acc[i][3] += a[i]*e.w;
      }
    }
  }
  #pragma unroll
  for (int i = 0; i < R; ++i){
    int o = tr*R + i;
    float g = bnp[o], be = bnp[COUT+o], mn = bnp[2*COUT+o], vv = bnp[3*COUT+o];
    float sc = g * rsqrtf(vv + BN_EPS_);
    float sh = be - mn*sc;
    float4 r;
    float* rp = &r.x;
    #pragma unroll
    for (int j = 0; j < 4; ++j){
      float y = sc*acc[i][j] + sh;
      rp[j] = fmaxf(y, 0.0f);
    }
    *(float4*)&out[((size_t)b*COUT + o)*NN + m0 + tc*4] = r;
  }
}

// --------- pooled[b,o] = max_n relu(bn(Σ_c w5[o,c] h[c,n])); XCD-swizzled, atomicMax merge ---------
__global__ __launch_bounds__(256) void conv5_pool_kernel(const float* __restrict__ h,
      const float* __restrict__ w5, const float* __restrict__ bnp, float* __restrict__ pooled){
  __shared__ float ws[128][68];
  __shared__ float hs[128][68];
  const int id = blockIdx.x;                 // id = (b%8) + 8*inner + 512*(b/8)
  const int b  = (id & 7) + ((id >> 9) << 3);
  const int inner = (id >> 3) & 63;
  const int o0 = (inner & 15) * 64;
  const int nb = (inner >> 4) * (NN/4);
  const int t = threadIdx.x;
  const float* hb = h + (size_t)b*128*NN;
  #pragma unroll
  for (int i = 0; i < 32; ++i){
    int idx = t + 256*i;
    int cc = idx & 127, ol = idx >> 7;
    ws[cc][ol] = w5[(o0+ol)*128 + cc];
  }
  const int tr = t >> 4, tc = t & 15;
  float sc[4], sh[4];
  #pragma unroll
  for (int i = 0; i < 4; ++i){
    int o = o0 + tr*4 + i;
    float g = bnp[o], be = bnp[1024+o], mn = bnp[2*1024+o], vv = bnp[3*1024+o];
    sc[i] = g * rsqrtf(vv + BN_EPS_);
    sh[i] = be - mn*sc[i];
  }
  float vmax[4] = {0.f,0.f,0.f,0.f};
  for (int n0 = nb; n0 < nb + NN/4; n0 += 64){
    __syncthreads();
    #pragma unroll
    for (int i = 0; i < 32; ++i){
      int idx = t + 256*i;
      int nl = idx & 63, cc = idx >> 6;
      hs[cc][nl] = hb[cc*NN + n0 + nl];
    }
    __syncthreads();
    float acc[4][4];
    #pragma unroll
    for (int i = 0; i < 4; ++i){ acc[i][0]=acc[i][1]=acc[i][2]=acc[i][3]=0.0f; }
    #pragma unroll 8
    for (int k = 0; k < 128; ++k){
      float4 a = *(const float4*)&ws[k][tr*4];
      float4 e = *(const float4*)&hs[k][tc*4];
      acc[0][0]+=a.x*e.x; acc[0][1]+=a.x*e.y; acc[0][2]+=a.x*e.z; acc[0][3]+=a.x*e.w;
      acc[1][0]+=a.y*e.x; acc[1][1]+=a.y*e.y; acc[1][2]+=a.y*e.z; acc[1][3]+=a.y*e.w;
      acc[2][0]+=a.z*e.x; acc[2][1]+=a.z*e.y; acc[2][2]+=a.z*e.z; acc[2][3]+=a.z*e.w;
      acc[3][0]+=a.w*e.x; acc[3][1]+=a.w*e.y; acc[3][2]+=a.w*e.z; acc[3][3]+=a.w*e.w;
    }
    #pragma unroll
    for (int i = 0; i < 4; ++i){
      #pragma unroll
      for (int j = 0; j < 4; ++j){
        float y = sc[i]*acc[i][j] + sh[i];
        y = fmaxf(y, 0.0f);
        vmax[i] = fmaxf(vmax[i], y);
      }
    }
  }
  #pragma unroll
  for (int i = 0; i < 4; ++i){
    float v = vmax[i];
    v = fmaxf(v, __shfl_xor(v, 1));
    v = fmaxf(v, __shfl_xor(v, 2));
    v = fmaxf(v, __shfl_xor(v, 4));
    v = fmaxf(v, __shfl_xor(v, 8));
    if (tc == 0)
      atomicMax((unsigned int*)&pooled[b*1024 + o0 + tr*4 + i], __float_as_uint(v));
  }
}

// --------- lin1 + bn6 + relu ---------
__global__ void lin1_kernel(const float* __restrict__ pooled, const float* __restrict__ w,
      const float* __restrict__ bnp, float* __restrict__ out1){
  int tid = blockIdx.x*256 + threadIdx.x;
  int b = tid >> 9, j = tid & 511;
  const float4* p4 = (const float4*)(pooled + b*1024);
  const float4* w4 = (const float4*)(w + j*1024);
  float sum = 0.0f;
  for (int e = 0; e < 256; ++e){
    float4 a = p4[e], c = w4[e];
    sum += a.x*c.x + a.y*c.y + a.z*c.z + a.w*c.w;
  }
  float g = bnp[j], be = bnp[512+j], mn = bnp[2*512+j], vv = bnp[3*512+j];
  float s = g * rsqrtf(vv + BN_EPS_);
  float y = s*sum + (be - mn*s);
  out1[b*512 + j] = fmaxf(y, 0.0f);
}

// --------- lin2 ---------
__global__ void lin2_kernel(const float* __restrict__ h, const float* __restrict__ w,
      const float* __restrict__ bias, float* __restrict__ out){
  int tid = blockIdx.x*64 + threadIdx.x;
  if (tid >= 640) return;
  int b = tid / 40, k = tid % 40;
  const float4* h4 = (const float4*)(h + b*512);
  const float4* w4 = (const float4*)(w + k*512);
  float sum = 0.0f;
  for (int e = 0; e < 128; ++e){
    float4 a = h4[e], c = w4[e];
    sum += a.x*c.x + a.y*c.y + a.z*c.z + a.w*c.w;
  }
  out[tid] = sum + bias[k];
}

extern "C" void kernel_launch(void* const* d_in, const int* in_sizes, int n_in,
                              void* d_out, int out_size, void* d_ws, size_t ws_size,
                              hipStream_t stream){
  (void)in_sizes; (void)n_in; (void)out_size; (void)ws_size;
  const float* x     = (const float*)d_in[0];
  const float* w1    = (const float*)d_in[1];
  const float* w2    = (const float*)d_in[2];
  const float* w3    = (const float*)d_in[3];
  const float* w4    = (const float*)d_in[4];
  const float* w5    = (const float*)d_in[5];
  const float* bn1   = (const float*)d_in[6];
  const float* bn2   = (const float*)d_in[7];
  const float* bn3   = (const float*)d_in[8];
  const float* bn4   = (const float*)d_in[9];
  const float* bn5   = (const float*)d_in[10];
  const float* da_wqk[4] = {(const float*)d_in[11], (const float*)d_in[15], (const float*)d_in[19], (const float*)d_in[23]};
  const float* da_wt[4]  = {(const float*)d_in[12], (const float*)d_in[16], (const float*)d_in[20], (const float*)d_in[24]};
  const float* da_bt[4]  = {(const float*)d_in[13], (const float*)d_in[17], (const float*)d_in[21], (const float*)d_in[25]};
  const float* da_bn[4]  = {(const float*)d_in[14], (const float*)d_in[18], (const float*)d_in[22], (const float*)d_in[26]};
  const float* lin1_w = (const float*)d_in[27];
  const float* bn6    = (const float*)d_in[28];
  const float* lin2_w = (const float*)d_in[29];
  const float* lin2_b = (const float*)d_in[30];

  float* ws = (float*)d_ws;
  float* maxval = ws;                   // 1 float (padded to 64)
  float* dens   = ws + 64;
  float* zinv   = dens + BB*NN;
  float* hA     = zinv + BB*NN;
  float* hB     = hA  + (size_t)BB*64*NN;
  float* h4A    = hB  + (size_t)BB*64*NN;
  float* raw    = h4A + (size_t)BB*128*NN;      // sized for RA=144 rows
  float* pooled = raw + (size_t)BB*144*NN;
  float* l1o    = pooled + BB*1024;
  float* uvec   = l1o + BB*512;
  float* blockmax = uvec + (size_t)BB*3*NN;     // 4096 floats
  float* h4B    = hA;   // attn4 output reuses the (hA|hB) region

  normalize_points_kernel<<<dim3(BB*NN/256), 256, 0, stream>>>(x, uvec);
  density5_kernel<<<dim3(NN/DG, BB), 256, 0, stream>>>(uvec, dens, blockmax);
  finalize_max_kernel<<<dim3(1), 256, 0, stream>>>(blockmax, maxval);
  normalize_kernel<<<dim3(BB*NN/256), 256, 0, stream>>>(dens, maxval);

  conv_bn_relu_kernel<3,64><<<dim3(32,BB),256,0,stream>>>(x, w1, bn1, hA);

  // attn1: hA -> hB
  zrow_kernel<<<dim3(32,BB),256,0,stream>>>(dens, da_wqk[0], 16, zinv);
  attn_mfma_kernel<64><<<dim3(512),256,0,stream>>>(hA, dens, zinv, da_wqk[0], 16, raw);
  attn_post_kernel<64><<<dim3(32,BB),256,0,stream>>>(hA, raw, da_wt[0], da_bt[0], da_bn[0], hB);

  conv_bn_relu_kernel<64,64><<<dim3(32,BB),256,0,stream>>>(hB, w2, bn2, hA);

  // attn2: hA -> hB
  zrow_kernel<<<dim3(32,BB),256,0,stream>>>(dens, da_wqk[1], 16, zinv);
  attn_mfma_kernel<64><<<dim3(512),256,0,stream>>>(hA, dens, zinv, da_wqk[1], 16, raw);
  attn_post_kernel<64><<<dim3(32,BB),256,0,stream>>>(hA, raw, da_wt[1], da_bt[1], da_bn[1], hB);

  conv_bn_relu_kernel<64,64><<<dim3(32,BB),256,0,stream>>>(hB, w3, bn3, hA);

  // attn3: hA -> hB
  zrow_kernel<<<dim3(32,BB),256,0,stream>>>(dens, da_wqk[2], 16, zinv);
  attn_mfma_kernel<64><<<dim3(512),256,0,stream>>>(hA, dens, zinv, da_wqk[2], 16, raw);
  attn_post_kernel<64><<<dim3(32,BB),256,0,stream>>>(hA, raw, da_wt[2], da_bt[2], da_bn[2], hB);

  conv_bn_relu_kernel<64,128><<<dim3(32,BB),256,0,stream>>>(hB, w4, bn4, h4A);

  // attn4 (C=128): h4A -> h4B
  zrow_kernel<<<dim3(32,BB),256,0,stream>>>(dens, da_wqk[3], 32, zinv);
  attn_mfma_kernel<128><<<dim3(512),256,0,stream>>>(h4A, dens, zinv, da_wqk[3], 32, raw);
  attn_post_kernel<128><<<dim3(32,BB),256,0,stream>>>(h4A, raw, da_wt[3], da_bt[3], da_bn[3], h4B);

  hipMemsetAsync(pooled, 0, BB*1024*sizeof(float), stream);
  conv5_pool_kernel<<<dim3(1024),256,0,stream>>>(h4B, w5, bn5, pooled);
  lin1_kernel<<<dim3(32),256,0,stream>>>(pooled, lin1_w, bn6, l1o);
  lin2_kernel<<<dim3(10),64,0,stream>>>(l1o, lin2_w, lin2_b, (float*)d_out);
}